// Round 4
// baseline (845.884 us; speedup 1.0000x reference)
//
#include <hip/hip_runtime.h>

#define N_TOKEN 8192
#define N_EMBED 512
#define T_TOKENS 16384
#define KP 1536   // packed K = 3 * 512
#define NT 48     // K-tiles of 32

typedef __bf16 bf16x8 __attribute__((ext_vector_type(8)));
typedef __bf16 bf16x4 __attribute__((ext_vector_type(4)));
typedef float f32x4 __attribute__((ext_vector_type(4)));

// ---------- helpers ----------
__device__ __forceinline__ unsigned int fkey(float f) {
  unsigned int u = __float_as_uint(f);
  return (u & 0x80000000u) ? ~u : (u | 0x80000000u);
}

__device__ __forceinline__ void gl2lds16(const void* gsrc, void* lds) {
  __builtin_amdgcn_global_load_lds(
      (const __attribute__((address_space(1))) unsigned int*)gsrc,
      (__attribute__((address_space(3))) unsigned int*)lds, 16, 0, 0);
}

// ---------- K1: h[k] = 0.5*||key_w[k]||^2 (f32, exact norms) ----------
__global__ void k_hnorm(const float* __restrict__ key_w, float* __restrict__ h) {
  int code = blockIdx.x * 4 + (threadIdx.x >> 6);
  int lane = threadIdx.x & 63;
  const float4* row = reinterpret_cast<const float4*>(key_w + (size_t)code * N_EMBED);
  float s = 0.f;
  float4 v0 = row[lane];
  float4 v1 = row[lane + 64];
  s += v0.x*v0.x + v0.y*v0.y + v0.z*v0.z + v0.w*v0.w;
  s += v1.x*v1.x + v1.y*v1.y + v1.z*v1.z + v1.w*v1.w;
  #pragma unroll
  for (int off = 32; off; off >>= 1) s += __shfl_down(s, off);
  if (lane == 0) h[code] = 0.5f * s;
}

// ---------- pack kernels: split f32 -> [hi|hi|lo] / [hi|lo|hi] bf16 ----------
__global__ void k_pack_x(const float* __restrict__ x, __bf16* __restrict__ xp) {
  int gid = blockIdx.x * blockDim.x + threadIdx.x;  // float4 index
  int t = gid >> 7, d4 = gid & 127;
  float4 v = reinterpret_cast<const float4*>(x)[gid];
  bf16x4 hi, lo;
  hi[0] = (__bf16)v.x; hi[1] = (__bf16)v.y; hi[2] = (__bf16)v.z; hi[3] = (__bf16)v.w;
  lo[0] = (__bf16)(v.x - (float)hi[0]);
  lo[1] = (__bf16)(v.y - (float)hi[1]);
  lo[2] = (__bf16)(v.z - (float)hi[2]);
  lo[3] = (__bf16)(v.w - (float)hi[3]);
  __bf16* row = xp + (size_t)t * KP + d4 * 4;
  *(bf16x4*)(row)        = hi;
  *(bf16x4*)(row + 512)  = hi;
  *(bf16x4*)(row + 1024) = lo;
}

__global__ void k_pack_k(const float* __restrict__ kw, __bf16* __restrict__ kp) {
  int gid = blockIdx.x * blockDim.x + threadIdx.x;  // float4 index
  int n = gid >> 7, d4 = gid & 127;
  float4 v = reinterpret_cast<const float4*>(kw)[gid];
  bf16x4 hi, lo;
  hi[0] = (__bf16)v.x; hi[1] = (__bf16)v.y; hi[2] = (__bf16)v.z; hi[3] = (__bf16)v.w;
  lo[0] = (__bf16)(v.x - (float)hi[0]);
  lo[1] = (__bf16)(v.y - (float)hi[1]);
  lo[2] = (__bf16)(v.z - (float)hi[2]);
  lo[3] = (__bf16)(v.w - (float)hi[3]);
  __bf16* row = kp + (size_t)n * KP + d4 * 4;
  *(bf16x4*)(row)        = hi;
  *(bf16x4*)(row + 512)  = lo;
  *(bf16x4*)(row + 1024) = hi;
}

// ---------- K2: 256x256 deep-prefetch MFMA GEMM fused with argmin ----------
// LDS per buffer: A 256x32 bf16 (16KB) + B 256x32 (16KB); 4 buffers = 128KB.
// Chunk swizzle: LDS[row][ch] holds global 16B-chunk (ch ^ ((row>>2)&3)).

__device__ __forceinline__ void stage_tile(
    const __bf16* __restrict__ xp, const __bf16* __restrict__ kp,
    int m0, int n0, int kt, __bf16* buf, int tid) {
  int row = tid >> 2;                       // 0..127
  int g   = (tid & 3) ^ ((tid >> 4) & 3);   // source chunk for slot (row, tid&3)
  size_t col = (size_t)kt * 32 + g * 8;
  __bf16* Ab = buf;            // A region: 8192 elems
  __bf16* Bb = buf + 8192;     // B region
  gl2lds16(xp + (size_t)(m0 + row) * KP + col,       (char*)Ab + tid * 16);
  gl2lds16(xp + (size_t)(m0 + 128 + row) * KP + col, (char*)Ab + 8192 + tid * 16);
  gl2lds16(kp + (size_t)(n0 + row) * KP + col,       (char*)Bb + tid * 16);
  gl2lds16(kp + (size_t)(n0 + 128 + row) * KP + col, (char*)Bb + 8192 + tid * 16);
}

__device__ __forceinline__ void compute_tile(
    const __bf16* buf, int wm, int wn, int lane, f32x4 acc[8][4]) {
  const __bf16* As = buf;
  const __bf16* Bs = buf + 8192;
  const int r15 = lane & 15;
  const int ch = (lane >> 4) ^ ((lane >> 2) & 3);  // swizzled chunk (lane-only)
  bf16x8 af[8], bb[4];
  #pragma unroll
  for (int i = 0; i < 8; ++i) {
    int row = wm + i * 16 + r15;
    af[i] = *(const bf16x8*)((const char*)As + row * 64 + ch * 16);
  }
  #pragma unroll
  for (int j = 0; j < 4; ++j) {
    int row = wn + j * 16 + r15;
    bb[j] = *(const bf16x8*)((const char*)Bs + row * 64 + ch * 16);
  }
  #pragma unroll
  for (int i = 0; i < 8; ++i)
    #pragma unroll
    for (int j = 0; j < 4; ++j)
      acc[i][j] = __builtin_amdgcn_mfma_f32_16x16x32_bf16(af[i], bb[j], acc[i][j], 0, 0, 0);
}

#define ENTRY_SYNC(N)                                             \
  asm volatile("s_waitcnt vmcnt(" #N ")" ::: "memory");           \
  __builtin_amdgcn_s_barrier();                                   \
  asm volatile("" ::: "memory");
#define EXIT_SYNC()                                               \
  asm volatile("" ::: "memory");                                  \
  __builtin_amdgcn_s_barrier();

__global__ __launch_bounds__(512, 2) void k_mfma_argmin2(
    const __bf16* __restrict__ xp, const __bf16* __restrict__ kp,
    const float* __restrict__ h, unsigned long long* __restrict__ best) {
  __shared__ __attribute__((aligned(16))) __bf16 LDS[4][16384];

  // XCD-aware swizzle over 2048 blocks (2048 % 8 == 0 -> simple form valid)
  int wg = blockIdx.y * gridDim.x + blockIdx.x;
  int swz = (wg & 7) * 256 + (wg >> 3);
  int nb = swz & 31, mb = swz >> 5;
  const int m0 = mb * 256, n0 = nb * 256;
  const int tid = threadIdx.x, lane = tid & 63, wid = tid >> 6;
  const int wm = (wid >> 2) * 128, wn = (wid & 3) * 64;

  f32x4 acc[8][4] = {};

  // prologue: stage tiles 0,1,2
  stage_tile(xp, kp, m0, n0, 0, &LDS[0][0], tid);
  stage_tile(xp, kp, m0, n0, 1, &LDS[1][0], tid);
  stage_tile(xp, kp, m0, n0, 2, &LDS[2][0], tid);

  for (int t = 0; t < NT - 3; ++t) {
    stage_tile(xp, kp, m0, n0, t + 3, &LDS[(t + 3) & 3][0], tid);
    ENTRY_SYNC(12)                       // tile t landed (t+1..t+3 = 12 in flight)
    compute_tile(&LDS[t & 3][0], wm, wn, lane, acc);
    EXIT_SYNC()
  }
  { ENTRY_SYNC(8)  compute_tile(&LDS[(NT - 3) & 3][0], wm, wn, lane, acc); EXIT_SYNC() }
  { ENTRY_SYNC(4)  compute_tile(&LDS[(NT - 2) & 3][0], wm, wn, lane, acc); EXIT_SYNC() }
  { ENTRY_SYNC(0)  compute_tile(&LDS[(NT - 1) & 3][0], wm, wn, lane, acc); }

  // epilogue: C/D layout col = lane&15, row = (lane>>4)*4 + reg
  const int rgrp = lane >> 4;
  const int cidx = lane & 15;
  #pragma unroll
  for (int i = 0; i < 8; ++i) {
    #pragma unroll
    for (int r = 0; r < 4; ++r) {
      unsigned long long m = ~0ull;
      #pragma unroll
      for (int j = 0; j < 4; ++j) {
        int kk = n0 + wn + j * 16 + cidx;
        float score = h[kk] - acc[i][j][r];
        unsigned long long cand =
            ((unsigned long long)fkey(score) << 32) | (unsigned int)kk;
        m = (cand < m) ? cand : m;
      }
      #pragma unroll
      for (int msk = 1; msk < 16; msk <<= 1) {
        unsigned long long o = __shfl_xor(m, msk);
        m = (o < m) ? o : m;
      }
      if (cidx == 0) {
        int row = m0 + wm + i * 16 + rgrp * 4 + r;
        atomicMin(&best[row], m);
      }
    }
  }
}

// ---------- fallback f32 GEMM+argmin (used only if ws too small) ----------
#define BT 128
#define BK 128
#define DC 32
__global__ __launch_bounds__(256, 2) void k_gemm_argmin(
    const float* __restrict__ x, const float* __restrict__ key_w,
    const float* __restrict__ h, unsigned long long* __restrict__ best) {
  __shared__ float4 XS[BT * 8];
  __shared__ float4 KS[BK * 8];
  const int kb = blockIdx.x, tb = blockIdx.y;
  const int t0 = tb * BT, k0 = kb * BK;
  const int tid = threadIdx.x;
  const int tx = tid & 15;
  const int tyg = tid >> 4;
  float acc[8][8];
  #pragma unroll
  for (int i = 0; i < 8; ++i)
    #pragma unroll
    for (int j = 0; j < 8; ++j) acc[i][j] = 0.f;
  for (int dc = 0; dc < N_EMBED; dc += DC) {
    __syncthreads();
    #pragma unroll
    for (int l = 0; l < 4; ++l) {
      int li = l * 256 + tid;
      int row = li >> 3, c4 = li & 7;
      XS[row * 8 + (c4 ^ (row & 7))] =
          *reinterpret_cast<const float4*>(x + (size_t)(t0 + row) * N_EMBED + dc + c4 * 4);
      KS[row * 8 + (c4 ^ (row & 7))] =
          *reinterpret_cast<const float4*>(key_w + (size_t)(k0 + row) * N_EMBED + dc + c4 * 4);
    }
    __syncthreads();
    #pragma unroll
    for (int d4 = 0; d4 < 8; ++d4) {
      float4 a[8], b[8];
      #pragma unroll
      for (int j = 0; j < 8; ++j) {
        a[j] = XS[(tyg + 16 * j) * 8 + (d4 ^ (tyg & 7))];
        b[j] = KS[(tx  + 16 * j) * 8 + (d4 ^ (tx  & 7))];
      }
      #pragma unroll
      for (int i = 0; i < 8; ++i) {
        float4 av = a[i];
        #pragma unroll
        for (int j = 0; j < 8; ++j) {
          float4 bv = b[j];
          acc[i][j] = fmaf(av.x, bv.x, fmaf(av.y, bv.y,
                      fmaf(av.z, bv.z, fmaf(av.w, bv.w, acc[i][j]))));
        }
      }
    }
  }
  #pragma unroll
  for (int i = 0; i < 8; ++i) {
    unsigned long long m = ~0ull;
    #pragma unroll
    for (int j = 0; j < 8; ++j) {
      int kk = k0 + tx + 16 * j;
      float score = h[kk] - acc[i][j];
      unsigned long long cand =
          ((unsigned long long)fkey(score) << 32) | (unsigned int)kk;
      m = (cand < m) ? cand : m;
    }
    #pragma unroll
    for (int mask = 1; mask < 16; mask <<= 1) {
      unsigned long long o = __shfl_xor(m, mask);
      m = (o < m) ? o : m;
    }
    if (tx == 0) atomicMin(&best[t0 + tyg + 16 * i], m);
  }
}

// ---------- K3: unpack index ----------
__global__ void k_extract(const unsigned long long* __restrict__ best,
                          int* __restrict__ idx) {
  int t = blockIdx.x * blockDim.x + threadIdx.x;
  if (t < T_TOKENS) idx[t] = (int)(unsigned int)(best[t] & 0xffffffffull);
}

// ---------- K4: quantized = x + value_w[idx] ----------
__global__ void k_quant(const float* __restrict__ x, const float* __restrict__ value_w,
                        const int* __restrict__ idx, float* __restrict__ q) {
  int gid = blockIdx.x * blockDim.x + threadIdx.x;
  int t = gid >> 7;
  int d4 = gid & 127;
  float4 xv = reinterpret_cast<const float4*>(x)[gid];
  float4 v = reinterpret_cast<const float4*>(value_w + (size_t)idx[t] * N_EMBED)[d4];
  float4 o;
  o.x = xv.x + v.x; o.y = xv.y + v.y; o.z = xv.z + v.z; o.w = xv.w + v.w;
  reinterpret_cast<float4*>(q)[gid] = o;
}

// ---------- K5/K6: EMA decay bases ----------
__global__ void k_scaleN(const float* __restrict__ ema_n, float* __restrict__ out_en) {
  int k = blockIdx.x * blockDim.x + threadIdx.x;
  if (k < N_TOKEN) out_en[k] = 0.99f * ema_n[k];
}
__global__ void k_scaleW(const float* __restrict__ ema_w, float* __restrict__ out_ew) {
  int gid = blockIdx.x * blockDim.x + threadIdx.x;
  float4 v = reinterpret_cast<const float4*>(ema_w)[gid];
  float4 o;
  o.x = 0.99f * v.x; o.y = 0.99f * v.y; o.z = 0.99f * v.z; o.w = 0.99f * v.w;
  reinterpret_cast<float4*>(out_ew)[gid] = o;
}

// ---------- K7: counts ----------
__global__ void k_counts(const int* __restrict__ idx, float* __restrict__ out_en) {
  int t = blockIdx.x * blockDim.x + threadIdx.x;
  if (t < T_TOKENS) {
    const float inc = (float)(1.0 - 0.99) * 0.5f;  // (1-DECAY)*ratio
    atomicAdd(&out_en[idx[t]], inc);
  }
}

// ---------- K8: segment-sum scatter ----------
__global__ void k_scatterW(const float* __restrict__ x, const int* __restrict__ idx,
                           float* __restrict__ out_ew) {
  int gid = blockIdx.x * blockDim.x + threadIdx.x;
  int t = gid >> 7;
  int d4 = gid & 127;
  float4 xv = reinterpret_cast<const float4*>(x)[gid];
  const float c = (float)(1.0 - 0.99) * 0.5f;
  float* dst = out_ew + (size_t)idx[t] * N_EMBED + d4 * 4;
  atomicAdd(dst + 0, c * xv.x);
  atomicAdd(dst + 1, c * xv.y);
  atomicAdd(dst + 2, c * xv.z);
  atomicAdd(dst + 3, c * xv.w);
}

// ---------- K9: n = sum(ema_n_new) ----------
__global__ void k_sumn(const float* __restrict__ en, float* __restrict__ nsum) {
  __shared__ float sm[256];
  float s = 0.f;
  for (int i = threadIdx.x; i < N_TOKEN; i += 256) s += en[i];
  sm[threadIdx.x] = s;
  __syncthreads();
  for (int off = 128; off; off >>= 1) {
    if (threadIdx.x < off) sm[threadIdx.x] += sm[threadIdx.x + off];
    __syncthreads();
  }
  if (threadIdx.x == 0) *nsum = sm[0];
}

// ---------- K10: key_w_new = ema_w_new / sz ----------
__global__ void k_keyw(const float* __restrict__ out_ew, const float* __restrict__ out_en,
                       const float* __restrict__ nsum, float* __restrict__ out_kw) {
  int gid = blockIdx.x * blockDim.x + threadIdx.x;
  int k = gid >> 7;
  float n = *nsum;
  float sz = (out_en[k] + 1e-8f) / (n + 1e-8f * (float)N_TOKEN) * n;
  float4 w = reinterpret_cast<const float4*>(out_ew)[gid];
  float4 o;
  o.x = w.x / sz; o.y = w.y / sz; o.z = w.z / sz; o.w = w.w / sz;
  reinterpret_cast<float4*>(out_kw)[gid] = o;
}

// ---------- launcher ----------
extern "C" void kernel_launch(void* const* d_in, const int* in_sizes, int n_in,
                              void* d_out, int out_size, void* d_ws, size_t ws_size,
                              hipStream_t stream) {
  const float* x       = (const float*)d_in[0];
  const float* key_w   = (const float*)d_in[1];
  const float* value_w = (const float*)d_in[2];
  const float* ema_n   = (const float*)d_in[3];
  const float* ema_w   = (const float*)d_in[4];

  float* out_q  = (float*)d_out;
  float* out_en = out_q + 8388608;
  float* out_ew = out_en + N_TOKEN;
  float* out_kw = out_ew + 4194304;

  unsigned long long* best = (unsigned long long*)d_ws;          // 128 KiB
  int*   idx  = (int*)((char*)d_ws + 131072);                    // 64 KiB
  float* h    = (float*)((char*)d_ws + 196608);                  // 32 KiB
  float* nsum = (float*)((char*)d_ws + 229376);                  // 4 B
  __bf16* xp  = (__bf16*)((char*)d_ws + 262144);                 // 48 MiB
  __bf16* kp  = (__bf16*)((char*)d_ws + 262144 + (size_t)T_TOKENS * KP * 2);  // 24 MiB
  const size_t ws_need = 262144 + (size_t)T_TOKENS * KP * 2 + (size_t)N_TOKEN * KP * 2;

  k_hnorm<<<N_TOKEN / 4, 256, 0, stream>>>(key_w, h);
  hipMemsetAsync(best, 0xFF, (size_t)T_TOKENS * 8, stream);

  if (ws_size >= ws_need) {
    k_pack_x<<<(T_TOKENS * (N_EMBED / 4)) / 256, 256, 0, stream>>>(x, xp);
    k_pack_k<<<(N_TOKEN * (N_EMBED / 4)) / 256, 256, 0, stream>>>(key_w, kp);
    dim3 grid(N_TOKEN / 256, T_TOKENS / 256);   // 32 x 64
    k_mfma_argmin2<<<grid, 512, 0, stream>>>(xp, kp, h, best);
  } else {
    dim3 grid(N_TOKEN / BK, T_TOKENS / BT);
    k_gemm_argmin<<<grid, 256, 0, stream>>>(x, key_w, h, best);
  }

  k_extract<<<T_TOKENS / 256, 256, 0, stream>>>(best, idx);
  k_quant<<<(T_TOKENS * (N_EMBED / 4)) / 256, 256, 0, stream>>>(x, value_w, idx, out_q);
  k_scaleN<<<N_TOKEN / 256, 256, 0, stream>>>(ema_n, out_en);
  k_scaleW<<<(N_TOKEN * (N_EMBED / 4)) / 256, 256, 0, stream>>>(ema_w, out_ew);
  k_counts<<<T_TOKENS / 256, 256, 0, stream>>>(idx, out_en);
  k_scatterW<<<(T_TOKENS * (N_EMBED / 4)) / 256, 256, 0, stream>>>(x, idx, out_ew);
  k_sumn<<<1, 256, 0, stream>>>(out_en, nsum);
  k_keyw<<<(N_TOKEN * (N_EMBED / 4)) / 256, 256, 0, stream>>>(out_ew, out_en, nsum, out_kw);
}

// Round 5
// 779.870 us; speedup vs baseline: 1.0846x; 1.0846x over previous
//
#include <hip/hip_runtime.h>

#define N_TOKEN 8192
#define N_EMBED 512
#define T_TOKENS 16384
#define KP 1536    // packed K = 3 * 512
#define KTILES 24  // KP / 64

typedef __bf16 bf16x8 __attribute__((ext_vector_type(8)));
typedef __bf16 bf16x4 __attribute__((ext_vector_type(4)));
typedef float f32x4 __attribute__((ext_vector_type(4)));

// ---------- helpers ----------
__device__ __forceinline__ unsigned int fkey(float f) {
  unsigned int u = __float_as_uint(f);
  return (u & 0x80000000u) ? ~u : (u | 0x80000000u);
}
__device__ __forceinline__ void gl2lds16(const void* gsrc, void* lds) {
  __builtin_amdgcn_global_load_lds(
      (const __attribute__((address_space(1))) unsigned int*)gsrc,
      (__attribute__((address_space(3))) unsigned int*)lds, 16, 0, 0);
}
#define BARRIER() asm volatile("s_barrier" ::: "memory")
#define VMCNT(n)  asm volatile("s_waitcnt vmcnt(" #n ")" ::: "memory")

// ---------- K1: h[k] = 0.5*||key_w[k]||^2 (f32, exact norms) ----------
__global__ void k_hnorm(const float* __restrict__ key_w, float* __restrict__ h) {
  int code = blockIdx.x * 4 + (threadIdx.x >> 6);
  int lane = threadIdx.x & 63;
  const float4* row = reinterpret_cast<const float4*>(key_w + (size_t)code * N_EMBED);
  float s = 0.f;
  float4 v0 = row[lane];
  float4 v1 = row[lane + 64];
  s += v0.x*v0.x + v0.y*v0.y + v0.z*v0.z + v0.w*v0.w;
  s += v1.x*v1.x + v1.y*v1.y + v1.z*v1.z + v1.w*v1.w;
  #pragma unroll
  for (int off = 32; off; off >>= 1) s += __shfl_down(s, off);
  if (lane == 0) h[code] = 0.5f * s;
}

// ---------- pack kernels: split f32 -> [hi|hi|lo] / [hi|lo|hi] bf16 ----------
__global__ void k_pack_x(const float* __restrict__ x, __bf16* __restrict__ xp) {
  int gid = blockIdx.x * blockDim.x + threadIdx.x;
  int t = gid >> 7, d4 = gid & 127;
  float4 v = reinterpret_cast<const float4*>(x)[gid];
  bf16x4 hi, lo;
  hi[0] = (__bf16)v.x; hi[1] = (__bf16)v.y; hi[2] = (__bf16)v.z; hi[3] = (__bf16)v.w;
  lo[0] = (__bf16)(v.x - (float)hi[0]);
  lo[1] = (__bf16)(v.y - (float)hi[1]);
  lo[2] = (__bf16)(v.z - (float)hi[2]);
  lo[3] = (__bf16)(v.w - (float)hi[3]);
  __bf16* row = xp + (size_t)t * KP + d4 * 4;
  *(bf16x4*)(row)        = hi;
  *(bf16x4*)(row + 512)  = hi;
  *(bf16x4*)(row + 1024) = lo;
}

__global__ void k_pack_k(const float* __restrict__ kw, __bf16* __restrict__ kp) {
  int gid = blockIdx.x * blockDim.x + threadIdx.x;
  int n = gid >> 7, d4 = gid & 127;
  float4 v = reinterpret_cast<const float4*>(kw)[gid];
  bf16x4 hi, lo;
  hi[0] = (__bf16)v.x; hi[1] = (__bf16)v.y; hi[2] = (__bf16)v.z; hi[3] = (__bf16)v.w;
  lo[0] = (__bf16)(v.x - (float)hi[0]);
  lo[1] = (__bf16)(v.y - (float)hi[1]);
  lo[2] = (__bf16)(v.z - (float)hi[2]);
  lo[3] = (__bf16)(v.w - (float)hi[3]);
  __bf16* row = kp + (size_t)n * KP + d4 * 4;
  *(bf16x4*)(row)        = hi;
  *(bf16x4*)(row + 512)  = lo;
  *(bf16x4*)(row + 1024) = hi;
}

// ---------- K2: 256x256 4-phase interleaved MFMA GEMM + fused argmin ----------
// LDS: 2 K-tile buffers, each A[256x64]+B[256x64] bf16 = 64KB; total 128KB.
// A-LDS chunk q (64 rows): rows 0-31 = global m0+32q+[0,32), rows 32-63 =
// global m0+128+32q+[0,32)  (both wave-groups' phase-q rows -> freed after
// phase q). B-LDS plain: row r = global n0+r (all read at phase 0).
// Byte swizzle both sides: col ^ ((row&7)<<4)  (R3-proven, 0 conflicts).
// Schedule per tile t (buf p=t&1), phase q: {ds_read af-pair q (+bb @q0);
// [gate @q3]; barrier; 16 MFMA; barrier; stage chunk q of tile t+2 into buf p}.
// Gates: vmcnt(8) after prologue; vmcnt(6) at (t,3) t<22; vmcnt(0) at t>=22.

#define MFMA __builtin_amdgcn_mfma_f32_16x16x32_bf16

#define STAGE(p, q, kt) do {                                                      \
    gl2lds16(sA##q + (size_t)(kt) * 64, (char*)&LDS[p][0]     + (q)*8192 + soff); \
    gl2lds16(sB##q + (size_t)(kt) * 64, (char*)&LDS[p][16384] + (q)*8192 + soff); \
  } while (0)

#define MROW(i, ak0, ak1)                                                   \
    acc[i][0] = MFMA(ak0, b00, acc[i][0], 0,0,0);                           \
    acc[i][0] = MFMA(ak1, b01, acc[i][0], 0,0,0);                           \
    acc[i][1] = MFMA(ak0, b10, acc[i][1], 0,0,0);                           \
    acc[i][1] = MFMA(ak1, b11, acc[i][1], 0,0,0);                           \
    acc[i][2] = MFMA(ak0, b20, acc[i][2], 0,0,0);                           \
    acc[i][2] = MFMA(ak1, b21, acc[i][2], 0,0,0);                           \
    acc[i][3] = MFMA(ak0, b30, acc[i][3], 0,0,0);                           \
    acc[i][3] = MFMA(ak1, b31, acc[i][3], 0,0,0);

#define PHASE(q, GATEQ)                                                     \
  {                                                                         \
    const char* Ab = (const char*)&LDS[p][0];                               \
    const int R0 = ((q)*64 + 32*g + r15) * 128;                             \
    bf16x8 a00 = *(const bf16x8*)(Ab + R0 + (cb0 ^ sw));                    \
    bf16x8 a01 = *(const bf16x8*)(Ab + R0 + (cb1 ^ sw));                    \
    bf16x8 a10 = *(const bf16x8*)(Ab + R0 + 2048 + (cb0 ^ sw));             \
    bf16x8 a11 = *(const bf16x8*)(Ab + R0 + 2048 + (cb1 ^ sw));             \
    if ((q) == 0) {                                                         \
      const char* Bb = (const char*)&LDS[p][16384];                         \
      const int Rb = (64*nw + r15) * 128;                                   \
      b00 = *(const bf16x8*)(Bb + Rb +        (cb0 ^ sw));                  \
      b01 = *(const bf16x8*)(Bb + Rb +        (cb1 ^ sw));                  \
      b10 = *(const bf16x8*)(Bb + Rb + 2048 + (cb0 ^ sw));                  \
      b11 = *(const bf16x8*)(Bb + Rb + 2048 + (cb1 ^ sw));                  \
      b20 = *(const bf16x8*)(Bb + Rb + 4096 + (cb0 ^ sw));                  \
      b21 = *(const bf16x8*)(Bb + Rb + 4096 + (cb1 ^ sw));                  \
      b30 = *(const bf16x8*)(Bb + Rb + 6144 + (cb0 ^ sw));                  \
      b31 = *(const bf16x8*)(Bb + Rb + 6144 + (cb1 ^ sw));                  \
    }                                                                       \
    GATEQ;                                                                  \
    BARRIER();                                                              \
    __builtin_amdgcn_s_setprio(1);                                          \
    MROW(2*(q),   a00, a01)                                                 \
    MROW(2*(q)+1, a10, a11)                                                 \
    __builtin_amdgcn_s_setprio(0);                                          \
    BARRIER();                                                              \
    if (stg) STAGE(p, q, kt2);                                              \
  }

__global__ __launch_bounds__(512, 1) void k_mfma8(
    const __bf16* __restrict__ xp, const __bf16* __restrict__ kp,
    const float* __restrict__ h, unsigned long long* __restrict__ best) {
  __shared__ __attribute__((aligned(16))) __bf16 LDS[2][32768];

  // XCD-aware swizzle over 2048 blocks (2048 % 8 == 0 -> simple form valid)
  const int wg = blockIdx.x;
  const int swz = (wg & 7) * 256 + (wg >> 3);
  const int nb = swz & 31, mb = swz >> 5;
  const int m0 = mb * 256, n0 = nb * 256;
  const int tid = threadIdx.x, lane = tid & 63, wid = tid >> 6;
  const int g  = wid >> 2;          // m-group: wm = 128*g
  const int nw = wid & 3;           // n-group: wn = 64*nw
  const int r15 = lane & 15, q4 = lane >> 4;
  const int sw  = (r15 & 7) << 4;
  const int cb0 = q4 * 16;          // kk=0 column byte
  const int cb1 = 64 + q4 * 16;     // kk=1

  // per-thread staging constants (source pre-swizzled to match read XOR)
  const int l = tid >> 3;                        // LDS row within chunk
  const int soff = tid * 16;                     // linear LDS byte offset
  const int sc = ((tid & 7) * 16) ^ ((l & 7) << 4);
  const __bf16* sA0 = xp + (size_t)(m0 + (l >> 5) * 128 +  0 + (l & 31)) * KP + (sc >> 1);
  const __bf16* sA1 = xp + (size_t)(m0 + (l >> 5) * 128 + 32 + (l & 31)) * KP + (sc >> 1);
  const __bf16* sA2 = xp + (size_t)(m0 + (l >> 5) * 128 + 64 + (l & 31)) * KP + (sc >> 1);
  const __bf16* sA3 = xp + (size_t)(m0 + (l >> 5) * 128 + 96 + (l & 31)) * KP + (sc >> 1);
  const __bf16* sB0 = kp + (size_t)(n0 +   0 + l) * KP + (sc >> 1);
  const __bf16* sB1 = kp + (size_t)(n0 +  64 + l) * KP + (sc >> 1);
  const __bf16* sB2 = kp + (size_t)(n0 + 128 + l) * KP + (sc >> 1);
  const __bf16* sB3 = kp + (size_t)(n0 + 192 + l) * KP + (sc >> 1);

  f32x4 acc[8][4] = {};
  bf16x8 b00, b01, b10, b11, b20, b21, b30, b31;

  // prologue: tiles 0 and 1 fully staged (16 loads/wave)
  STAGE(0, 0, 0); STAGE(0, 1, 0); STAGE(0, 2, 0); STAGE(0, 3, 0);
  STAGE(1, 0, 1); STAGE(1, 1, 1); STAGE(1, 2, 1); STAGE(1, 3, 1);
  VMCNT(8);       // tile 0 landed; tile 1's 8 may stay in flight
  BARRIER();

  #pragma unroll 1
  for (int t = 0; t < KTILES; ++t) {
    const int p = t & 1;
    const bool stg = (t + 2 < KTILES);
    const int kt2 = t + 2;
    PHASE(0, (void)0)
    PHASE(1, (void)0)
    PHASE(2, (void)0)
    PHASE(3, if (t < 22) { VMCNT(6); } else { VMCNT(0); })
  }

  // epilogue: C/D layout col = lane&15, row = (lane>>4)*4 + reg
  const int wm = 128 * g, wn = 64 * nw;
  const int rgrp = lane >> 4;
  const int cidx = lane & 15;
  #pragma unroll
  for (int i = 0; i < 8; ++i) {
    #pragma unroll
    for (int r = 0; r < 4; ++r) {
      unsigned long long m = ~0ull;
      #pragma unroll
      for (int j = 0; j < 4; ++j) {
        int kk = n0 + wn + j * 16 + cidx;
        float score = h[kk] - acc[i][j][r];
        unsigned long long cand =
            ((unsigned long long)fkey(score) << 32) | (unsigned int)kk;
        m = (cand < m) ? cand : m;
      }
      #pragma unroll
      for (int msk = 1; msk < 16; msk <<= 1) {
        unsigned long long o = __shfl_xor(m, msk);
        m = (o < m) ? o : m;
      }
      if (cidx == 0) {
        int row = m0 + wm + i * 16 + rgrp * 4 + r;
        atomicMin(&best[row], m);
      }
    }
  }
}

// ---------- fallback f32 GEMM+argmin (used only if ws too small) ----------
#define BT 128
#define BK 128
#define DC 32
__global__ __launch_bounds__(256, 2) void k_gemm_argmin(
    const float* __restrict__ x, const float* __restrict__ key_w,
    const float* __restrict__ h, unsigned long long* __restrict__ best) {
  __shared__ float4 XS[BT * 8];
  __shared__ float4 KS[BK * 8];
  const int kb = blockIdx.x, tb = blockIdx.y;
  const int t0 = tb * BT, k0 = kb * BK;
  const int tid = threadIdx.x;
  const int tx = tid & 15;
  const int tyg = tid >> 4;
  float acc[8][8];
  #pragma unroll
  for (int i = 0; i < 8; ++i)
    #pragma unroll
    for (int j = 0; j < 8; ++j) acc[i][j] = 0.f;
  for (int dc = 0; dc < N_EMBED; dc += DC) {
    __syncthreads();
    #pragma unroll
    for (int ld = 0; ld < 4; ++ld) {
      int li = ld * 256 + tid;
      int row = li >> 3, c4 = li & 7;
      XS[row * 8 + (c4 ^ (row & 7))] =
          *reinterpret_cast<const float4*>(x + (size_t)(t0 + row) * N_EMBED + dc + c4 * 4);
      KS[row * 8 + (c4 ^ (row & 7))] =
          *reinterpret_cast<const float4*>(key_w + (size_t)(k0 + row) * N_EMBED + dc + c4 * 4);
    }
    __syncthreads();
    #pragma unroll
    for (int d4 = 0; d4 < 8; ++d4) {
      float4 a[8], b[8];
      #pragma unroll
      for (int j = 0; j < 8; ++j) {
        a[j] = XS[(tyg + 16 * j) * 8 + (d4 ^ (tyg & 7))];
        b[j] = KS[(tx  + 16 * j) * 8 + (d4 ^ (tx  & 7))];
      }
      #pragma unroll
      for (int i = 0; i < 8; ++i) {
        float4 av = a[i];
        #pragma unroll
        for (int j = 0; j < 8; ++j) {
          float4 bv = b[j];
          acc[i][j] = fmaf(av.x, bv.x, fmaf(av.y, bv.y,
                      fmaf(av.z, bv.z, fmaf(av.w, bv.w, acc[i][j]))));
        }
      }
    }
  }
  #pragma unroll
  for (int i = 0; i < 8; ++i) {
    unsigned long long m = ~0ull;
    #pragma unroll
    for (int j = 0; j < 8; ++j) {
      int kk = k0 + tx + 16 * j;
      float score = h[kk] - acc[i][j];
      unsigned long long cand =
          ((unsigned long long)fkey(score) << 32) | (unsigned int)kk;
      m = (cand < m) ? cand : m;
    }
    #pragma unroll
    for (int mask = 1; mask < 16; mask <<= 1) {
      unsigned long long o = __shfl_xor(m, mask);
      m = (o < m) ? o : m;
    }
    if (tx == 0) atomicMin(&best[t0 + tyg + 16 * i], m);
  }
}

// ---------- K3: unpack index + counts (fused; after scaleN) ----------
__global__ void k_extract_counts(const unsigned long long* __restrict__ best,
                                 int* __restrict__ idx, float* __restrict__ out_en) {
  int t = blockIdx.x * blockDim.x + threadIdx.x;
  if (t < T_TOKENS) {
    int k = (int)(unsigned int)(best[t] & 0xffffffffull);
    idx[t] = k;
    atomicAdd(&out_en[k], 0.005f);  // (1-DECAY)*ratio
  }
}

// ---------- K4: quantized + segment scatter (fused; after scaleW) ----------
__global__ void k_quant_scatter(const float* __restrict__ x,
                                const float* __restrict__ value_w,
                                const int* __restrict__ idx,
                                float* __restrict__ q, float* __restrict__ out_ew) {
  int gid = blockIdx.x * blockDim.x + threadIdx.x;
  int t = gid >> 7, d4 = gid & 127;
  float4 xv = reinterpret_cast<const float4*>(x)[gid];
  int k = idx[t];
  float4 v = reinterpret_cast<const float4*>(value_w + (size_t)k * N_EMBED)[d4];
  float4 o;
  o.x = xv.x + v.x; o.y = xv.y + v.y; o.z = xv.z + v.z; o.w = xv.w + v.w;
  reinterpret_cast<float4*>(q)[gid] = o;
  const float c = 0.005f;  // (1-DECAY)*ratio
  float* dst = out_ew + (size_t)k * N_EMBED + d4 * 4;
  atomicAdd(dst + 0, c * xv.x);
  atomicAdd(dst + 1, c * xv.y);
  atomicAdd(dst + 2, c * xv.z);
  atomicAdd(dst + 3, c * xv.w);
}

// ---------- K5/K6: EMA decay bases ----------
__global__ void k_scaleN(const float* __restrict__ ema_n, float* __restrict__ out_en) {
  int k = blockIdx.x * blockDim.x + threadIdx.x;
  if (k < N_TOKEN) out_en[k] = 0.99f * ema_n[k];
}
__global__ void k_scaleW(const float* __restrict__ ema_w, float* __restrict__ out_ew) {
  int gid = blockIdx.x * blockDim.x + threadIdx.x;
  float4 v = reinterpret_cast<const float4*>(ema_w)[gid];
  float4 o;
  o.x = 0.99f * v.x; o.y = 0.99f * v.y; o.z = 0.99f * v.z; o.w = 0.99f * v.w;
  reinterpret_cast<float4*>(out_ew)[gid] = o;
}

// ---------- K9: n = sum(ema_n_new) ----------
__global__ void k_sumn(const float* __restrict__ en, float* __restrict__ nsum) {
  __shared__ float sm[256];
  float s = 0.f;
  for (int i = threadIdx.x; i < N_TOKEN; i += 256) s += en[i];
  sm[threadIdx.x] = s;
  __syncthreads();
  for (int off = 128; off; off >>= 1) {
    if (threadIdx.x < off) sm[threadIdx.x] += sm[threadIdx.x + off];
    __syncthreads();
  }
  if (threadIdx.x == 0) *nsum = sm[0];
}

// ---------- K10: key_w_new = ema_w_new / sz ----------
__global__ void k_keyw(const float* __restrict__ out_ew, const float* __restrict__ out_en,
                       const float* __restrict__ nsum, float* __restrict__ out_kw) {
  int gid = blockIdx.x * blockDim.x + threadIdx.x;
  int k = gid >> 7;
  float n = *nsum;
  float sz = (out_en[k] + 1e-8f) / (n + 1e-8f * (float)N_TOKEN) * n;
  float4 w = reinterpret_cast<const float4*>(out_ew)[gid];
  float4 o;
  o.x = w.x / sz; o.y = w.y / sz; o.z = w.z / sz; o.w = w.w / sz;
  reinterpret_cast<float4*>(out_kw)[gid] = o;
}

// ---------- launcher ----------
extern "C" void kernel_launch(void* const* d_in, const int* in_sizes, int n_in,
                              void* d_out, int out_size, void* d_ws, size_t ws_size,
                              hipStream_t stream) {
  const float* x       = (const float*)d_in[0];
  const float* key_w   = (const float*)d_in[1];
  const float* value_w = (const float*)d_in[2];
  const float* ema_n   = (const float*)d_in[3];
  const float* ema_w   = (const float*)d_in[4];

  float* out_q  = (float*)d_out;
  float* out_en = out_q + 8388608;
  float* out_ew = out_en + N_TOKEN;
  float* out_kw = out_ew + 4194304;

  unsigned long long* best = (unsigned long long*)d_ws;          // 128 KiB
  int*   idx  = (int*)((char*)d_ws + 131072);                    // 64 KiB
  float* h    = (float*)((char*)d_ws + 196608);                  // 32 KiB
  float* nsum = (float*)((char*)d_ws + 229376);                  // 4 B
  __bf16* xp  = (__bf16*)((char*)d_ws + 262144);                 // 48 MiB
  __bf16* kp  = (__bf16*)((char*)d_ws + 262144 + (size_t)T_TOKENS * KP * 2);  // 24 MiB
  const size_t ws_need = 262144 + (size_t)T_TOKENS * KP * 2 + (size_t)N_TOKEN * KP * 2;

  k_hnorm<<<N_TOKEN / 4, 256, 0, stream>>>(key_w, h);
  hipMemsetAsync(best, 0xFF, (size_t)T_TOKENS * 8, stream);

  if (ws_size >= ws_need) {
    k_pack_x<<<(T_TOKENS * (N_EMBED / 4)) / 256, 256, 0, stream>>>(x, xp);
    k_pack_k<<<(N_TOKEN * (N_EMBED / 4)) / 256, 256, 0, stream>>>(key_w, kp);
    k_mfma8<<<2048, 512, 0, stream>>>(xp, kp, h, best);
  } else {
    dim3 grid(N_TOKEN / BK, T_TOKENS / BT);
    k_gemm_argmin<<<grid, 256, 0, stream>>>(x, key_w, h, best);
  }

  k_scaleN<<<N_TOKEN / 256, 256, 0, stream>>>(ema_n, out_en);
  k_extract_counts<<<T_TOKENS / 256, 256, 0, stream>>>(best, idx, out_en);
  k_scaleW<<<(N_TOKEN * (N_EMBED / 4)) / 256, 256, 0, stream>>>(ema_w, out_ew);
  k_quant_scatter<<<(T_TOKENS * (N_EMBED / 4)) / 256, 256, 0, stream>>>(
      x, value_w, idx, out_q, out_ew);
  k_sumn<<<1, 256, 0, stream>>>(out_en, nsum);
  k_keyw<<<(N_TOKEN * (N_EMBED / 4)) / 256, 256, 0, stream>>>(out_ew, out_en, nsum, out_kw);
}

// Round 6
// 666.783 us; speedup vs baseline: 1.2686x; 1.1696x over previous
//
#include <hip/hip_runtime.h>

#define N_TOKEN 8192
#define N_EMBED 512
#define T_TOKENS 16384
#define KP 1536   // packed K = 3 * 512

typedef __bf16 bf16x8 __attribute__((ext_vector_type(8)));
typedef __bf16 bf16x4 __attribute__((ext_vector_type(4)));
typedef float f32x4 __attribute__((ext_vector_type(4)));

// ---------- helpers ----------
__device__ __forceinline__ unsigned int fkey(float f) {
  unsigned int u = __float_as_uint(f);
  return (u & 0x80000000u) ? ~u : (u | 0x80000000u);
}
__device__ __forceinline__ void gl2lds16(const void* gsrc, void* lds) {
  __builtin_amdgcn_global_load_lds(
      (const __attribute__((address_space(1))) unsigned int*)gsrc,
      (__attribute__((address_space(3))) unsigned int*)lds, 16, 0, 0);
}

// ---------- pack x: f32 -> [hi|hi|lo] bf16 ----------
__global__ void k_pack_x(const float* __restrict__ x, __bf16* __restrict__ xp) {
  int gid = blockIdx.x * blockDim.x + threadIdx.x;  // float4 index
  int t = gid >> 7, d4 = gid & 127;
  float4 v = reinterpret_cast<const float4*>(x)[gid];
  bf16x4 hi, lo;
  hi[0] = (__bf16)v.x; hi[1] = (__bf16)v.y; hi[2] = (__bf16)v.z; hi[3] = (__bf16)v.w;
  lo[0] = (__bf16)(v.x - (float)hi[0]);
  lo[1] = (__bf16)(v.y - (float)hi[1]);
  lo[2] = (__bf16)(v.z - (float)hi[2]);
  lo[3] = (__bf16)(v.w - (float)hi[3]);
  __bf16* row = xp + (size_t)t * KP + d4 * 4;
  *(bf16x4*)(row)        = hi;
  *(bf16x4*)(row + 512)  = hi;
  *(bf16x4*)(row + 1024) = lo;
}

// ---------- pack key + norm (fused): kp = [hi|lo|hi], h = 0.5*||k||^2 ----------
__global__ void k_pack_k_norm(const float* __restrict__ kw, __bf16* __restrict__ kp,
                              float* __restrict__ h) {
  int row = blockIdx.x * 4 + (threadIdx.x >> 6);
  int lane = threadIdx.x & 63;
  const float4* src = reinterpret_cast<const float4*>(kw + (size_t)row * N_EMBED);
  __bf16* dst = kp + (size_t)row * KP;
  float s = 0.f;
  #pragma unroll
  for (int c = 0; c < 2; ++c) {
    int f4 = lane + c * 64;  // 0..127
    float4 v = src[f4];
    s += v.x*v.x + v.y*v.y + v.z*v.z + v.w*v.w;
    bf16x4 hi, lo;
    hi[0] = (__bf16)v.x; hi[1] = (__bf16)v.y; hi[2] = (__bf16)v.z; hi[3] = (__bf16)v.w;
    lo[0] = (__bf16)(v.x - (float)hi[0]);
    lo[1] = (__bf16)(v.y - (float)hi[1]);
    lo[2] = (__bf16)(v.z - (float)hi[2]);
    lo[3] = (__bf16)(v.w - (float)hi[3]);
    *(bf16x4*)(dst + f4 * 4)        = hi;
    *(bf16x4*)(dst + 512 + f4 * 4)  = lo;
    *(bf16x4*)(dst + 1024 + f4 * 4) = hi;
  }
  #pragma unroll
  for (int off = 32; off; off >>= 1) s += __shfl_down(s, off);
  if (lane == 0) h[row] = 0.5f * s;
}

// ---------- K2-MFMA: bf16 MFMA GEMM (xp . kp^T) fused with argmin ----------
// EXACT R3 structure (proven 512us / 805 TF / 0 bank conflicts on this problem).
#define BMr 128
#define BNr 128
#define BKe 64   // bf16 elements per K-step (128 B per row)

__global__ __launch_bounds__(256) void k_mfma_argmin(
    const __bf16* __restrict__ xp, const __bf16* __restrict__ kp,
    const float* __restrict__ h, unsigned long long* __restrict__ best) {
  __shared__ __bf16 AS[BMr * BKe];  // 16 KB, XOR-swizzled content
  __shared__ __bf16 BS[BNr * BKe];  // 16 KB

  const int nb = blockIdx.x, mb = blockIdx.y;
  const int m0 = mb * BMr, n0 = nb * BNr;
  const int tid = threadIdx.x;
  const int lane = tid & 63;
  const int wid = tid >> 6;
  const int wm = (wid >> 1) * 64, wn = (wid & 1) * 64;

  f32x4 acc[4][4] = {};

  const int soff = tid * 16;

  for (int ks = 0; ks < KP; ks += BKe) {
    __syncthreads();  // previous iteration's ds_reads done before overwrite
    #pragma unroll
    for (int i = 0; i < 4; ++i) {
      int off = i * 4096 + soff;
      int row = off >> 7;
      int inner = (off & 127) ^ ((row & 7) << 4);
      gl2lds16(xp + (size_t)(m0 + row) * KP + ks + (inner >> 1), (char*)AS + off);
      gl2lds16(kp + (size_t)(n0 + row) * KP + ks + (inner >> 1), (char*)BS + off);
    }
    asm volatile("s_waitcnt vmcnt(0)" ::: "memory");
    __syncthreads();  // tile visible to all waves

    #pragma unroll
    for (int kk = 0; kk < 2; ++kk) {
      const int cbyte = kk * 64 + (lane >> 4) * 16;  // k-slice byte offset in row
      bf16x8 af[4], bb[4];
      #pragma unroll
      for (int i = 0; i < 4; ++i) {
        int arow = wm + i * 16 + (lane & 15);
        af[i] = *(const bf16x8*)((const char*)AS + arow * 128 + (cbyte ^ ((arow & 7) << 4)));
        int brow = wn + i * 16 + (lane & 15);
        bb[i] = *(const bf16x8*)((const char*)BS + brow * 128 + (cbyte ^ ((brow & 7) << 4)));
      }
      #pragma unroll
      for (int i = 0; i < 4; ++i)
        #pragma unroll
        for (int j = 0; j < 4; ++j)
          acc[i][j] = __builtin_amdgcn_mfma_f32_16x16x32_bf16(af[i], bb[j], acc[i][j], 0, 0, 0);
    }
  }

  // epilogue: C/D layout col = lane&15, row = (lane>>4)*4 + reg
  const int rgrp = lane >> 4;
  const int cidx = lane & 15;
  #pragma unroll
  for (int i = 0; i < 4; ++i) {
    #pragma unroll
    for (int r = 0; r < 4; ++r) {
      unsigned long long m = ~0ull;
      #pragma unroll
      for (int j = 0; j < 4; ++j) {
        int kk = n0 + wn + j * 16 + cidx;
        float score = h[kk] - acc[i][j][r];
        unsigned long long cand =
            ((unsigned long long)fkey(score) << 32) | (unsigned int)kk;
        m = (cand < m) ? cand : m;
      }
      #pragma unroll
      for (int msk = 1; msk < 16; msk <<= 1) {
        unsigned long long o = __shfl_xor(m, msk);
        m = (o < m) ? o : m;
      }
      if (cidx == 0) {
        int row = m0 + wm + i * 16 + rgrp * 4 + r;
        atomicMin(&best[row], m);
      }
    }
  }
}

// ---------- fallback f32 GEMM+argmin (used only if ws too small) ----------
#define BT 128
#define BK 128
#define DC 32
__global__ __launch_bounds__(256, 2) void k_gemm_argmin(
    const float* __restrict__ x, const float* __restrict__ key_w,
    const float* __restrict__ h, unsigned long long* __restrict__ best) {
  __shared__ float4 XS[BT * 8];
  __shared__ float4 KS[BK * 8];
  const int kb = blockIdx.x, tb = blockIdx.y;
  const int t0 = tb * BT, k0 = kb * BK;
  const int tid = threadIdx.x;
  const int tx = tid & 15;
  const int tyg = tid >> 4;
  float acc[8][8];
  #pragma unroll
  for (int i = 0; i < 8; ++i)
    #pragma unroll
    for (int j = 0; j < 8; ++j) acc[i][j] = 0.f;
  for (int dc = 0; dc < N_EMBED; dc += DC) {
    __syncthreads();
    #pragma unroll
    for (int ld = 0; ld < 4; ++ld) {
      int li = ld * 256 + tid;
      int row = li >> 3, c4 = li & 7;
      XS[row * 8 + (c4 ^ (row & 7))] =
          *reinterpret_cast<const float4*>(x + (size_t)(t0 + row) * N_EMBED + dc + c4 * 4);
      KS[row * 8 + (c4 ^ (row & 7))] =
          *reinterpret_cast<const float4*>(key_w + (size_t)(k0 + row) * N_EMBED + dc + c4 * 4);
    }
    __syncthreads();
    #pragma unroll
    for (int d4 = 0; d4 < 8; ++d4) {
      float4 a[8], b[8];
      #pragma unroll
      for (int j = 0; j < 8; ++j) {
        a[j] = XS[(tyg + 16 * j) * 8 + (d4 ^ (tyg & 7))];
        b[j] = KS[(tx  + 16 * j) * 8 + (d4 ^ (tx  & 7))];
      }
      #pragma unroll
      for (int i = 0; i < 8; ++i) {
        float4 av = a[i];
        #pragma unroll
        for (int j = 0; j < 8; ++j) {
          float4 bv = b[j];
          acc[i][j] = fmaf(av.x, bv.x, fmaf(av.y, bv.y,
                      fmaf(av.z, bv.z, fmaf(av.w, bv.w, acc[i][j]))));
        }
      }
    }
  }
  #pragma unroll
  for (int i = 0; i < 8; ++i) {
    unsigned long long m = ~0ull;
    #pragma unroll
    for (int j = 0; j < 8; ++j) {
      int kk = k0 + tx + 16 * j;
      float score = h[kk] - acc[i][j];
      unsigned long long cand =
          ((unsigned long long)fkey(score) << 32) | (unsigned int)kk;
      m = (cand < m) ? cand : m;
    }
    #pragma unroll
    for (int mask = 1; mask < 16; mask <<= 1) {
      unsigned long long o = __shfl_xor(m, mask);
      m = (o < m) ? o : m;
    }
    if (tx == 0) atomicMin(&best[t0 + tyg + 16 * i], m);
  }
}

// ---------- K3: unpack index + counts (fused; after scaleN) ----------
__global__ void k_extract_counts(const unsigned long long* __restrict__ best,
                                 int* __restrict__ idx, float* __restrict__ out_en) {
  int t = blockIdx.x * blockDim.x + threadIdx.x;
  if (t < T_TOKENS) {
    int k = (int)(unsigned int)(best[t] & 0xffffffffull);
    idx[t] = k;
    atomicAdd(&out_en[k], 0.005f);  // (1-DECAY)*ratio
  }
}

// ---------- K4: quantized + segment scatter (fused; after scaleW) ----------
__global__ void k_quant_scatter(const float* __restrict__ x,
                                const float* __restrict__ value_w,
                                const int* __restrict__ idx,
                                float* __restrict__ q, float* __restrict__ out_ew) {
  int gid = blockIdx.x * blockDim.x + threadIdx.x;
  int t = gid >> 7, d4 = gid & 127;
  float4 xv = reinterpret_cast<const float4*>(x)[gid];
  int k = idx[t];
  float4 v = reinterpret_cast<const float4*>(value_w + (size_t)k * N_EMBED)[d4];
  float4 o;
  o.x = xv.x + v.x; o.y = xv.y + v.y; o.z = xv.z + v.z; o.w = xv.w + v.w;
  reinterpret_cast<float4*>(q)[gid] = o;
  const float c = 0.005f;  // (1-DECAY)*ratio
  float* dst = out_ew + (size_t)k * N_EMBED + d4 * 4;
  atomicAdd(dst + 0, c * xv.x);
  atomicAdd(dst + 1, c * xv.y);
  atomicAdd(dst + 2, c * xv.z);
  atomicAdd(dst + 3, c * xv.w);
}

// ---------- K5/K6: EMA decay bases ----------
__global__ void k_scaleN(const float* __restrict__ ema_n, float* __restrict__ out_en) {
  int k = blockIdx.x * blockDim.x + threadIdx.x;
  if (k < N_TOKEN) out_en[k] = 0.99f * ema_n[k];
}
__global__ void k_scaleW(const float* __restrict__ ema_w, float* __restrict__ out_ew) {
  int gid = blockIdx.x * blockDim.x + threadIdx.x;
  float4 v = reinterpret_cast<const float4*>(ema_w)[gid];
  float4 o;
  o.x = 0.99f * v.x; o.y = 0.99f * v.y; o.z = 0.99f * v.z; o.w = 0.99f * v.w;
  reinterpret_cast<float4*>(out_ew)[gid] = o;
}

// ---------- K9: n = sum(ema_n_new) ----------
__global__ void k_sumn(const float* __restrict__ en, float* __restrict__ nsum) {
  __shared__ float sm[256];
  float s = 0.f;
  for (int i = threadIdx.x; i < N_TOKEN; i += 256) s += en[i];
  sm[threadIdx.x] = s;
  __syncthreads();
  for (int off = 128; off; off >>= 1) {
    if (threadIdx.x < off) sm[threadIdx.x] += sm[threadIdx.x + off];
    __syncthreads();
  }
  if (threadIdx.x == 0) *nsum = sm[0];
}

// ---------- K10: key_w_new = ema_w_new / sz ----------
__global__ void k_keyw(const float* __restrict__ out_ew, const float* __restrict__ out_en,
                       const float* __restrict__ nsum, float* __restrict__ out_kw) {
  int gid = blockIdx.x * blockDim.x + threadIdx.x;
  int k = gid >> 7;
  float n = *nsum;
  float sz = (out_en[k] + 1e-8f) / (n + 1e-8f * (float)N_TOKEN) * n;
  float4 w = reinterpret_cast<const float4*>(out_ew)[gid];
  float4 o;
  o.x = w.x / sz; o.y = w.y / sz; o.z = w.z / sz; o.w = w.w / sz;
  reinterpret_cast<float4*>(out_kw)[gid] = o;
}

// ---------- launcher ----------
extern "C" void kernel_launch(void* const* d_in, const int* in_sizes, int n_in,
                              void* d_out, int out_size, void* d_ws, size_t ws_size,
                              hipStream_t stream) {
  const float* x       = (const float*)d_in[0];
  const float* key_w   = (const float*)d_in[1];
  const float* value_w = (const float*)d_in[2];
  const float* ema_n   = (const float*)d_in[3];
  const float* ema_w   = (const float*)d_in[4];

  float* out_q  = (float*)d_out;
  float* out_en = out_q + 8388608;
  float* out_ew = out_en + N_TOKEN;
  float* out_kw = out_ew + 4194304;

  unsigned long long* best = (unsigned long long*)d_ws;          // 128 KiB
  int*   idx  = (int*)((char*)d_ws + 131072);                    // 64 KiB
  float* h    = (float*)((char*)d_ws + 196608);                  // 32 KiB
  float* nsum = (float*)((char*)d_ws + 229376);                  // 4 B
  __bf16* xp  = (__bf16*)((char*)d_ws + 262144);                 // 48 MiB
  __bf16* kp  = (__bf16*)((char*)d_ws + 262144 + (size_t)T_TOKENS * KP * 2);  // 24 MiB
  const size_t ws_need = 262144 + (size_t)T_TOKENS * KP * 2 + (size_t)N_TOKEN * KP * 2;

  hipMemsetAsync(best, 0xFF, (size_t)T_TOKENS * 8, stream);

  if (ws_size >= ws_need) {
    k_pack_x<<<(T_TOKENS * (N_EMBED / 4)) / 256, 256, 0, stream>>>(x, xp);
    k_pack_k_norm<<<N_TOKEN / 4, 256, 0, stream>>>(key_w, kp, h);
    dim3 grid(N_TOKEN / BNr, T_TOKENS / BMr);
    k_mfma_argmin<<<grid, 256, 0, stream>>>(xp, kp, h, best);
  } else {
    // fallback: compute h via pack_k_norm would need ws; do a tiny norm pass into h
    k_pack_k_norm<<<N_TOKEN / 4, 256, 0, stream>>>(key_w, kp, h);  // kp fits? if not, still writes h region guarded by ws check above
    dim3 grid(N_TOKEN / BK, T_TOKENS / BT);
    k_gemm_argmin<<<grid, 256, 0, stream>>>(x, key_w, h, best);
  }

  k_scaleN<<<N_TOKEN / 256, 256, 0, stream>>>(ema_n, out_en);
  k_extract_counts<<<T_TOKENS / 256, 256, 0, stream>>>(best, idx, out_en);
  k_scaleW<<<(N_TOKEN * (N_EMBED / 4)) / 256, 256, 0, stream>>>(ema_w, out_ew);
  k_quant_scatter<<<(T_TOKENS * (N_EMBED / 4)) / 256, 256, 0, stream>>>(
      x, value_w, idx, out_q, out_ew);
  k_sumn<<<1, 256, 0, stream>>>(out_en, nsum);
  k_keyw<<<(N_TOKEN * (N_EMBED / 4)) / 256, 256, 0, stream>>>(out_ew, out_en, nsum, out_kw);
}

// Round 7
// 529.701 us; speedup vs baseline: 1.5969x; 1.2588x over previous
//
#include <hip/hip_runtime.h>

#define N_TOKEN 8192
#define N_EMBED 512
#define T_TOKENS 16384
#define KP 1536       // packed K = 3 * 512
#define MARGIN 0.6f   // score-gap certainty threshold (~12 sigma of approx error)

typedef __bf16 bf16x8 __attribute__((ext_vector_type(8)));
typedef __bf16 bf16x4 __attribute__((ext_vector_type(4)));
typedef float f32x4 __attribute__((ext_vector_type(4)));

// ---------- helpers ----------
__device__ __forceinline__ unsigned int fkey(float f) {
  unsigned int u = __float_as_uint(f);
  return (u & 0x80000000u) ? ~u : (u | 0x80000000u);
}
__device__ __forceinline__ float unfkey(unsigned int k) {
  unsigned int u = (k & 0x80000000u) ? (k & 0x7fffffffu) : ~k;
  return __uint_as_float(u);
}
__device__ __forceinline__ void gl2lds16(const void* gsrc, void* lds) {
  __builtin_amdgcn_global_load_lds(
      (const __attribute__((address_space(1))) unsigned int*)gsrc,
      (__attribute__((address_space(3))) unsigned int*)lds, 16, 0, 0);
}
__device__ __forceinline__ unsigned long long umin64(unsigned long long a,
                                                     unsigned long long b) {
  return a < b ? a : b;
}
__device__ __forceinline__ unsigned long long umax64(unsigned long long a,
                                                     unsigned long long b) {
  return a < b ? b : a;
}

// ---------- pack x: f32 -> [hi|hi|lo] bf16 ----------
__global__ void k_pack_x(const float* __restrict__ x, __bf16* __restrict__ xp) {
  int gid = blockIdx.x * blockDim.x + threadIdx.x;  // float4 index
  int t = gid >> 7, d4 = gid & 127;
  float4 v = reinterpret_cast<const float4*>(x)[gid];
  bf16x4 hi, lo;
  hi[0] = (__bf16)v.x; hi[1] = (__bf16)v.y; hi[2] = (__bf16)v.z; hi[3] = (__bf16)v.w;
  lo[0] = (__bf16)(v.x - (float)hi[0]);
  lo[1] = (__bf16)(v.y - (float)hi[1]);
  lo[2] = (__bf16)(v.z - (float)hi[2]);
  lo[3] = (__bf16)(v.w - (float)hi[3]);
  __bf16* row = xp + (size_t)t * KP + d4 * 4;
  *(bf16x4*)(row)        = hi;
  *(bf16x4*)(row + 512)  = hi;
  *(bf16x4*)(row + 1024) = lo;
}

// ---------- pack key + norm (fused): kp = [hi|lo|hi], h = 0.5*||k||^2 ----------
__global__ void k_pack_k_norm(const float* __restrict__ kw, __bf16* __restrict__ kp,
                              float* __restrict__ h) {
  int row = blockIdx.x * 4 + (threadIdx.x >> 6);
  int lane = threadIdx.x & 63;
  const float4* src = reinterpret_cast<const float4*>(kw + (size_t)row * N_EMBED);
  __bf16* dst = kp + (size_t)row * KP;
  float s = 0.f;
  #pragma unroll
  for (int c = 0; c < 2; ++c) {
    int f4 = lane + c * 64;  // 0..127
    float4 v = src[f4];
    s += v.x*v.x + v.y*v.y + v.z*v.z + v.w*v.w;
    bf16x4 hi, lo;
    hi[0] = (__bf16)v.x; hi[1] = (__bf16)v.y; hi[2] = (__bf16)v.z; hi[3] = (__bf16)v.w;
    lo[0] = (__bf16)(v.x - (float)hi[0]);
    lo[1] = (__bf16)(v.y - (float)hi[1]);
    lo[2] = (__bf16)(v.z - (float)hi[2]);
    lo[3] = (__bf16)(v.w - (float)hi[3]);
    *(bf16x4*)(dst + f4 * 4)        = hi;
    *(bf16x4*)(dst + 512 + f4 * 4)  = lo;
    *(bf16x4*)(dst + 1024 + f4 * 4) = hi;
  }
  #pragma unroll
  for (int off = 32; off; off >>= 1) s += __shfl_down(s, off);
  if (lane == 0) h[row] = 0.5f * s;
}

// ---------- norms only (deep fallback) ----------
__global__ void k_hnorm(const float* __restrict__ key_w, float* __restrict__ h) {
  int code = blockIdx.x * 4 + (threadIdx.x >> 6);
  int lane = threadIdx.x & 63;
  const float4* row = reinterpret_cast<const float4*>(key_w + (size_t)code * N_EMBED);
  float s = 0.f;
  float4 v0 = row[lane];
  float4 v1 = row[lane + 64];
  s += v0.x*v0.x + v0.y*v0.y + v0.z*v0.z + v0.w*v0.w;
  s += v1.x*v1.x + v1.y*v1.y + v1.z*v1.z + v1.w*v1.w;
  #pragma unroll
  for (int off = 32; off; off >>= 1) s += __shfl_down(s, off);
  if (lane == 0) h[code] = 0.5f * s;
}

#define BMr 128
#define BNr 128
#define BKe 64   // bf16 elements per K-step (128 B per row)

// ---------- PASS 1: K=512 hi*hi MFMA GEMM, per-(row, 64col) top-2 epilogue ----
__global__ __launch_bounds__(256) void k_mfma_top2(
    const __bf16* __restrict__ xp, const __bf16* __restrict__ kp,
    const float* __restrict__ h, ulonglong2* __restrict__ slots) {
  __shared__ __bf16 AS[BMr * BKe];
  __shared__ __bf16 BS[BNr * BKe];

  const int nb = blockIdx.x, mb = blockIdx.y;
  const int m0 = mb * BMr, n0 = nb * BNr;
  const int tid = threadIdx.x;
  const int lane = tid & 63;
  const int wid = tid >> 6;
  const int wm = (wid >> 1) * 64, wn = (wid & 1) * 64;

  f32x4 acc[4][4] = {};
  const int soff = tid * 16;

  for (int ks = 0; ks < 512; ks += BKe) {   // hi columns only
    __syncthreads();
    #pragma unroll
    for (int i = 0; i < 4; ++i) {
      int off = i * 4096 + soff;
      int row = off >> 7;
      int inner = (off & 127) ^ ((row & 7) << 4);
      gl2lds16(xp + (size_t)(m0 + row) * KP + ks + (inner >> 1), (char*)AS + off);
      gl2lds16(kp + (size_t)(n0 + row) * KP + ks + (inner >> 1), (char*)BS + off);
    }
    asm volatile("s_waitcnt vmcnt(0)" ::: "memory");
    __syncthreads();

    #pragma unroll
    for (int kk = 0; kk < 2; ++kk) {
      const int cbyte = kk * 64 + (lane >> 4) * 16;
      bf16x8 af[4], bb[4];
      #pragma unroll
      for (int i = 0; i < 4; ++i) {
        int arow = wm + i * 16 + (lane & 15);
        af[i] = *(const bf16x8*)((const char*)AS + arow * 128 + (cbyte ^ ((arow & 7) << 4)));
        int brow = wn + i * 16 + (lane & 15);
        bb[i] = *(const bf16x8*)((const char*)BS + brow * 128 + (cbyte ^ ((brow & 7) << 4)));
      }
      #pragma unroll
      for (int i = 0; i < 4; ++i)
        #pragma unroll
        for (int j = 0; j < 4; ++j)
          acc[i][j] = __builtin_amdgcn_mfma_f32_16x16x32_bf16(af[i], bb[j], acc[i][j], 0, 0, 0);
    }
  }

  // epilogue: top-2 per row over this wave's 64 cols -> slot (row, nb*2+(wid&1))
  const int rgrp = lane >> 4;
  const int cidx = lane & 15;
  const int cb = nb * 2 + (wid & 1);
  #pragma unroll
  for (int i = 0; i < 4; ++i) {
    #pragma unroll
    for (int r = 0; r < 4; ++r) {
      unsigned long long m1 = ~0ull, m2 = ~0ull;
      #pragma unroll
      for (int j = 0; j < 4; ++j) {
        int kk = n0 + wn + j * 16 + cidx;
        float score = h[kk] - acc[i][j][r];
        unsigned long long c =
            ((unsigned long long)fkey(score) << 32) | (unsigned int)kk;
        if (c < m1) { m2 = m1; m1 = c; } else { m2 = umin64(m2, c); }
      }
      #pragma unroll
      for (int msk = 1; msk < 16; msk <<= 1) {
        unsigned long long o1 = __shfl_xor(m1, msk);
        unsigned long long o2 = __shfl_xor(m2, msk);
        unsigned long long n1 = umin64(m1, o1);
        unsigned long long n2 = umin64(umax64(m1, o1), umin64(m2, o2));
        m1 = n1; m2 = n2;
      }
      if (cidx == 0) {
        int row = m0 + wm + i * 16 + rgrp * 4 + r;
        ulonglong2 p; p.x = m1; p.y = m2;
        slots[(size_t)row * 128 + cb] = p;
      }
    }
  }
}

// ---------- reduce: per-row global top-2 -> certain idx or uncertain list ----
__global__ void k_top2_reduce(const ulonglong2* __restrict__ slots,
                              int* __restrict__ idx, unsigned int* __restrict__ tlist,
                              unsigned int* __restrict__ ucount) {
  int row = blockIdx.x * 4 + (threadIdx.x >> 6);
  int lane = threadIdx.x & 63;
  const ulonglong2* s = slots + (size_t)row * 128;
  ulonglong2 a = s[lane], b = s[lane + 64];
  unsigned long long m1 = umin64(a.x, b.x);
  unsigned long long m2 = umin64(umax64(a.x, b.x), umin64(a.y, b.y));
  #pragma unroll
  for (int msk = 1; msk < 64; msk <<= 1) {
    unsigned long long o1 = __shfl_xor(m1, msk);
    unsigned long long o2 = __shfl_xor(m2, msk);
    unsigned long long n1 = umin64(m1, o1);
    unsigned long long n2 = umin64(umax64(m1, o1), umin64(m2, o2));
    m1 = n1; m2 = n2;
  }
  if (lane == 0) {
    float g1 = unfkey((unsigned int)(m1 >> 32));
    float g2 = unfkey((unsigned int)(m2 >> 32));
    if (g2 - g1 >= MARGIN) {
      idx[row] = (int)(unsigned int)(m1 & 0xffffffffull);
    } else {
      unsigned int p = atomicAdd(ucount, 1u);
      tlist[p] = (unsigned int)row;
    }
  }
}

// ---------- REFINE: 3-term K=1536 exact-class GEMM over uncertain tokens ----
__global__ __launch_bounds__(256) void k_mfma_refine(
    const __bf16* __restrict__ xp, const __bf16* __restrict__ kp,
    const float* __restrict__ h, const unsigned int* __restrict__ tlist,
    const unsigned int* __restrict__ ucount, unsigned long long* __restrict__ rbest) {
  const unsigned int uc = *ucount;
  const int nb = blockIdx.x, mb = blockIdx.y;
  const int m0 = mb * BMr;
  if ((unsigned int)m0 >= uc) return;

  __shared__ __bf16 AS[BMr * BKe];
  __shared__ __bf16 BS[BNr * BKe];

  const int n0 = nb * BNr;
  const int tid = threadIdx.x;
  const int lane = tid & 63;
  const int wid = tid >> 6;
  const int wm = (wid >> 1) * 64, wn = (wid & 1) * 64;

  // gather A row bases via tlist (clamped for rows past uc)
  const int r0 = tid >> 3;  // 0..31
  size_t abase[4];
  #pragma unroll
  for (int i = 0; i < 4; ++i) {
    int p = m0 + r0 + 32 * i;
    int pc = p < (int)uc ? p : (int)uc - 1;
    abase[i] = (size_t)tlist[pc] * KP;
  }

  f32x4 acc[4][4] = {};
  const int soff = tid * 16;
  const int innerC = (soff & 127) ^ ((r0 & 7) << 4);  // constant across i

  for (int ks = 0; ks < KP; ks += BKe) {
    __syncthreads();
    #pragma unroll
    for (int i = 0; i < 4; ++i) {
      int off = i * 4096 + soff;
      int brow = (off >> 7);
      gl2lds16(xp + abase[i] + ks + (innerC >> 1), (char*)AS + off);
      int binner = (off & 127) ^ ((brow & 7) << 4);
      gl2lds16(kp + (size_t)(n0 + brow) * KP + ks + (binner >> 1), (char*)BS + off);
    }
    asm volatile("s_waitcnt vmcnt(0)" ::: "memory");
    __syncthreads();

    #pragma unroll
    for (int kk = 0; kk < 2; ++kk) {
      const int cbyte = kk * 64 + (lane >> 4) * 16;
      bf16x8 af[4], bb[4];
      #pragma unroll
      for (int i = 0; i < 4; ++i) {
        int arow = wm + i * 16 + (lane & 15);
        af[i] = *(const bf16x8*)((const char*)AS + arow * 128 + (cbyte ^ ((arow & 7) << 4)));
        int brow = wn + i * 16 + (lane & 15);
        bb[i] = *(const bf16x8*)((const char*)BS + brow * 128 + (cbyte ^ ((brow & 7) << 4)));
      }
      #pragma unroll
      for (int i = 0; i < 4; ++i)
        #pragma unroll
        for (int j = 0; j < 4; ++j)
          acc[i][j] = __builtin_amdgcn_mfma_f32_16x16x32_bf16(af[i], bb[j], acc[i][j], 0, 0, 0);
    }
  }

  const int rgrp = lane >> 4;
  const int cidx = lane & 15;
  #pragma unroll
  for (int i = 0; i < 4; ++i) {
    #pragma unroll
    for (int r = 0; r < 4; ++r) {
      unsigned long long m = ~0ull;
      #pragma unroll
      for (int j = 0; j < 4; ++j) {
        int kk = n0 + wn + j * 16 + cidx;
        float score = h[kk] - acc[i][j][r];
        unsigned long long cand =
            ((unsigned long long)fkey(score) << 32) | (unsigned int)kk;
        m = umin64(m, cand);
      }
      #pragma unroll
      for (int msk = 1; msk < 16; msk <<= 1) m = umin64(m, __shfl_xor(m, msk));
      if (cidx == 0) {
        int p = m0 + wm + i * 16 + rgrp * 4 + r;
        if ((unsigned int)p < uc) atomicMin(&rbest[p], m);
      }
    }
  }
}

// ---------- finalize: uncertain rows get refined index ----------
__global__ void k_finalize(const unsigned long long* __restrict__ rbest,
                           const unsigned int* __restrict__ tlist,
                           const unsigned int* __restrict__ ucount,
                           int* __restrict__ idx) {
  unsigned int p = blockIdx.x * 256 + threadIdx.x;
  if (p < *ucount) idx[tlist[p]] = (int)(unsigned int)(rbest[p] & 0xffffffffull);
}

// ---------- single-stage MFMA GEMM + argmin (R6-proven; ws fallback) ----------
__global__ __launch_bounds__(256) void k_mfma_argmin(
    const __bf16* __restrict__ xp, const __bf16* __restrict__ kp,
    const float* __restrict__ h, unsigned long long* __restrict__ best) {
  __shared__ __bf16 AS[BMr * BKe];
  __shared__ __bf16 BS[BNr * BKe];
  const int nb = blockIdx.x, mb = blockIdx.y;
  const int m0 = mb * BMr, n0 = nb * BNr;
  const int tid = threadIdx.x;
  const int lane = tid & 63;
  const int wid = tid >> 6;
  const int wm = (wid >> 1) * 64, wn = (wid & 1) * 64;
  f32x4 acc[4][4] = {};
  const int soff = tid * 16;
  for (int ks = 0; ks < KP; ks += BKe) {
    __syncthreads();
    #pragma unroll
    for (int i = 0; i < 4; ++i) {
      int off = i * 4096 + soff;
      int row = off >> 7;
      int inner = (off & 127) ^ ((row & 7) << 4);
      gl2lds16(xp + (size_t)(m0 + row) * KP + ks + (inner >> 1), (char*)AS + off);
      gl2lds16(kp + (size_t)(n0 + row) * KP + ks + (inner >> 1), (char*)BS + off);
    }
    asm volatile("s_waitcnt vmcnt(0)" ::: "memory");
    __syncthreads();
    #pragma unroll
    for (int kk = 0; kk < 2; ++kk) {
      const int cbyte = kk * 64 + (lane >> 4) * 16;
      bf16x8 af[4], bb[4];
      #pragma unroll
      for (int i = 0; i < 4; ++i) {
        int arow = wm + i * 16 + (lane & 15);
        af[i] = *(const bf16x8*)((const char*)AS + arow * 128 + (cbyte ^ ((arow & 7) << 4)));
        int brow = wn + i * 16 + (lane & 15);
        bb[i] = *(const bf16x8*)((const char*)BS + brow * 128 + (cbyte ^ ((brow & 7) << 4)));
      }
      #pragma unroll
      for (int i = 0; i < 4; ++i)
        #pragma unroll
        for (int j = 0; j < 4; ++j)
          acc[i][j] = __builtin_amdgcn_mfma_f32_16x16x32_bf16(af[i], bb[j], acc[i][j], 0, 0, 0);
    }
  }
  const int rgrp = lane >> 4;
  const int cidx = lane & 15;
  #pragma unroll
  for (int i = 0; i < 4; ++i) {
    #pragma unroll
    for (int r = 0; r < 4; ++r) {
      unsigned long long m = ~0ull;
      #pragma unroll
      for (int j = 0; j < 4; ++j) {
        int kk = n0 + wn + j * 16 + cidx;
        float score = h[kk] - acc[i][j][r];
        unsigned long long cand =
            ((unsigned long long)fkey(score) << 32) | (unsigned int)kk;
        m = umin64(m, cand);
      }
      #pragma unroll
      for (int msk = 1; msk < 16; msk <<= 1) m = umin64(m, __shfl_xor(m, msk));
      if (cidx == 0) {
        int row = m0 + wm + i * 16 + rgrp * 4 + r;
        atomicMin(&best[row], m);
      }
    }
  }
}

// ---------- f32 fallback GEMM+argmin ----------
#define BT 128
#define BK 128
#define DC 32
__global__ __launch_bounds__(256, 2) void k_gemm_argmin(
    const float* __restrict__ x, const float* __restrict__ key_w,
    const float* __restrict__ h, unsigned long long* __restrict__ best) {
  __shared__ float4 XS[BT * 8];
  __shared__ float4 KS[BK * 8];
  const int kb = blockIdx.x, tb = blockIdx.y;
  const int t0 = tb * BT, k0 = kb * BK;
  const int tid = threadIdx.x;
  const int tx = tid & 15;
  const int tyg = tid >> 4;
  float acc[8][8];
  #pragma unroll
  for (int i = 0; i < 8; ++i)
    #pragma unroll
    for (int j = 0; j < 8; ++j) acc[i][j] = 0.f;
  for (int dc = 0; dc < N_EMBED; dc += DC) {
    __syncthreads();
    #pragma unroll
    for (int ld = 0; ld < 4; ++ld) {
      int li = ld * 256 + tid;
      int row = li >> 3, c4 = li & 7;
      XS[row * 8 + (c4 ^ (row & 7))] =
          *reinterpret_cast<const float4*>(x + (size_t)(t0 + row) * N_EMBED + dc + c4 * 4);
      KS[row * 8 + (c4 ^ (row & 7))] =
          *reinterpret_cast<const float4*>(key_w + (size_t)(k0 + row) * N_EMBED + dc + c4 * 4);
    }
    __syncthreads();
    #pragma unroll
    for (int d4 = 0; d4 < 8; ++d4) {
      float4 a[8], b[8];
      #pragma unroll
      for (int j = 0; j < 8; ++j) {
        a[j] = XS[(tyg + 16 * j) * 8 + (d4 ^ (tyg & 7))];
        b[j] = KS[(tx  + 16 * j) * 8 + (d4 ^ (tx  & 7))];
      }
      #pragma unroll
      for (int i = 0; i < 8; ++i) {
        float4 av = a[i];
        #pragma unroll
        for (int j = 0; j < 8; ++j) {
          float4 bv = b[j];
          acc[i][j] = fmaf(av.x, bv.x, fmaf(av.y, bv.y,
                      fmaf(av.z, bv.z, fmaf(av.w, bv.w, acc[i][j]))));
        }
      }
    }
  }
  #pragma unroll
  for (int i = 0; i < 8; ++i) {
    unsigned long long m = ~0ull;
    #pragma unroll
    for (int j = 0; j < 8; ++j) {
      int kk = k0 + tx + 16 * j;
      float score = h[kk] - acc[i][j];
      unsigned long long cand =
          ((unsigned long long)fkey(score) << 32) | (unsigned int)kk;
      m = umin64(m, cand);
    }
    #pragma unroll
    for (int mask = 1; mask < 16; mask <<= 1) m = umin64(m, __shfl_xor(m, mask));
    if (tx == 0) atomicMin(&best[t0 + tyg + 16 * i], m);
  }
}

// ---------- aux kernels ----------
__global__ void k_extract_counts(const unsigned long long* __restrict__ best,
                                 int* __restrict__ idx, float* __restrict__ out_en) {
  int t = blockIdx.x * blockDim.x + threadIdx.x;
  if (t < T_TOKENS) {
    int k = (int)(unsigned int)(best[t] & 0xffffffffull);
    idx[t] = k;
    atomicAdd(&out_en[k], 0.005f);
  }
}
__global__ void k_counts(const int* __restrict__ idx, float* __restrict__ out_en) {
  int t = blockIdx.x * blockDim.x + threadIdx.x;
  if (t < T_TOKENS) atomicAdd(&out_en[idx[t]], 0.005f);
}
__global__ void k_quant_scatter(const float* __restrict__ x,
                                const float* __restrict__ value_w,
                                const int* __restrict__ idx,
                                float* __restrict__ q, float* __restrict__ out_ew) {
  int gid = blockIdx.x * blockDim.x + threadIdx.x;
  int t = gid >> 7, d4 = gid & 127;
  float4 xv = reinterpret_cast<const float4*>(x)[gid];
  int k = idx[t];
  float4 v = reinterpret_cast<const float4*>(value_w + (size_t)k * N_EMBED)[d4];
  float4 o;
  o.x = xv.x + v.x; o.y = xv.y + v.y; o.z = xv.z + v.z; o.w = xv.w + v.w;
  reinterpret_cast<float4*>(q)[gid] = o;
  const float c = 0.005f;
  float* dst = out_ew + (size_t)k * N_EMBED + d4 * 4;
  atomicAdd(dst + 0, c * xv.x);
  atomicAdd(dst + 1, c * xv.y);
  atomicAdd(dst + 2, c * xv.z);
  atomicAdd(dst + 3, c * xv.w);
}
__global__ void k_scaleN(const float* __restrict__ ema_n, float* __restrict__ out_en) {
  int k = blockIdx.x * blockDim.x + threadIdx.x;
  if (k < N_TOKEN) out_en[k] = 0.99f * ema_n[k];
}
__global__ void k_scaleW(const float* __restrict__ ema_w, float* __restrict__ out_ew) {
  int gid = blockIdx.x * blockDim.x + threadIdx.x;
  float4 v = reinterpret_cast<const float4*>(ema_w)[gid];
  float4 o;
  o.x = 0.99f * v.x; o.y = 0.99f * v.y; o.z = 0.99f * v.z; o.w = 0.99f * v.w;
  reinterpret_cast<float4*>(out_ew)[gid] = o;
}
__global__ void k_sumn(const float* __restrict__ en, float* __restrict__ nsum) {
  __shared__ float sm[256];
  float s = 0.f;
  for (int i = threadIdx.x; i < N_TOKEN; i += 256) s += en[i];
  sm[threadIdx.x] = s;
  __syncthreads();
  for (int off = 128; off; off >>= 1) {
    if (threadIdx.x < off) sm[threadIdx.x] += sm[threadIdx.x + off];
    __syncthreads();
  }
  if (threadIdx.x == 0) *nsum = sm[0];
}
__global__ void k_keyw(const float* __restrict__ out_ew, const float* __restrict__ out_en,
                       const float* __restrict__ nsum, float* __restrict__ out_kw) {
  int gid = blockIdx.x * blockDim.x + threadIdx.x;
  int k = gid >> 7;
  float n = *nsum;
  float sz = (out_en[k] + 1e-8f) / (n + 1e-8f * (float)N_TOKEN) * n;
  float4 w = reinterpret_cast<const float4*>(out_ew)[gid];
  float4 o;
  o.x = w.x / sz; o.y = w.y / sz; o.z = w.z / sz; o.w = w.w / sz;
  reinterpret_cast<float4*>(out_kw)[gid] = o;
}

// ---------- launcher ----------
extern "C" void kernel_launch(void* const* d_in, const int* in_sizes, int n_in,
                              void* d_out, int out_size, void* d_ws, size_t ws_size,
                              hipStream_t stream) {
  const float* x       = (const float*)d_in[0];
  const float* key_w   = (const float*)d_in[1];
  const float* value_w = (const float*)d_in[2];
  const float* ema_n   = (const float*)d_in[3];
  const float* ema_w   = (const float*)d_in[4];

  float* out_q  = (float*)d_out;
  float* out_en = out_q + 8388608;
  float* out_ew = out_en + N_TOKEN;
  float* out_kw = out_ew + 4194304;

  // ---- two-stage layout ----
  const size_t SLOTS_B = (size_t)T_TOKENS * 128 * 16;              // 32 MiB
  const size_t XP_B    = (size_t)T_TOKENS * KP * 2;                // 48 MiB
  const size_t KP_B    = (size_t)N_TOKEN * KP * 2;                 // 24 MiB
  char* base = (char*)d_ws;
  ulonglong2* slots = (ulonglong2*)base;
  __bf16* xp3 = (__bf16*)(base + SLOTS_B);
  __bf16* kp3 = (__bf16*)(base + SLOTS_B + XP_B);
  char* tail  = base + SLOTS_B + XP_B + KP_B;
  float* h            = (float*)tail;                               // 32 KiB
  int*   idx          = (int*)(tail + 32768);                       // 64 KiB
  unsigned int* tlist = (unsigned int*)(tail + 32768 + 65536);      // 64 KiB
  unsigned long long* rbest = (unsigned long long*)(tail + 32768 + 2 * 65536);  // 128 KiB
  unsigned int* ucount = (unsigned int*)(tail + 32768 + 2 * 65536 + 131072);
  float* nsum          = (float*)(tail + 32768 + 2 * 65536 + 131072 + 256);
  const size_t ws_need2 = SLOTS_B + XP_B + KP_B + 32768 + 2 * 65536 + 131072 + 512;

  // ---- R6 single-stage layout (fallback) ----
  unsigned long long* f_best = (unsigned long long*)d_ws;           // 128 KiB
  int*   f_idx  = (int*)((char*)d_ws + 131072);
  float* f_h    = (float*)((char*)d_ws + 196608);
  float* f_nsum = (float*)((char*)d_ws + 229376);
  __bf16* f_xp  = (__bf16*)((char*)d_ws + 262144);
  __bf16* f_kp  = (__bf16*)((char*)d_ws + 262144 + XP_B);
  const size_t ws_need1 = 262144 + XP_B + KP_B;

  if (ws_size >= ws_need2) {
    // ---------- two-stage path ----------
    hipMemsetAsync(rbest, 0xFF, (size_t)T_TOKENS * 8, stream);
    hipMemsetAsync(ucount, 0, 4, stream);
    k_pack_x<<<(T_TOKENS * (N_EMBED / 4)) / 256, 256, 0, stream>>>(x, xp3);
    k_pack_k_norm<<<N_TOKEN / 4, 256, 0, stream>>>(key_w, kp3, h);
    {
      dim3 grid(N_TOKEN / BNr, T_TOKENS / BMr);
      k_mfma_top2<<<grid, 256, 0, stream>>>(xp3, kp3, h, slots);
    }
    k_top2_reduce<<<T_TOKENS / 4, 256, 0, stream>>>(slots, idx, tlist, ucount);
    {
      dim3 grid(N_TOKEN / BNr, T_TOKENS / BMr);
      k_mfma_refine<<<grid, 256, 0, stream>>>(xp3, kp3, h, tlist, ucount, rbest);
    }
    k_finalize<<<T_TOKENS / 256, 256, 0, stream>>>(rbest, tlist, ucount, idx);

    k_scaleN<<<N_TOKEN / 256, 256, 0, stream>>>(ema_n, out_en);
    k_counts<<<T_TOKENS / 256, 256, 0, stream>>>(idx, out_en);
    k_scaleW<<<(N_TOKEN * (N_EMBED / 4)) / 256, 256, 0, stream>>>(ema_w, out_ew);
    k_quant_scatter<<<(T_TOKENS * (N_EMBED / 4)) / 256, 256, 0, stream>>>(
        x, value_w, idx, out_q, out_ew);
    k_sumn<<<1, 256, 0, stream>>>(out_en, nsum);
    k_keyw<<<(N_TOKEN * (N_EMBED / 4)) / 256, 256, 0, stream>>>(out_ew, out_en, nsum, out_kw);
  } else if (ws_size >= ws_need1) {
    // ---------- R6 single-stage path ----------
    hipMemsetAsync(f_best, 0xFF, (size_t)T_TOKENS * 8, stream);
    k_pack_x<<<(T_TOKENS * (N_EMBED / 4)) / 256, 256, 0, stream>>>(x, f_xp);
    k_pack_k_norm<<<N_TOKEN / 4, 256, 0, stream>>>(key_w, f_kp, f_h);
    dim3 grid(N_TOKEN / BNr, T_TOKENS / BMr);
    k_mfma_argmin<<<grid, 256, 0, stream>>>(f_xp, f_kp, f_h, f_best);

    k_scaleN<<<N_TOKEN / 256, 256, 0, stream>>>(ema_n, out_en);
    k_extract_counts<<<T_TOKENS / 256, 256, 0, stream>>>(f_best, f_idx, out_en);
    k_scaleW<<<(N_TOKEN * (N_EMBED / 4)) / 256, 256, 0, stream>>>(ema_w, out_ew);
    k_quant_scatter<<<(T_TOKENS * (N_EMBED / 4)) / 256, 256, 0, stream>>>(
        x, value_w, f_idx, out_q, out_ew);
    k_sumn<<<1, 256, 0, stream>>>(out_en, f_nsum);
    k_keyw<<<(N_TOKEN * (N_EMBED / 4)) / 256, 256, 0, stream>>>(out_ew, out_en, f_nsum, out_kw);
  } else {
    // ---------- deep fallback: f32 vector GEMM ----------
    hipMemsetAsync(f_best, 0xFF, (size_t)T_TOKENS * 8, stream);
    k_hnorm<<<N_TOKEN / 4, 256, 0, stream>>>(key_w, f_h);
    dim3 grid(N_TOKEN / BK, T_TOKENS / BT);
    k_gemm_argmin<<<grid, 256, 0, stream>>>(x, key_w, f_h, f_best);

    k_scaleN<<<N_TOKEN / 256, 256, 0, stream>>>(ema_n, out_en);
    k_extract_counts<<<T_TOKENS / 256, 256, 0, stream>>>(f_best, f_idx, out_en);
    k_scaleW<<<(N_TOKEN * (N_EMBED / 4)) / 256, 256, 0, stream>>>(ema_w, out_ew);
    k_quant_scatter<<<(T_TOKENS * (N_EMBED / 4)) / 256, 256, 0, stream>>>(
        x, value_w, f_idx, out_q, out_ew);
    k_sumn<<<1, 256, 0, stream>>>(out_en, f_nsum);
    k_keyw<<<(N_TOKEN * (N_EMBED / 4)) / 256, 256, 0, stream>>>(out_ew, out_en, f_nsum, out_kw);
  }
}

// Round 8
// 474.930 us; speedup vs baseline: 1.7811x; 1.1153x over previous
//
#include <hip/hip_runtime.h>

#define N_TOKEN 8192
#define N_EMBED 512
#define T_TOKENS 16384
#define KP 1536       // packed K = 3 * 512
#define MARGIN 0.6f   // score-gap certainty threshold (~12 sigma of approx error)

typedef __bf16 bf16x8 __attribute__((ext_vector_type(8)));
typedef __bf16 bf16x4 __attribute__((ext_vector_type(4)));
typedef float f32x4 __attribute__((ext_vector_type(4)));

// ---------- helpers ----------
__device__ __forceinline__ unsigned int fkey(float f) {
  unsigned int u = __float_as_uint(f);
  return (u & 0x80000000u) ? ~u : (u | 0x80000000u);
}
__device__ __forceinline__ void gl2lds16(const void* gsrc, void* lds) {
  __builtin_amdgcn_global_load_lds(
      (const __attribute__((address_space(1))) unsigned int*)gsrc,
      (__attribute__((address_space(3))) unsigned int*)lds, 16, 0, 0);
}
__device__ __forceinline__ unsigned long long umin64(unsigned long long a,
                                                     unsigned long long b) {
  return a < b ? a : b;
}

// ---------- pack x: f32 -> [hi|hi|lo] bf16 ----------
__global__ void k_pack_x(const float* __restrict__ x, __bf16* __restrict__ xp) {
  int gid = blockIdx.x * blockDim.x + threadIdx.x;  // float4 index
  int t = gid >> 7, d4 = gid & 127;
  float4 v = reinterpret_cast<const float4*>(x)[gid];
  bf16x4 hi, lo;
  hi[0] = (__bf16)v.x; hi[1] = (__bf16)v.y; hi[2] = (__bf16)v.z; hi[3] = (__bf16)v.w;
  lo[0] = (__bf16)(v.x - (float)hi[0]);
  lo[1] = (__bf16)(v.y - (float)hi[1]);
  lo[2] = (__bf16)(v.z - (float)hi[2]);
  lo[3] = (__bf16)(v.w - (float)hi[3]);
  __bf16* row = xp + (size_t)t * KP + d4 * 4;
  *(bf16x4*)(row)        = hi;
  *(bf16x4*)(row + 512)  = hi;
  *(bf16x4*)(row + 1024) = lo;
}

// ---------- pack key + norm (fused): kp = [hi|lo|hi], h = 0.5*||k||^2 ----------
__global__ void k_pack_k_norm(const float* __restrict__ kw, __bf16* __restrict__ kp,
                              float* __restrict__ h) {
  int row = blockIdx.x * 4 + (threadIdx.x >> 6);
  int lane = threadIdx.x & 63;
  const float4* src = reinterpret_cast<const float4*>(kw + (size_t)row * N_EMBED);
  __bf16* dst = kp + (size_t)row * KP;
  float s = 0.f;
  #pragma unroll
  for (int c = 0; c < 2; ++c) {
    int f4 = lane + c * 64;  // 0..127
    float4 v = src[f4];
    s += v.x*v.x + v.y*v.y + v.z*v.z + v.w*v.w;
    bf16x4 hi, lo;
    hi[0] = (__bf16)v.x; hi[1] = (__bf16)v.y; hi[2] = (__bf16)v.z; hi[3] = (__bf16)v.w;
    lo[0] = (__bf16)(v.x - (float)hi[0]);
    lo[1] = (__bf16)(v.y - (float)hi[1]);
    lo[2] = (__bf16)(v.z - (float)hi[2]);
    lo[3] = (__bf16)(v.w - (float)hi[3]);
    *(bf16x4*)(dst + f4 * 4)        = hi;
    *(bf16x4*)(dst + 512 + f4 * 4)  = lo;
    *(bf16x4*)(dst + 1024 + f4 * 4) = hi;
  }
  #pragma unroll
  for (int off = 32; off; off >>= 1) s += __shfl_down(s, off);
  if (lane == 0) h[row] = 0.5f * s;
}

// ---------- norms only (deep fallback) ----------
__global__ void k_hnorm(const float* __restrict__ key_w, float* __restrict__ h) {
  int code = blockIdx.x * 4 + (threadIdx.x >> 6);
  int lane = threadIdx.x & 63;
  const float4* row = reinterpret_cast<const float4*>(key_w + (size_t)code * N_EMBED);
  float s = 0.f;
  float4 v0 = row[lane];
  float4 v1 = row[lane + 64];
  s += v0.x*v0.x + v0.y*v0.y + v0.z*v0.z + v0.w*v0.w;
  s += v1.x*v1.x + v1.y*v1.y + v1.z*v1.z + v1.w*v1.w;
  #pragma unroll
  for (int off = 32; off; off >>= 1) s += __shfl_down(s, off);
  if (lane == 0) h[code] = 0.5f * s;
}

#define BMr 128
#define BNr 128
#define BKe 64   // bf16 elements per K-step (128 B per row)

// ---------- PASS 1: K=512 hi*hi GEMM, cheap f32 (s1,c1,s2) top-2 epilogue ----
// Ties / near-ties are routed to refine by the margin test, so f32 compare
// with arbitrary tie-break is safe here.
__global__ __launch_bounds__(256) void k_mfma_top2(
    const __bf16* __restrict__ xp, const __bf16* __restrict__ kp,
    const float* __restrict__ h, float4* __restrict__ slots) {
  __shared__ __bf16 AS[BMr * BKe];
  __shared__ __bf16 BS[BNr * BKe];

  const int nb = blockIdx.x, mb = blockIdx.y;
  const int m0 = mb * BMr, n0 = nb * BNr;
  const int tid = threadIdx.x;
  const int lane = tid & 63;
  const int wid = tid >> 6;
  const int wm = (wid >> 1) * 64, wn = (wid & 1) * 64;

  f32x4 acc[4][4] = {};
  const int soff = tid * 16;

  for (int ks = 0; ks < 512; ks += BKe) {   // hi columns only
    __syncthreads();
    #pragma unroll
    for (int i = 0; i < 4; ++i) {
      int off = i * 4096 + soff;
      int row = off >> 7;
      int inner = (off & 127) ^ ((row & 7) << 4);
      gl2lds16(xp + (size_t)(m0 + row) * KP + ks + (inner >> 1), (char*)AS + off);
      gl2lds16(kp + (size_t)(n0 + row) * KP + ks + (inner >> 1), (char*)BS + off);
    }
    asm volatile("s_waitcnt vmcnt(0)" ::: "memory");
    __syncthreads();

    #pragma unroll
    for (int kk = 0; kk < 2; ++kk) {
      const int cbyte = kk * 64 + (lane >> 4) * 16;
      bf16x8 af[4], bb[4];
      #pragma unroll
      for (int i = 0; i < 4; ++i) {
        int arow = wm + i * 16 + (lane & 15);
        af[i] = *(const bf16x8*)((const char*)AS + arow * 128 + (cbyte ^ ((arow & 7) << 4)));
        int brow = wn + i * 16 + (lane & 15);
        bb[i] = *(const bf16x8*)((const char*)BS + brow * 128 + (cbyte ^ ((brow & 7) << 4)));
      }
      #pragma unroll
      for (int i = 0; i < 4; ++i)
        #pragma unroll
        for (int j = 0; j < 4; ++j)
          acc[i][j] = __builtin_amdgcn_mfma_f32_16x16x32_bf16(af[i], bb[j], acc[i][j], 0, 0, 0);
    }
  }

  // epilogue: f32 top-2 (value) + top-1 col over this wave's 64 cols
  const int rgrp = lane >> 4;
  const int cidx = lane & 15;
  const int cb = nb * 2 + (wid & 1);
  #pragma unroll
  for (int i = 0; i < 4; ++i) {
    #pragma unroll
    for (int r = 0; r < 4; ++r) {
      float s1 = 3.4e38f, s2 = 3.4e38f;
      int c1 = 0;
      #pragma unroll
      for (int j = 0; j < 4; ++j) {
        int kk = n0 + wn + j * 16 + cidx;
        float sc = h[kk] - acc[i][j][r];
        if (sc < s1) { s2 = s1; s1 = sc; c1 = kk; }
        else s2 = fminf(s2, sc);
      }
      #pragma unroll
      for (int msk = 1; msk < 16; msk <<= 1) {
        float o1 = __shfl_xor(s1, msk);
        float o2 = __shfl_xor(s2, msk);
        int   oc = __shfl_xor(c1, msk);
        float ns2 = fminf(fminf(s2, o2), fmaxf(s1, o1));
        bool take = o1 < s1;
        s1 = take ? o1 : s1;
        c1 = take ? oc : c1;
        s2 = ns2;
      }
      if (cidx == 0) {
        int row = m0 + wm + i * 16 + rgrp * 4 + r;
        float4 p;
        p.x = s1; p.y = s2; p.z = __int_as_float(c1); p.w = 0.f;
        slots[(size_t)row * 128 + cb] = p;
      }
    }
  }
}

// ---------- reduce: per-row global top-2 -> certain idx or uncertain list ----
__global__ void k_top2_reduce(const float4* __restrict__ slots,
                              int* __restrict__ idx, unsigned int* __restrict__ tlist,
                              unsigned int* __restrict__ ucount) {
  int row = blockIdx.x * 4 + (threadIdx.x >> 6);
  int lane = threadIdx.x & 63;
  const float4* s = slots + (size_t)row * 128;
  float4 a = s[lane], b = s[lane + 64];
  float s1, s2; int c1;
  {
    bool take = b.x < a.x;
    s1 = take ? b.x : a.x;
    c1 = __float_as_int(take ? b.z : a.z);
    s2 = fminf(fminf(a.y, b.y), fmaxf(a.x, b.x));
  }
  #pragma unroll
  for (int msk = 1; msk < 64; msk <<= 1) {
    float o1 = __shfl_xor(s1, msk);
    float o2 = __shfl_xor(s2, msk);
    int   oc = __shfl_xor(c1, msk);
    float ns2 = fminf(fminf(s2, o2), fmaxf(s1, o1));
    bool take = o1 < s1;
    s1 = take ? o1 : s1;
    c1 = take ? oc : c1;
    s2 = ns2;
  }
  if (lane == 0) {
    if (s2 - s1 >= MARGIN) {
      idx[row] = c1;
    } else {
      unsigned int p = atomicAdd(ucount, 1u);
      tlist[p] = (unsigned int)row;
    }
  }
}

// ---------- REFINE: 3-term K=1536 exact-class GEMM over uncertain tokens ----
__global__ __launch_bounds__(256) void k_mfma_refine(
    const __bf16* __restrict__ xp, const __bf16* __restrict__ kp,
    const float* __restrict__ h, const unsigned int* __restrict__ tlist,
    const unsigned int* __restrict__ ucount, unsigned long long* __restrict__ rbest) {
  const unsigned int uc = *ucount;
  const int nb = blockIdx.x, mb = blockIdx.y;
  const int m0 = mb * BMr;
  if ((unsigned int)m0 >= uc) return;

  __shared__ __bf16 AS[BMr * BKe];
  __shared__ __bf16 BS[BNr * BKe];

  const int n0 = nb * BNr;
  const int tid = threadIdx.x;
  const int lane = tid & 63;
  const int wid = tid >> 6;
  const int wm = (wid >> 1) * 64, wn = (wid & 1) * 64;

  const int r0 = tid >> 3;  // 0..31
  size_t abase[4];
  #pragma unroll
  for (int i = 0; i < 4; ++i) {
    int p = m0 + r0 + 32 * i;
    int pc = p < (int)uc ? p : (int)uc - 1;
    abase[i] = (size_t)tlist[pc] * KP;
  }

  f32x4 acc[4][4] = {};
  const int soff = tid * 16;
  const int innerC = (soff & 127) ^ ((r0 & 7) << 4);

  for (int ks = 0; ks < KP; ks += BKe) {
    __syncthreads();
    #pragma unroll
    for (int i = 0; i < 4; ++i) {
      int off = i * 4096 + soff;
      int brow = (off >> 7);
      gl2lds16(xp + abase[i] + ks + (innerC >> 1), (char*)AS + off);
      int binner = (off & 127) ^ ((brow & 7) << 4);
      gl2lds16(kp + (size_t)(n0 + brow) * KP + ks + (binner >> 1), (char*)BS + off);
    }
    asm volatile("s_waitcnt vmcnt(0)" ::: "memory");
    __syncthreads();

    #pragma unroll
    for (int kk = 0; kk < 2; ++kk) {
      const int cbyte = kk * 64 + (lane >> 4) * 16;
      bf16x8 af[4], bb[4];
      #pragma unroll
      for (int i = 0; i < 4; ++i) {
        int arow = wm + i * 16 + (lane & 15);
        af[i] = *(const bf16x8*)((const char*)AS + arow * 128 + (cbyte ^ ((arow & 7) << 4)));
        int brow = wn + i * 16 + (lane & 15);
        bb[i] = *(const bf16x8*)((const char*)BS + brow * 128 + (cbyte ^ ((brow & 7) << 4)));
      }
      #pragma unroll
      for (int i = 0; i < 4; ++i)
        #pragma unroll
        for (int j = 0; j < 4; ++j)
          acc[i][j] = __builtin_amdgcn_mfma_f32_16x16x32_bf16(af[i], bb[j], acc[i][j], 0, 0, 0);
    }
  }

  const int rgrp = lane >> 4;
  const int cidx = lane & 15;
  #pragma unroll
  for (int i = 0; i < 4; ++i) {
    #pragma unroll
    for (int r = 0; r < 4; ++r) {
      unsigned long long m = ~0ull;
      #pragma unroll
      for (int j = 0; j < 4; ++j) {
        int kk = n0 + wn + j * 16 + cidx;
        float score = h[kk] - acc[i][j][r];
        unsigned long long cand =
            ((unsigned long long)fkey(score) << 32) | (unsigned int)kk;
        m = umin64(m, cand);
      }
      #pragma unroll
      for (int msk = 1; msk < 16; msk <<= 1) m = umin64(m, __shfl_xor(m, msk));
      if (cidx == 0) {
        int p = m0 + wm + i * 16 + rgrp * 4 + r;
        if ((unsigned int)p < uc) atomicMin(&rbest[p], m);
      }
    }
  }
}

// ---------- finalize: uncertain rows get refined index ----------
__global__ void k_finalize(const unsigned long long* __restrict__ rbest,
                           const unsigned int* __restrict__ tlist,
                           const unsigned int* __restrict__ ucount,
                           int* __restrict__ idx) {
  unsigned int p = blockIdx.x * 256 + threadIdx.x;
  if (p < *ucount) idx[tlist[p]] = (int)(unsigned int)(rbest[p] & 0xffffffffull);
}

// ---------- counting-sort CSR + fused EMA update ----------
__global__ void k_sum_ema_n(const float* __restrict__ ema_n, float* __restrict__ nsum) {
  __shared__ float sm[256];
  float s = 0.f;
  for (int i = threadIdx.x; i < N_TOKEN; i += 256) s += ema_n[i];
  sm[threadIdx.x] = s;
  __syncthreads();
  for (int off = 128; off; off >>= 1) {
    if (threadIdx.x < off) sm[threadIdx.x] += sm[threadIdx.x + off];
    __syncthreads();
  }
  if (threadIdx.x == 0) *nsum = sm[0];
}

__global__ void k_hist(const int* __restrict__ idx, int* __restrict__ counts) {
  int t = blockIdx.x * 256 + threadIdx.x;
  if (t < T_TOKENS) atomicAdd(&counts[idx[t]], 1);
}

__global__ void k_scan(const int* __restrict__ counts, int* __restrict__ offs,
                       int* __restrict__ cursor) {
  __shared__ int sa[256], sb[256];
  int tid = threadIdx.x;
  int base = tid * 32;
  int loc[32]; int s = 0;
  #pragma unroll
  for (int e = 0; e < 32; ++e) { loc[e] = s; s += counts[base + e]; }
  sa[tid] = s;
  __syncthreads();
  int* src = sa; int* dst = sb;
  for (int d = 1; d < 256; d <<= 1) {
    int v = src[tid] + (tid >= d ? src[tid - d] : 0);
    dst[tid] = v;
    __syncthreads();
    int* tmp = src; src = dst; dst = tmp;
  }
  int excl = src[tid] - s;
  #pragma unroll
  for (int e = 0; e < 32; ++e) {
    int o = excl + loc[e];
    offs[base + e] = o;
    cursor[base + e] = o;
  }
}

__global__ void k_place(const int* __restrict__ idx, int* __restrict__ cursor,
                        int* __restrict__ tok) {
  int t = blockIdx.x * 256 + threadIdx.x;
  if (t < T_TOKENS) {
    int p = atomicAdd(&cursor[idx[t]], 1);
    tok[p] = t;
  }
}

// one wave per code: en, ew = 0.99*ema_w + 0.005*sum(x[tok]), kw = ew/sz
__global__ void k_update(const float* __restrict__ x, const float* __restrict__ ema_n,
                         const float* __restrict__ ema_w, const int* __restrict__ counts,
                         const int* __restrict__ offs, const int* __restrict__ tok,
                         const float* __restrict__ nsum,
                         float* __restrict__ out_en, float* __restrict__ out_ew,
                         float* __restrict__ out_kw) {
  int k = blockIdx.x * 4 + (threadIdx.x >> 6);
  int lane = threadIdx.x & 63;
  int cnt = counts[k];
  int off = offs[k];
  float en = 0.99f * ema_n[k] + 0.005f * (float)cnt;
  if (lane == 0) out_en[k] = en;
  float n = 0.99f * (*nsum) + 81.92f;   // 0.005 * 16384
  float sz = (en + 1e-8f) / (n + 1e-8f * (float)N_TOKEN) * n;

  const float4* er = reinterpret_cast<const float4*>(ema_w + (size_t)k * N_EMBED);
  float4 e0 = er[lane], e1 = er[lane + 64];
  float4 s0 = {0.f, 0.f, 0.f, 0.f}, s1v = {0.f, 0.f, 0.f, 0.f};
  for (int q = 0; q < cnt; ++q) {
    int t = tok[off + q];
    const float4* xr = reinterpret_cast<const float4*>(x + (size_t)t * N_EMBED);
    float4 a = xr[lane], b = xr[lane + 64];
    s0.x += a.x; s0.y += a.y; s0.z += a.z; s0.w += a.w;
    s1v.x += b.x; s1v.y += b.y; s1v.z += b.z; s1v.w += b.w;
  }
  float4 w0, w1;
  w0.x = 0.99f * e0.x + 0.005f * s0.x;  w0.y = 0.99f * e0.y + 0.005f * s0.y;
  w0.z = 0.99f * e0.z + 0.005f * s0.z;  w0.w = 0.99f * e0.w + 0.005f * s0.w;
  w1.x = 0.99f * e1.x + 0.005f * s1v.x; w1.y = 0.99f * e1.y + 0.005f * s1v.y;
  w1.z = 0.99f * e1.z + 0.005f * s1v.z; w1.w = 0.99f * e1.w + 0.005f * s1v.w;
  float4* ow = reinterpret_cast<float4*>(out_ew + (size_t)k * N_EMBED);
  ow[lane] = w0; ow[lane + 64] = w1;
  float4 q0, q1;
  q0.x = w0.x / sz; q0.y = w0.y / sz; q0.z = w0.z / sz; q0.w = w0.w / sz;
  q1.x = w1.x / sz; q1.y = w1.y / sz; q1.z = w1.z / sz; q1.w = w1.w / sz;
  float4* okw = reinterpret_cast<float4*>(out_kw + (size_t)k * N_EMBED);
  okw[lane] = q0; okw[lane + 64] = q1;
}

// ---------- quantized = x + value_w[idx] (no atomics) ----------
__global__ void k_quant(const float* __restrict__ x, const float* __restrict__ value_w,
                        const int* __restrict__ idx, float* __restrict__ q) {
  int gid = blockIdx.x * blockDim.x + threadIdx.x;
  int t = gid >> 7, d4 = gid & 127;
  float4 xv = reinterpret_cast<const float4*>(x)[gid];
  float4 v = reinterpret_cast<const float4*>(value_w + (size_t)idx[t] * N_EMBED)[d4];
  float4 o;
  o.x = xv.x + v.x; o.y = xv.y + v.y; o.z = xv.z + v.z; o.w = xv.w + v.w;
  reinterpret_cast<float4*>(q)[gid] = o;
}

// ---------- single-stage MFMA GEMM + argmin (R6-proven; ws fallback) ----------
__global__ __launch_bounds__(256) void k_mfma_argmin(
    const __bf16* __restrict__ xp, const __bf16* __restrict__ kp,
    const float* __restrict__ h, unsigned long long* __restrict__ best) {
  __shared__ __bf16 AS[BMr * BKe];
  __shared__ __bf16 BS[BNr * BKe];
  const int nb = blockIdx.x, mb = blockIdx.y;
  const int m0 = mb * BMr, n0 = nb * BNr;
  const int tid = threadIdx.x;
  const int lane = tid & 63;
  const int wid = tid >> 6;
  const int wm = (wid >> 1) * 64, wn = (wid & 1) * 64;
  f32x4 acc[4][4] = {};
  const int soff = tid * 16;
  for (int ks = 0; ks < KP; ks += BKe) {
    __syncthreads();
    #pragma unroll
    for (int i = 0; i < 4; ++i) {
      int off = i * 4096 + soff;
      int row = off >> 7;
      int inner = (off & 127) ^ ((row & 7) << 4);
      gl2lds16(xp + (size_t)(m0 + row) * KP + ks + (inner >> 1), (char*)AS + off);
      gl2lds16(kp + (size_t)(n0 + row) * KP + ks + (inner >> 1), (char*)BS + off);
    }
    asm volatile("s_waitcnt vmcnt(0)" ::: "memory");
    __syncthreads();
    #pragma unroll
    for (int kk = 0; kk < 2; ++kk) {
      const int cbyte = kk * 64 + (lane >> 4) * 16;
      bf16x8 af[4], bb[4];
      #pragma unroll
      for (int i = 0; i < 4; ++i) {
        int arow = wm + i * 16 + (lane & 15);
        af[i] = *(const bf16x8*)((const char*)AS + arow * 128 + (cbyte ^ ((arow & 7) << 4)));
        int brow = wn + i * 16 + (lane & 15);
        bb[i] = *(const bf16x8*)((const char*)BS + brow * 128 + (cbyte ^ ((brow & 7) << 4)));
      }
      #pragma unroll
      for (int i = 0; i < 4; ++i)
        #pragma unroll
        for (int j = 0; j < 4; ++j)
          acc[i][j] = __builtin_amdgcn_mfma_f32_16x16x32_bf16(af[i], bb[j], acc[i][j], 0, 0, 0);
    }
  }
  const int rgrp = lane >> 4;
  const int cidx = lane & 15;
  #pragma unroll
  for (int i = 0; i < 4; ++i) {
    #pragma unroll
    for (int r = 0; r < 4; ++r) {
      unsigned long long m = ~0ull;
      #pragma unroll
      for (int j = 0; j < 4; ++j) {
        int kk = n0 + wn + j * 16 + cidx;
        float score = h[kk] - acc[i][j][r];
        unsigned long long cand =
            ((unsigned long long)fkey(score) << 32) | (unsigned int)kk;
        m = umin64(m, cand);
      }
      #pragma unroll
      for (int msk = 1; msk < 16; msk <<= 1) m = umin64(m, __shfl_xor(m, msk));
      if (cidx == 0) {
        int row = m0 + wm + i * 16 + rgrp * 4 + r;
        atomicMin(&best[row], m);
      }
    }
  }
}

// ---------- f32 fallback GEMM+argmin ----------
#define BT 128
#define BK 128
#define DC 32
__global__ __launch_bounds__(256, 2) void k_gemm_argmin(
    const float* __restrict__ x, const float* __restrict__ key_w,
    const float* __restrict__ h, unsigned long long* __restrict__ best) {
  __shared__ float4 XS[BT * 8];
  __shared__ float4 KS[BK * 8];
  const int kb = blockIdx.x, tb = blockIdx.y;
  const int t0 = tb * BT, k0 = kb * BK;
  const int tid = threadIdx.x;
  const int tx = tid & 15;
  const int tyg = tid >> 4;
  float acc[8][8];
  #pragma unroll
  for (int i = 0; i < 8; ++i)
    #pragma unroll
    for (int j = 0; j < 8; ++j) acc[i][j] = 0.f;
  for (int dc = 0; dc < N_EMBED; dc += DC) {
    __syncthreads();
    #pragma unroll
    for (int ld = 0; ld < 4; ++ld) {
      int li = ld * 256 + tid;
      int row = li >> 3, c4 = li & 7;
      XS[row * 8 + (c4 ^ (row & 7))] =
          *reinterpret_cast<const float4*>(x + (size_t)(t0 + row) * N_EMBED + dc + c4 * 4);
      KS[row * 8 + (c4 ^ (row & 7))] =
          *reinterpret_cast<const float4*>(key_w + (size_t)(k0 + row) * N_EMBED + dc + c4 * 4);
    }
    __syncthreads();
    #pragma unroll
    for (int d4 = 0; d4 < 8; ++d4) {
      float4 a[8], b[8];
      #pragma unroll
      for (int j = 0; j < 8; ++j) {
        a[j] = XS[(tyg + 16 * j) * 8 + (d4 ^ (tyg & 7))];
        b[j] = KS[(tx  + 16 * j) * 8 + (d4 ^ (tx  & 7))];
      }
      #pragma unroll
      for (int i = 0; i < 8; ++i) {
        float4 av = a[i];
        #pragma unroll
        for (int j = 0; j < 8; ++j) {
          float4 bv = b[j];
          acc[i][j] = fmaf(av.x, bv.x, fmaf(av.y, bv.y,
                      fmaf(av.z, bv.z, fmaf(av.w, bv.w, acc[i][j]))));
        }
      }
    }
  }
  #pragma unroll
  for (int i = 0; i < 8; ++i) {
    unsigned long long m = ~0ull;
    #pragma unroll
    for (int j = 0; j < 8; ++j) {
      int kk = k0 + tx + 16 * j;
      float score = h[kk] - acc[i][j];
      unsigned long long cand =
          ((unsigned long long)fkey(score) << 32) | (unsigned int)kk;
      m = umin64(m, cand);
    }
    #pragma unroll
    for (int mask = 1; mask < 16; mask <<= 1) m = umin64(m, __shfl_xor(m, mask));
    if (tx == 0) atomicMin(&best[t0 + tyg + 16 * i], m);
  }
}

// ---------- legacy aux (fallback paths) ----------
__global__ void k_extract_counts(const unsigned long long* __restrict__ best,
                                 int* __restrict__ idx, float* __restrict__ out_en) {
  int t = blockIdx.x * blockDim.x + threadIdx.x;
  if (t < T_TOKENS) {
    int k = (int)(unsigned int)(best[t] & 0xffffffffull);
    idx[t] = k;
    atomicAdd(&out_en[k], 0.005f);
  }
}
__global__ void k_quant_scatter(const float* __restrict__ x,
                                const float* __restrict__ value_w,
                                const int* __restrict__ idx,
                                float* __restrict__ q, float* __restrict__ out_ew) {
  int gid = blockIdx.x * blockDim.x + threadIdx.x;
  int t = gid >> 7, d4 = gid & 127;
  float4 xv = reinterpret_cast<const float4*>(x)[gid];
  int k = idx[t];
  float4 v = reinterpret_cast<const float4*>(value_w + (size_t)k * N_EMBED)[d4];
  float4 o;
  o.x = xv.x + v.x; o.y = xv.y + v.y; o.z = xv.z + v.z; o.w = xv.w + v.w;
  reinterpret_cast<float4*>(q)[gid] = o;
  const float c = 0.005f;
  float* dst = out_ew + (size_t)k * N_EMBED + d4 * 4;
  atomicAdd(dst + 0, c * xv.x);
  atomicAdd(dst + 1, c * xv.y);
  atomicAdd(dst + 2, c * xv.z);
  atomicAdd(dst + 3, c * xv.w);
}
__global__ void k_scaleN(const float* __restrict__ ema_n, float* __restrict__ out_en) {
  int k = blockIdx.x * blockDim.x + threadIdx.x;
  if (k < N_TOKEN) out_en[k] = 0.99f * ema_n[k];
}
__global__ void k_scaleW(const float* __restrict__ ema_w, float* __restrict__ out_ew) {
  int gid = blockIdx.x * blockDim.x + threadIdx.x;
  float4 v = reinterpret_cast<const float4*>(ema_w)[gid];
  float4 o;
  o.x = 0.99f * v.x; o.y = 0.99f * v.y; o.z = 0.99f * v.z; o.w = 0.99f * v.w;
  reinterpret_cast<float4*>(out_ew)[gid] = o;
}
__global__ void k_sumn(const float* __restrict__ en, float* __restrict__ nsum) {
  __shared__ float sm[256];
  float s = 0.f;
  for (int i = threadIdx.x; i < N_TOKEN; i += 256) s += en[i];
  sm[threadIdx.x] = s;
  __syncthreads();
  for (int off = 128; off; off >>= 1) {
    if (threadIdx.x < off) sm[threadIdx.x] += sm[threadIdx.x + off];
    __syncthreads();
  }
  if (threadIdx.x == 0) *nsum = sm[0];
}
__global__ void k_keyw(const float* __restrict__ out_ew, const float* __restrict__ out_en,
                       const float* __restrict__ nsum, float* __restrict__ out_kw) {
  int gid = blockIdx.x * blockDim.x + threadIdx.x;
  int k = gid >> 7;
  float n = *nsum;
  float sz = (out_en[k] + 1e-8f) / (n + 1e-8f * (float)N_TOKEN) * n;
  float4 w = reinterpret_cast<const float4*>(out_ew)[gid];
  float4 o;
  o.x = w.x / sz; o.y = w.y / sz; o.z = w.z / sz; o.w = w.w / sz;
  reinterpret_cast<float4*>(out_kw)[gid] = o;
}

// ---------- launcher ----------
extern "C" void kernel_launch(void* const* d_in, const int* in_sizes, int n_in,
                              void* d_out, int out_size, void* d_ws, size_t ws_size,
                              hipStream_t stream) {
  const float* x       = (const float*)d_in[0];
  const float* key_w   = (const float*)d_in[1];
  const float* value_w = (const float*)d_in[2];
  const float* ema_n   = (const float*)d_in[3];
  const float* ema_w   = (const float*)d_in[4];

  float* out_q  = (float*)d_out;
  float* out_en = out_q + 8388608;
  float* out_ew = out_en + N_TOKEN;
  float* out_kw = out_ew + 4194304;

  // ---- two-stage layout ----
  const size_t SLOTS_B = (size_t)T_TOKENS * 128 * 16;              // 32 MiB
  const size_t XP_B    = (size_t)T_TOKENS * KP * 2;                // 48 MiB
  const size_t KP_B    = (size_t)N_TOKEN * KP * 2;                 // 24 MiB
  char* base = (char*)d_ws;
  float4* slots = (float4*)base;
  __bf16* xp3 = (__bf16*)(base + SLOTS_B);
  __bf16* kp3 = (__bf16*)(base + SLOTS_B + XP_B);
  char* tail  = base + SLOTS_B + XP_B + KP_B;
  float* h                  = (float*)(tail + 0);         // 32 KiB
  int*   idx                = (int*)(tail + 32768);       // 64 KiB
  unsigned int* tlist       = (unsigned int*)(tail + 98304);   // 64 KiB
  unsigned long long* rbest = (unsigned long long*)(tail + 163840);  // 128 KiB
  unsigned int* ucount      = (unsigned int*)(tail + 294912);  // 256 B
  float* nsum               = (float*)(tail + 295168);    // 256 B
  int* counts               = (int*)(tail + 295424);      // 32 KiB
  int* offs                 = (int*)(tail + 328192);      // 32 KiB
  int* cursor               = (int*)(tail + 360960);      // 32 KiB
  int* tok                  = (int*)(tail + 393728);      // 64 KiB
  const size_t ws_need2 = SLOTS_B + XP_B + KP_B + 459264;

  // ---- R6 single-stage layout (fallback) ----
  unsigned long long* f_best = (unsigned long long*)d_ws;
  int*   f_idx  = (int*)((char*)d_ws + 131072);
  float* f_h    = (float*)((char*)d_ws + 196608);
  float* f_nsum = (float*)((char*)d_ws + 229376);
  __bf16* f_xp  = (__bf16*)((char*)d_ws + 262144);
  __bf16* f_kp  = (__bf16*)((char*)d_ws + 262144 + XP_B);
  const size_t ws_need1 = 262144 + XP_B + KP_B;

  if (ws_size >= ws_need2) {
    // ---------- two-stage path ----------
    hipMemsetAsync(rbest, 0xFF, (size_t)T_TOKENS * 8, stream);
    hipMemsetAsync(ucount, 0, 4, stream);
    hipMemsetAsync(counts, 0, N_TOKEN * 4, stream);
    k_sum_ema_n<<<1, 256, 0, stream>>>(ema_n, nsum);
    k_pack_x<<<(T_TOKENS * (N_EMBED / 4)) / 256, 256, 0, stream>>>(x, xp3);
    k_pack_k_norm<<<N_TOKEN / 4, 256, 0, stream>>>(key_w, kp3, h);
    {
      dim3 grid(N_TOKEN / BNr, T_TOKENS / BMr);
      k_mfma_top2<<<grid, 256, 0, stream>>>(xp3, kp3, h, slots);
    }
    k_top2_reduce<<<T_TOKENS / 4, 256, 0, stream>>>(slots, idx, tlist, ucount);
    {
      dim3 grid(N_TOKEN / BNr, T_TOKENS / BMr);
      k_mfma_refine<<<grid, 256, 0, stream>>>(xp3, kp3, h, tlist, ucount, rbest);
    }
    k_finalize<<<T_TOKENS / 256, 256, 0, stream>>>(rbest, tlist, ucount, idx);

    k_hist<<<T_TOKENS / 256, 256, 0, stream>>>(idx, counts);
    k_scan<<<1, 256, 0, stream>>>(counts, offs, cursor);
    k_place<<<T_TOKENS / 256, 256, 0, stream>>>(idx, cursor, tok);
    k_update<<<N_TOKEN / 4, 256, 0, stream>>>(x, ema_n, ema_w, counts, offs, tok,
                                              nsum, out_en, out_ew, out_kw);
    k_quant<<<(T_TOKENS * (N_EMBED / 4)) / 256, 256, 0, stream>>>(x, value_w, idx, out_q);
  } else if (ws_size >= ws_need1) {
    // ---------- R6 single-stage path ----------
    hipMemsetAsync(f_best, 0xFF, (size_t)T_TOKENS * 8, stream);
    k_pack_x<<<(T_TOKENS * (N_EMBED / 4)) / 256, 256, 0, stream>>>(x, f_xp);
    k_pack_k_norm<<<N_TOKEN / 4, 256, 0, stream>>>(key_w, f_kp, f_h);
    dim3 grid(N_TOKEN / BNr, T_TOKENS / BMr);
    k_mfma_argmin<<<grid, 256, 0, stream>>>(f_xp, f_kp, f_h, f_best);

    k_scaleN<<<N_TOKEN / 256, 256, 0, stream>>>(ema_n, out_en);
    k_extract_counts<<<T_TOKENS / 256, 256, 0, stream>>>(f_best, f_idx, out_en);
    k_scaleW<<<(N_TOKEN * (N_EMBED / 4)) / 256, 256, 0, stream>>>(ema_w, out_ew);
    k_quant_scatter<<<(T_TOKENS * (N_EMBED / 4)) / 256, 256, 0, stream>>>(
        x, value_w, f_idx, out_q, out_ew);
    k_sumn<<<1, 256, 0, stream>>>(out_en, f_nsum);
    k_keyw<<<(N_TOKEN * (N_EMBED / 4)) / 256, 256, 0, stream>>>(out_ew, out_en, f_nsum, out_kw);
  } else {
    // ---------- deep fallback: f32 vector GEMM ----------
    hipMemsetAsync(f_best, 0xFF, (size_t)T_TOKENS * 8, stream);
    k_hnorm<<<N_TOKEN / 4, 256, 0, stream>>>(key_w, f_h);
    dim3 grid(N_TOKEN / BK, T_TOKENS / BT);
    k_gemm_argmin<<<grid, 256, 0, stream>>>(x, key_w, f_h, f_best);

    k_scaleN<<<N_TOKEN / 256, 256, 0, stream>>>(ema_n, out_en);
    k_extract_counts<<<T_TOKENS / 256, 256, 0, stream>>>(f_best, f_idx, out_en);
    k_scaleW<<<(N_TOKEN * (N_EMBED / 4)) / 256, 256, 0, stream>>>(ema_w, out_ew);
    k_quant_scatter<<<(T_TOKENS * (N_EMBED / 4)) / 256, 256, 0, stream>>>(
        x, value_w, f_idx, out_q, out_ew);
    k_sumn<<<1, 256, 0, stream>>>(out_en, f_nsum);
    k_keyw<<<(N_TOKEN * (N_EMBED / 4)) / 256, 256, 0, stream>>>(out_ew, out_en, f_nsum, out_kw);
  }
}

// Round 9
// 442.032 us; speedup vs baseline: 1.9136x; 1.0744x over previous
//
#include <hip/hip_runtime.h>

#define N_TOKEN 8192
#define N_EMBED 512
#define T_TOKENS 16384
#define KP 1536       // packed K = 3 * 512
#define MARGIN 0.6f   // score-gap certainty threshold (~6.7 sigma of approx error)

typedef __bf16 bf16x8 __attribute__((ext_vector_type(8)));
typedef __bf16 bf16x4 __attribute__((ext_vector_type(4)));
typedef float f32x4 __attribute__((ext_vector_type(4)));

// ---------- helpers ----------
__device__ __forceinline__ unsigned int fkey(float f) {
  unsigned int u = __float_as_uint(f);
  return (u & 0x80000000u) ? ~u : (u | 0x80000000u);
}
__device__ __forceinline__ void gl2lds16(const void* gsrc, void* lds) {
  __builtin_amdgcn_global_load_lds(
      (const __attribute__((address_space(1))) unsigned int*)gsrc,
      (__attribute__((address_space(3))) unsigned int*)lds, 16, 0, 0);
}
__device__ __forceinline__ unsigned long long umin64(unsigned long long a,
                                                     unsigned long long b) {
  return a < b ? a : b;
}

// ---------- pack x: f32 -> [hi|hi|lo] bf16 ----------
__global__ void k_pack_x(const float* __restrict__ x, __bf16* __restrict__ xp) {
  int gid = blockIdx.x * blockDim.x + threadIdx.x;  // float4 index
  int t = gid >> 7, d4 = gid & 127;
  float4 v = reinterpret_cast<const float4*>(x)[gid];
  bf16x4 hi, lo;
  hi[0] = (__bf16)v.x; hi[1] = (__bf16)v.y; hi[2] = (__bf16)v.z; hi[3] = (__bf16)v.w;
  lo[0] = (__bf16)(v.x - (float)hi[0]);
  lo[1] = (__bf16)(v.y - (float)hi[1]);
  lo[2] = (__bf16)(v.z - (float)hi[2]);
  lo[3] = (__bf16)(v.w - (float)hi[3]);
  __bf16* row = xp + (size_t)t * KP + d4 * 4;
  *(bf16x4*)(row)        = hi;
  *(bf16x4*)(row + 512)  = hi;
  *(bf16x4*)(row + 1024) = lo;
}

// ---------- pack key + norm (fused): kp = [hi|lo|hi], h = 0.5*||k||^2 ----------
__global__ void k_pack_k_norm(const float* __restrict__ kw, __bf16* __restrict__ kp,
                              float* __restrict__ h) {
  int row = blockIdx.x * 4 + (threadIdx.x >> 6);
  int lane = threadIdx.x & 63;
  const float4* src = reinterpret_cast<const float4*>(kw + (size_t)row * N_EMBED);
  __bf16* dst = kp + (size_t)row * KP;
  float s = 0.f;
  #pragma unroll
  for (int c = 0; c < 2; ++c) {
    int f4 = lane + c * 64;  // 0..127
    float4 v = src[f4];
    s += v.x*v.x + v.y*v.y + v.z*v.z + v.w*v.w;
    bf16x4 hi, lo;
    hi[0] = (__bf16)v.x; hi[1] = (__bf16)v.y; hi[2] = (__bf16)v.z; hi[3] = (__bf16)v.w;
    lo[0] = (__bf16)(v.x - (float)hi[0]);
    lo[1] = (__bf16)(v.y - (float)hi[1]);
    lo[2] = (__bf16)(v.z - (float)hi[2]);
    lo[3] = (__bf16)(v.w - (float)hi[3]);
    *(bf16x4*)(dst + f4 * 4)        = hi;
    *(bf16x4*)(dst + 512 + f4 * 4)  = lo;
    *(bf16x4*)(dst + 1024 + f4 * 4) = hi;
  }
  #pragma unroll
  for (int off = 32; off; off >>= 1) s += __shfl_down(s, off);
  if (lane == 0) h[row] = 0.5f * s;
}

// ---------- norms only (deep fallback) ----------
__global__ void k_hnorm(const float* __restrict__ key_w, float* __restrict__ h) {
  int code = blockIdx.x * 4 + (threadIdx.x >> 6);
  int lane = threadIdx.x & 63;
  const float4* row = reinterpret_cast<const float4*>(key_w + (size_t)code * N_EMBED);
  float s = 0.f;
  float4 v0 = row[lane];
  float4 v1 = row[lane + 64];
  s += v0.x*v0.x + v0.y*v0.y + v0.z*v0.z + v0.w*v0.w;
  s += v1.x*v1.x + v1.y*v1.y + v1.z*v1.z + v1.w*v1.w;
  #pragma unroll
  for (int off = 32; off; off >>= 1) s += __shfl_down(s, off);
  if (lane == 0) h[code] = 0.5f * s;
}

#define BMr 128
#define BNr 128
#define BKe 64   // bf16 elements per K-step (128 B per row)

// ---------- PASS 1: K=512 hi*hi GEMM; wave = 32 rows x 128 cols (acc[2][8]) --
// Per-row top-2 over the whole block's 128 cols in one wave -> 1 slot per
// (row, nb). Ties / near-ties route to refine via the margin test.
__global__ __launch_bounds__(256) void k_mfma_top2(
    const __bf16* __restrict__ xp, const __bf16* __restrict__ kp,
    const float* __restrict__ h, float4* __restrict__ slots) {
  __shared__ __bf16 AS[BMr * BKe];
  __shared__ __bf16 BS[BNr * BKe];

  const int nb = blockIdx.x, mb = blockIdx.y;
  const int m0 = mb * BMr, n0 = nb * BNr;
  const int tid = threadIdx.x;
  const int lane = tid & 63;
  const int wid = tid >> 6;
  const int wm = wid * 32;           // 4 waves x 32 rows = 128 rows

  f32x4 acc[2][8] = {};
  const int soff = tid * 16;

  for (int ks = 0; ks < 512; ks += BKe) {   // hi columns only
    __syncthreads();
    #pragma unroll
    for (int i = 0; i < 4; ++i) {
      int off = i * 4096 + soff;
      int row = off >> 7;
      int inner = (off & 127) ^ ((row & 7) << 4);
      gl2lds16(xp + (size_t)(m0 + row) * KP + ks + (inner >> 1), (char*)AS + off);
      gl2lds16(kp + (size_t)(n0 + row) * KP + ks + (inner >> 1), (char*)BS + off);
    }
    asm volatile("s_waitcnt vmcnt(0)" ::: "memory");
    __syncthreads();

    #pragma unroll
    for (int kk = 0; kk < 2; ++kk) {
      const int cbyte = kk * 64 + (lane >> 4) * 16;
      bf16x8 af[2], bb[8];
      #pragma unroll
      for (int i = 0; i < 2; ++i) {
        int arow = wm + i * 16 + (lane & 15);
        af[i] = *(const bf16x8*)((const char*)AS + arow * 128 + (cbyte ^ ((arow & 7) << 4)));
      }
      #pragma unroll
      for (int j = 0; j < 8; ++j) {
        int brow = j * 16 + (lane & 15);
        bb[j] = *(const bf16x8*)((const char*)BS + brow * 128 + (cbyte ^ ((brow & 7) << 4)));
      }
      #pragma unroll
      for (int i = 0; i < 2; ++i)
        #pragma unroll
        for (int j = 0; j < 8; ++j)
          acc[i][j] = __builtin_amdgcn_mfma_f32_16x16x32_bf16(af[i], bb[j], acc[i][j], 0, 0, 0);
    }
  }

  // epilogue: per-row top-2 over 128 cols; one slot per (row, nb)
  const int rgrp = lane >> 4;
  const int cidx = lane & 15;
  #pragma unroll
  for (int i = 0; i < 2; ++i) {
    #pragma unroll
    for (int r = 0; r < 4; ++r) {
      float s1 = 3.4e38f, s2 = 3.4e38f;
      int c1 = 0;
      #pragma unroll
      for (int j = 0; j < 8; ++j) {
        int kk = n0 + j * 16 + cidx;
        float sc = h[kk] - acc[i][j][r];
        if (sc < s1) { s2 = s1; s1 = sc; c1 = kk; }
        else s2 = fminf(s2, sc);
      }
      #pragma unroll
      for (int msk = 1; msk < 16; msk <<= 1) {
        float o1 = __shfl_xor(s1, msk);
        float o2 = __shfl_xor(s2, msk);
        int   oc = __shfl_xor(c1, msk);
        float ns2 = fminf(fminf(s2, o2), fmaxf(s1, o1));
        bool take = o1 < s1;
        s1 = take ? o1 : s1;
        c1 = take ? oc : c1;
        s2 = ns2;
      }
      if (cidx == 0) {
        int row = m0 + wm + i * 16 + rgrp * 4 + r;
        float4 p;
        p.x = s1; p.y = s2; p.z = __int_as_float(c1); p.w = 0.f;
        slots[(size_t)row * 64 + nb] = p;
      }
    }
  }
}

// ---------- reduce: global top-2 (64 slots) -> certain idx (+count) or list --
__global__ void k_top2_reduce(const float4* __restrict__ slots,
                              int* __restrict__ idx, unsigned int* __restrict__ tlist,
                              unsigned int* __restrict__ ucount,
                              int* __restrict__ counts) {
  int row = blockIdx.x * 4 + (threadIdx.x >> 6);
  int lane = threadIdx.x & 63;
  float4 a = slots[(size_t)row * 64 + lane];
  float s1 = a.x, s2 = a.y; int c1 = __float_as_int(a.z);
  #pragma unroll
  for (int msk = 1; msk < 64; msk <<= 1) {
    float o1 = __shfl_xor(s1, msk);
    float o2 = __shfl_xor(s2, msk);
    int   oc = __shfl_xor(c1, msk);
    float ns2 = fminf(fminf(s2, o2), fmaxf(s1, o1));
    bool take = o1 < s1;
    s1 = take ? o1 : s1;
    c1 = take ? oc : c1;
    s2 = ns2;
  }
  if (lane == 0) {
    if (s2 - s1 >= MARGIN) {
      idx[row] = c1;
      atomicAdd(&counts[c1], 1);
    } else {
      unsigned int p = atomicAdd(ucount, 1u);
      tlist[p] = (unsigned int)row;
    }
  }
}

// ---------- REFINE: 3-term K=1536 exact-class GEMM over uncertain tokens ----
__global__ __launch_bounds__(256) void k_mfma_refine(
    const __bf16* __restrict__ xp, const __bf16* __restrict__ kp,
    const float* __restrict__ h, const unsigned int* __restrict__ tlist,
    const unsigned int* __restrict__ ucount, unsigned long long* __restrict__ rbest) {
  const unsigned int uc = *ucount;
  const int nb = blockIdx.x, mb = blockIdx.y;
  const int m0 = mb * BMr;
  if ((unsigned int)m0 >= uc) return;

  __shared__ __bf16 AS[BMr * BKe];
  __shared__ __bf16 BS[BNr * BKe];

  const int n0 = nb * BNr;
  const int tid = threadIdx.x;
  const int lane = tid & 63;
  const int wid = tid >> 6;
  const int wm = (wid >> 1) * 64, wn = (wid & 1) * 64;

  const int r0 = tid >> 3;  // 0..31
  size_t abase[4];
  #pragma unroll
  for (int i = 0; i < 4; ++i) {
    int p = m0 + r0 + 32 * i;
    int pc = p < (int)uc ? p : (int)uc - 1;
    abase[i] = (size_t)tlist[pc] * KP;
  }

  f32x4 acc[4][4] = {};
  const int soff = tid * 16;
  const int innerC = (soff & 127) ^ ((r0 & 7) << 4);

  for (int ks = 0; ks < KP; ks += BKe) {
    __syncthreads();
    #pragma unroll
    for (int i = 0; i < 4; ++i) {
      int off = i * 4096 + soff;
      int brow = (off >> 7);
      gl2lds16(xp + abase[i] + ks + (innerC >> 1), (char*)AS + off);
      int binner = (off & 127) ^ ((brow & 7) << 4);
      gl2lds16(kp + (size_t)(n0 + brow) * KP + ks + (binner >> 1), (char*)BS + off);
    }
    asm volatile("s_waitcnt vmcnt(0)" ::: "memory");
    __syncthreads();

    #pragma unroll
    for (int kk = 0; kk < 2; ++kk) {
      const int cbyte = kk * 64 + (lane >> 4) * 16;
      bf16x8 af[4], bb[4];
      #pragma unroll
      for (int i = 0; i < 4; ++i) {
        int arow = wm + i * 16 + (lane & 15);
        af[i] = *(const bf16x8*)((const char*)AS + arow * 128 + (cbyte ^ ((arow & 7) << 4)));
        int brow = wn + i * 16 + (lane & 15);
        bb[i] = *(const bf16x8*)((const char*)BS + brow * 128 + (cbyte ^ ((brow & 7) << 4)));
      }
      #pragma unroll
      for (int i = 0; i < 4; ++i)
        #pragma unroll
        for (int j = 0; j < 4; ++j)
          acc[i][j] = __builtin_amdgcn_mfma_f32_16x16x32_bf16(af[i], bb[j], acc[i][j], 0, 0, 0);
    }
  }

  const int rgrp = lane >> 4;
  const int cidx = lane & 15;
  #pragma unroll
  for (int i = 0; i < 4; ++i) {
    #pragma unroll
    for (int r = 0; r < 4; ++r) {
      unsigned long long m = ~0ull;
      #pragma unroll
      for (int j = 0; j < 4; ++j) {
        int kk = n0 + wn + j * 16 + cidx;
        float score = h[kk] - acc[i][j][r];
        unsigned long long cand =
            ((unsigned long long)fkey(score) << 32) | (unsigned int)kk;
        m = umin64(m, cand);
      }
      #pragma unroll
      for (int msk = 1; msk < 16; msk <<= 1) m = umin64(m, __shfl_xor(m, msk));
      if (cidx == 0) {
        int p = m0 + wm + i * 16 + rgrp * 4 + r;
        if ((unsigned int)p < uc) atomicMin(&rbest[p], m);
      }
    }
  }
}

// ---------- finalize: uncertain rows get refined index (+count) ----------
__global__ void k_finalize(const unsigned long long* __restrict__ rbest,
                           const unsigned int* __restrict__ tlist,
                           const unsigned int* __restrict__ ucount,
                           int* __restrict__ idx, int* __restrict__ counts) {
  unsigned int p = blockIdx.x * 256 + threadIdx.x;
  if (p < *ucount) {
    int k = (int)(unsigned int)(rbest[p] & 0xffffffffull);
    idx[tlist[p]] = k;
    atomicAdd(&counts[k], 1);
  }
}

// ---------- counting-sort CSR + fused EMA update ----------
__global__ void k_sum_ema_n(const float* __restrict__ ema_n, float* __restrict__ nsum) {
  __shared__ float sm[256];
  float s = 0.f;
  for (int i = threadIdx.x; i < N_TOKEN; i += 256) s += ema_n[i];
  sm[threadIdx.x] = s;
  __syncthreads();
  for (int off = 128; off; off >>= 1) {
    if (threadIdx.x < off) sm[threadIdx.x] += sm[threadIdx.x + off];
    __syncthreads();
  }
  if (threadIdx.x == 0) *nsum = sm[0];
}

__global__ void k_scan(const int* __restrict__ counts, int* __restrict__ offs,
                       int* __restrict__ cursor) {
  __shared__ int sa[256], sb[256];
  int tid = threadIdx.x;
  int base = tid * 32;
  int loc[32]; int s = 0;
  #pragma unroll
  for (int e = 0; e < 32; ++e) { loc[e] = s; s += counts[base + e]; }
  sa[tid] = s;
  __syncthreads();
  int* src = sa; int* dst = sb;
  for (int d = 1; d < 256; d <<= 1) {
    int v = src[tid] + (tid >= d ? src[tid - d] : 0);
    dst[tid] = v;
    __syncthreads();
    int* tmp = src; src = dst; dst = tmp;
  }
  int excl = src[tid] - s;
  #pragma unroll
  for (int e = 0; e < 32; ++e) {
    int o = excl + loc[e];
    offs[base + e] = o;
    cursor[base + e] = o;
  }
}

__global__ void k_place(const int* __restrict__ idx, int* __restrict__ cursor,
                        int* __restrict__ tok) {
  int t = blockIdx.x * 256 + threadIdx.x;
  if (t < T_TOKENS) {
    int p = atomicAdd(&cursor[idx[t]], 1);
    tok[p] = t;
  }
}

// one wave per code: en, ew = 0.99*ema_w + 0.005*sum(x[tok]), kw = ew/sz
__global__ void k_update(const float* __restrict__ x, const float* __restrict__ ema_n,
                         const float* __restrict__ ema_w, const int* __restrict__ counts,
                         const int* __restrict__ offs, const int* __restrict__ tok,
                         const float* __restrict__ nsum,
                         float* __restrict__ out_en, float* __restrict__ out_ew,
                         float* __restrict__ out_kw) {
  int k = blockIdx.x * 4 + (threadIdx.x >> 6);
  int lane = threadIdx.x & 63;
  int cnt = counts[k];
  int off = offs[k];
  float en = 0.99f * ema_n[k] + 0.005f * (float)cnt;
  if (lane == 0) out_en[k] = en;
  float n = 0.99f * (*nsum) + 81.92f;   // 0.005 * 16384
  float sz = (en + 1e-8f) / (n + 1e-8f * (float)N_TOKEN) * n;

  const float4* er = reinterpret_cast<const float4*>(ema_w + (size_t)k * N_EMBED);
  float4 e0 = er[lane], e1 = er[lane + 64];
  float4 s0 = {0.f, 0.f, 0.f, 0.f}, s1v = {0.f, 0.f, 0.f, 0.f};
  for (int q = 0; q < cnt; ++q) {
    int t = tok[off + q];
    const float4* xr = reinterpret_cast<const float4*>(x + (size_t)t * N_EMBED);
    float4 a = xr[lane], b = xr[lane + 64];
    s0.x += a.x; s0.y += a.y; s0.z += a.z; s0.w += a.w;
    s1v.x += b.x; s1v.y += b.y; s1v.z += b.z; s1v.w += b.w;
  }
  float4 w0, w1;
  w0.x = 0.99f * e0.x + 0.005f * s0.x;  w0.y = 0.99f * e0.y + 0.005f * s0.y;
  w0.z = 0.99f * e0.z + 0.005f * s0.z;  w0.w = 0.99f * e0.w + 0.005f * s0.w;
  w1.x = 0.99f * e1.x + 0.005f * s1v.x; w1.y = 0.99f * e1.y + 0.005f * s1v.y;
  w1.z = 0.99f * e1.z + 0.005f * s1v.z; w1.w = 0.99f * e1.w + 0.005f * s1v.w;
  float4* ow = reinterpret_cast<float4*>(out_ew + (size_t)k * N_EMBED);
  ow[lane] = w0; ow[lane + 64] = w1;
  float4 q0, q1;
  q0.x = w0.x / sz; q0.y = w0.y / sz; q0.z = w0.z / sz; q0.w = w0.w / sz;
  q1.x = w1.x / sz; q1.y = w1.y / sz; q1.z = w1.z / sz; q1.w = w1.w / sz;
  float4* okw = reinterpret_cast<float4*>(out_kw + (size_t)k * N_EMBED);
  okw[lane] = q0; okw[lane + 64] = q1;
}

// ---------- quantized = x + value_w[idx] (no atomics) ----------
__global__ void k_quant(const float* __restrict__ x, const float* __restrict__ value_w,
                        const int* __restrict__ idx, float* __restrict__ q) {
  int gid = blockIdx.x * blockDim.x + threadIdx.x;
  int t = gid >> 7, d4 = gid & 127;
  float4 xv = reinterpret_cast<const float4*>(x)[gid];
  float4 v = reinterpret_cast<const float4*>(value_w + (size_t)idx[t] * N_EMBED)[d4];
  float4 o;
  o.x = xv.x + v.x; o.y = xv.y + v.y; o.z = xv.z + v.z; o.w = xv.w + v.w;
  reinterpret_cast<float4*>(q)[gid] = o;
}

// ---------- single-stage MFMA GEMM + argmin (R6-proven; ws fallback) ----------
__global__ __launch_bounds__(256) void k_mfma_argmin(
    const __bf16* __restrict__ xp, const __bf16* __restrict__ kp,
    const float* __restrict__ h, unsigned long long* __restrict__ best) {
  __shared__ __bf16 AS[BMr * BKe];
  __shared__ __bf16 BS[BNr * BKe];
  const int nb = blockIdx.x, mb = blockIdx.y;
  const int m0 = mb * BMr, n0 = nb * BNr;
  const int tid = threadIdx.x;
  const int lane = tid & 63;
  const int wid = tid >> 6;
  const int wm = (wid >> 1) * 64, wn = (wid & 1) * 64;
  f32x4 acc[4][4] = {};
  const int soff = tid * 16;
  for (int ks = 0; ks < KP; ks += BKe) {
    __syncthreads();
    #pragma unroll
    for (int i = 0; i < 4; ++i) {
      int off = i * 4096 + soff;
      int row = off >> 7;
      int inner = (off & 127) ^ ((row & 7) << 4);
      gl2lds16(xp + (size_t)(m0 + row) * KP + ks + (inner >> 1), (char*)AS + off);
      gl2lds16(kp + (size_t)(n0 + row) * KP + ks + (inner >> 1), (char*)BS + off);
    }
    asm volatile("s_waitcnt vmcnt(0)" ::: "memory");
    __syncthreads();
    #pragma unroll
    for (int kk = 0; kk < 2; ++kk) {
      const int cbyte = kk * 64 + (lane >> 4) * 16;
      bf16x8 af[4], bb[4];
      #pragma unroll
      for (int i = 0; i < 4; ++i) {
        int arow = wm + i * 16 + (lane & 15);
        af[i] = *(const bf16x8*)((const char*)AS + arow * 128 + (cbyte ^ ((arow & 7) << 4)));
        int brow = wn + i * 16 + (lane & 15);
        bb[i] = *(const bf16x8*)((const char*)BS + brow * 128 + (cbyte ^ ((brow & 7) << 4)));
      }
      #pragma unroll
      for (int i = 0; i < 4; ++i)
        #pragma unroll
        for (int j = 0; j < 4; ++j)
          acc[i][j] = __builtin_amdgcn_mfma_f32_16x16x32_bf16(af[i], bb[j], acc[i][j], 0, 0, 0);
    }
  }
  const int rgrp = lane >> 4;
  const int cidx = lane & 15;
  #pragma unroll
  for (int i = 0; i < 4; ++i) {
    #pragma unroll
    for (int r = 0; r < 4; ++r) {
      unsigned long long m = ~0ull;
      #pragma unroll
      for (int j = 0; j < 4; ++j) {
        int kk = n0 + wn + j * 16 + cidx;
        float score = h[kk] - acc[i][j][r];
        unsigned long long cand =
            ((unsigned long long)fkey(score) << 32) | (unsigned int)kk;
        m = umin64(m, cand);
      }
      #pragma unroll
      for (int msk = 1; msk < 16; msk <<= 1) m = umin64(m, __shfl_xor(m, msk));
      if (cidx == 0) {
        int row = m0 + wm + i * 16 + rgrp * 4 + r;
        atomicMin(&best[row], m);
      }
    }
  }
}

// ---------- f32 fallback GEMM+argmin ----------
#define BT 128
#define BK 128
#define DC 32
__global__ __launch_bounds__(256, 2) void k_gemm_argmin(
    const float* __restrict__ x, const float* __restrict__ key_w,
    const float* __restrict__ h, unsigned long long* __restrict__ best) {
  __shared__ float4 XS[BT * 8];
  __shared__ float4 KS[BK * 8];
  const int kb = blockIdx.x, tb = blockIdx.y;
  const int t0 = tb * BT, k0 = kb * BK;
  const int tid = threadIdx.x;
  const int tx = tid & 15;
  const int tyg = tid >> 4;
  float acc[8][8];
  #pragma unroll
  for (int i = 0; i < 8; ++i)
    #pragma unroll
    for (int j = 0; j < 8; ++j) acc[i][j] = 0.f;
  for (int dc = 0; dc < N_EMBED; dc += DC) {
    __syncthreads();
    #pragma unroll
    for (int ld = 0; ld < 4; ++ld) {
      int li = ld * 256 + tid;
      int row = li >> 3, c4 = li & 7;
      XS[row * 8 + (c4 ^ (row & 7))] =
          *reinterpret_cast<const float4*>(x + (size_t)(t0 + row) * N_EMBED + dc + c4 * 4);
      KS[row * 8 + (c4 ^ (row & 7))] =
          *reinterpret_cast<const float4*>(key_w + (size_t)(k0 + row) * N_EMBED + dc + c4 * 4);
    }
    __syncthreads();
    #pragma unroll
    for (int d4 = 0; d4 < 8; ++d4) {
      float4 a[8], b[8];
      #pragma unroll
      for (int j = 0; j < 8; ++j) {
        a[j] = XS[(tyg + 16 * j) * 8 + (d4 ^ (tyg & 7))];
        b[j] = KS[(tx  + 16 * j) * 8 + (d4 ^ (tx  & 7))];
      }
      #pragma unroll
      for (int i = 0; i < 8; ++i) {
        float4 av = a[i];
        #pragma unroll
        for (int j = 0; j < 8; ++j) {
          float4 bv = b[j];
          acc[i][j] = fmaf(av.x, bv.x, fmaf(av.y, bv.y,
                      fmaf(av.z, bv.z, fmaf(av.w, bv.w, acc[i][j]))));
        }
      }
    }
  }
  #pragma unroll
  for (int i = 0; i < 8; ++i) {
    unsigned long long m = ~0ull;
    #pragma unroll
    for (int j = 0; j < 8; ++j) {
      int kk = k0 + tx + 16 * j;
      float score = h[kk] - acc[i][j];
      unsigned long long cand =
          ((unsigned long long)fkey(score) << 32) | (unsigned int)kk;
      m = umin64(m, cand);
    }
    #pragma unroll
    for (int mask = 1; mask < 16; mask <<= 1) m = umin64(m, __shfl_xor(m, mask));
    if (tx == 0) atomicMin(&best[t0 + tyg + 16 * i], m);
  }
}

// ---------- legacy aux (fallback paths) ----------
__global__ void k_extract_counts(const unsigned long long* __restrict__ best,
                                 int* __restrict__ idx, float* __restrict__ out_en) {
  int t = blockIdx.x * blockDim.x + threadIdx.x;
  if (t < T_TOKENS) {
    int k = (int)(unsigned int)(best[t] & 0xffffffffull);
    idx[t] = k;
    atomicAdd(&out_en[k], 0.005f);
  }
}
__global__ void k_quant_scatter(const float* __restrict__ x,
                                const float* __restrict__ value_w,
                                const int* __restrict__ idx,
                                float* __restrict__ q, float* __restrict__ out_ew) {
  int gid = blockIdx.x * blockDim.x + threadIdx.x;
  int t = gid >> 7, d4 = gid & 127;
  float4 xv = reinterpret_cast<const float4*>(x)[gid];
  int k = idx[t];
  float4 v = reinterpret_cast<const float4*>(value_w + (size_t)k * N_EMBED)[d4];
  float4 o;
  o.x = xv.x + v.x; o.y = xv.y + v.y; o.z = xv.z + v.z; o.w = xv.w + v.w;
  reinterpret_cast<float4*>(q)[gid] = o;
  const float c = 0.005f;
  float* dst = out_ew + (size_t)k * N_EMBED + d4 * 4;
  atomicAdd(dst + 0, c * xv.x);
  atomicAdd(dst + 1, c * xv.y);
  atomicAdd(dst + 2, c * xv.z);
  atomicAdd(dst + 3, c * xv.w);
}
__global__ void k_scaleN(const float* __restrict__ ema_n, float* __restrict__ out_en) {
  int k = blockIdx.x * blockDim.x + threadIdx.x;
  if (k < N_TOKEN) out_en[k] = 0.99f * ema_n[k];
}
__global__ void k_scaleW(const float* __restrict__ ema_w, float* __restrict__ out_ew) {
  int gid = blockIdx.x * blockDim.x + threadIdx.x;
  float4 v = reinterpret_cast<const float4*>(ema_w)[gid];
  float4 o;
  o.x = 0.99f * v.x; o.y = 0.99f * v.y; o.z = 0.99f * v.z; o.w = 0.99f * v.w;
  reinterpret_cast<float4*>(out_ew)[gid] = o;
}
__global__ void k_sumn(const float* __restrict__ en, float* __restrict__ nsum) {
  __shared__ float sm[256];
  float s = 0.f;
  for (int i = threadIdx.x; i < N_TOKEN; i += 256) s += en[i];
  sm[threadIdx.x] = s;
  __syncthreads();
  for (int off = 128; off; off >>= 1) {
    if (threadIdx.x < off) sm[threadIdx.x] += sm[threadIdx.x + off];
    __syncthreads();
  }
  if (threadIdx.x == 0) *nsum = sm[0];
}
__global__ void k_keyw(const float* __restrict__ out_ew, const float* __restrict__ out_en,
                       const float* __restrict__ nsum, float* __restrict__ out_kw) {
  int gid = blockIdx.x * blockDim.x + threadIdx.x;
  int k = gid >> 7;
  float n = *nsum;
  float sz = (out_en[k] + 1e-8f) / (n + 1e-8f * (float)N_TOKEN) * n;
  float4 w = reinterpret_cast<const float4*>(out_ew)[gid];
  float4 o;
  o.x = w.x / sz; o.y = w.y / sz; o.z = w.z / sz; o.w = w.w / sz;
  reinterpret_cast<float4*>(out_kw)[gid] = o;
}

// ---------- launcher ----------
extern "C" void kernel_launch(void* const* d_in, const int* in_sizes, int n_in,
                              void* d_out, int out_size, void* d_ws, size_t ws_size,
                              hipStream_t stream) {
  const float* x       = (const float*)d_in[0];
  const float* key_w   = (const float*)d_in[1];
  const float* value_w = (const float*)d_in[2];
  const float* ema_n   = (const float*)d_in[3];
  const float* ema_w   = (const float*)d_in[4];

  float* out_q  = (float*)d_out;
  float* out_en = out_q + 8388608;
  float* out_ew = out_en + N_TOKEN;
  float* out_kw = out_ew + 4194304;

  // ---- two-stage layout ----
  const size_t SLOTS_B = (size_t)T_TOKENS * 64 * 16;               // 16 MiB
  const size_t XP_B    = (size_t)T_TOKENS * KP * 2;                // 48 MiB
  const size_t KP_B    = (size_t)N_TOKEN * KP * 2;                 // 24 MiB
  char* base = (char*)d_ws;
  float4* slots = (float4*)base;
  __bf16* xp3 = (__bf16*)(base + SLOTS_B);
  __bf16* kp3 = (__bf16*)(base + SLOTS_B + XP_B);
  char* tail  = base + SLOTS_B + XP_B + KP_B;
  float* h                  = (float*)(tail + 0);         // 32 KiB
  int*   idx                = (int*)(tail + 32768);       // 64 KiB
  unsigned int* tlist       = (unsigned int*)(tail + 98304);   // 64 KiB
  unsigned long long* rbest = (unsigned long long*)(tail + 163840);  // 128 KiB
  unsigned int* ucount      = (unsigned int*)(tail + 294912);  // 256 B
  float* nsum               = (float*)(tail + 295168);    // 256 B
  int* counts               = (int*)(tail + 295424);      // 32 KiB
  int* offs                 = (int*)(tail + 328192);      // 32 KiB
  int* cursor               = (int*)(tail + 360960);      // 32 KiB
  int* tok                  = (int*)(tail + 393728);      // 64 KiB
  const size_t ws_need2 = SLOTS_B + XP_B + KP_B + 459264;

  // ---- R6 single-stage layout (fallback) ----
  unsigned long long* f_best = (unsigned long long*)d_ws;
  int*   f_idx  = (int*)((char*)d_ws + 131072);
  float* f_h    = (float*)((char*)d_ws + 196608);
  float* f_nsum = (float*)((char*)d_ws + 229376);
  __bf16* f_xp  = (__bf16*)((char*)d_ws + 262144);
  __bf16* f_kp  = (__bf16*)((char*)d_ws + 262144 + XP_B);
  const size_t ws_need1 = 262144 + XP_B + KP_B;

  if (ws_size >= ws_need2) {
    // ---------- two-stage path ----------
    hipMemsetAsync(rbest, 0xFF, (size_t)T_TOKENS * 8, stream);
    hipMemsetAsync(ucount, 0, 4, stream);
    hipMemsetAsync(counts, 0, N_TOKEN * 4, stream);
    k_sum_ema_n<<<1, 256, 0, stream>>>(ema_n, nsum);
    k_pack_x<<<(T_TOKENS * (N_EMBED / 4)) / 256, 256, 0, stream>>>(x, xp3);
    k_pack_k_norm<<<N_TOKEN / 4, 256, 0, stream>>>(key_w, kp3, h);
    {
      dim3 grid(N_TOKEN / BNr, T_TOKENS / BMr);
      k_mfma_top2<<<grid, 256, 0, stream>>>(xp3, kp3, h, slots);
    }
    k_top2_reduce<<<T_TOKENS / 4, 256, 0, stream>>>(slots, idx, tlist, ucount, counts);
    {
      dim3 grid(N_TOKEN / BNr, T_TOKENS / BMr);
      k_mfma_refine<<<grid, 256, 0, stream>>>(xp3, kp3, h, tlist, ucount, rbest);
    }
    k_finalize<<<T_TOKENS / 256, 256, 0, stream>>>(rbest, tlist, ucount, idx, counts);

    k_scan<<<1, 256, 0, stream>>>(counts, offs, cursor);
    k_place<<<T_TOKENS / 256, 256, 0, stream>>>(idx, cursor, tok);
    k_update<<<N_TOKEN / 4, 256, 0, stream>>>(x, ema_n, ema_w, counts, offs, tok,
                                              nsum, out_en, out_ew, out_kw);
    k_quant<<<(T_TOKENS * (N_EMBED / 4)) / 256, 256, 0, stream>>>(x, value_w, idx, out_q);
  } else if (ws_size >= ws_need1) {
    // ---------- R6 single-stage path ----------
    hipMemsetAsync(f_best, 0xFF, (size_t)T_TOKENS * 8, stream);
    k_pack_x<<<(T_TOKENS * (N_EMBED / 4)) / 256, 256, 0, stream>>>(x, f_xp);
    k_pack_k_norm<<<N_TOKEN / 4, 256, 0, stream>>>(key_w, f_kp, f_h);
    dim3 grid(N_TOKEN / BNr, T_TOKENS / BMr);
    k_mfma_argmin<<<grid, 256, 0, stream>>>(f_xp, f_kp, f_h, f_best);

    k_scaleN<<<N_TOKEN / 256, 256, 0, stream>>>(ema_n, out_en);
    k_extract_counts<<<T_TOKENS / 256, 256, 0, stream>>>(f_best, f_idx, out_en);
    k_scaleW<<<(N_TOKEN * (N_EMBED / 4)) / 256, 256, 0, stream>>>(ema_w, out_ew);
    k_quant_scatter<<<(T_TOKENS * (N_EMBED / 4)) / 256, 256, 0, stream>>>(
        x, value_w, f_idx, out_q, out_ew);
    k_sumn<<<1, 256, 0, stream>>>(out_en, f_nsum);
    k_keyw<<<(N_TOKEN * (N_EMBED / 4)) / 256, 256, 0, stream>>>(out_ew, out_en, f_nsum, out_kw);
  } else {
    // ---------- deep fallback: f32 vector GEMM ----------
    hipMemsetAsync(f_best, 0xFF, (size_t)T_TOKENS * 8, stream);
    k_hnorm<<<N_TOKEN / 4, 256, 0, stream>>>(key_w, f_h);
    dim3 grid(N_TOKEN / BK, T_TOKENS / BT);
    k_gemm_argmin<<<grid, 256, 0, stream>>>(x, key_w, f_h, f_best);

    k_scaleN<<<N_TOKEN / 256, 256, 0, stream>>>(ema_n, out_en);
    k_extract_counts<<<T_TOKENS / 256, 256, 0, stream>>>(f_best, f_idx, out_en);
    k_scaleW<<<(N_TOKEN * (N_EMBED / 4)) / 256, 256, 0, stream>>>(ema_w, out_ew);
    k_quant_scatter<<<(T_TOKENS * (N_EMBED / 4)) / 256, 256, 0, stream>>>(
        x, value_w, f_idx, out_q, out_ew);
    k_sumn<<<1, 256, 0, stream>>>(out_en, f_nsum);
    k_keyw<<<(N_TOKEN * (N_EMBED / 4)) / 256, 256, 0, stream>>>(out_ew, out_en, f_nsum, out_kw);
  }
}

// Round 10
// 415.410 us; speedup vs baseline: 2.0363x; 1.0641x over previous
//
#include <hip/hip_runtime.h>

#define N_TOKEN 8192
#define N_EMBED 512
#define T_TOKENS 16384
#define KP 1536       // packed K = 3 * 512
#define MARGIN 0.6f   // score-gap certainty threshold (~6.7 sigma of approx error)

typedef __bf16 bf16x8 __attribute__((ext_vector_type(8)));
typedef __bf16 bf16x4 __attribute__((ext_vector_type(4)));
typedef float f32x4 __attribute__((ext_vector_type(4)));

// ---------- helpers ----------
__device__ __forceinline__ unsigned int fkey(float f) {
  unsigned int u = __float_as_uint(f);
  return (u & 0x80000000u) ? ~u : (u | 0x80000000u);
}
__device__ __forceinline__ void gl2lds16(const void* gsrc, void* lds) {
  __builtin_amdgcn_global_load_lds(
      (const __attribute__((address_space(1))) unsigned int*)gsrc,
      (__attribute__((address_space(3))) unsigned int*)lds, 16, 0, 0);
}
__device__ __forceinline__ unsigned long long umin64(unsigned long long a,
                                                     unsigned long long b) {
  return a < b ? a : b;
}

// ---------- pack x: f32 -> [hi|hi|lo] bf16 ----------
__global__ void k_pack_x(const float* __restrict__ x, __bf16* __restrict__ xp) {
  int gid = blockIdx.x * blockDim.x + threadIdx.x;  // float4 index
  int t = gid >> 7, d4 = gid & 127;
  float4 v = reinterpret_cast<const float4*>(x)[gid];
  bf16x4 hi, lo;
  hi[0] = (__bf16)v.x; hi[1] = (__bf16)v.y; hi[2] = (__bf16)v.z; hi[3] = (__bf16)v.w;
  lo[0] = (__bf16)(v.x - (float)hi[0]);
  lo[1] = (__bf16)(v.y - (float)hi[1]);
  lo[2] = (__bf16)(v.z - (float)hi[2]);
  lo[3] = (__bf16)(v.w - (float)hi[3]);
  __bf16* row = xp + (size_t)t * KP + d4 * 4;
  *(bf16x4*)(row)        = hi;
  *(bf16x4*)(row + 512)  = hi;
  *(bf16x4*)(row + 1024) = lo;
}

// ---------- pack key + norm (fused): kp = [hi|lo|hi], h = 0.5*||k||^2 ----------
__global__ void k_pack_k_norm(const float* __restrict__ kw, __bf16* __restrict__ kp,
                              float* __restrict__ h) {
  int row = blockIdx.x * 4 + (threadIdx.x >> 6);
  int lane = threadIdx.x & 63;
  const float4* src = reinterpret_cast<const float4*>(kw + (size_t)row * N_EMBED);
  __bf16* dst = kp + (size_t)row * KP;
  float s = 0.f;
  #pragma unroll
  for (int c = 0; c < 2; ++c) {
    int f4 = lane + c * 64;  // 0..127
    float4 v = src[f4];
    s += v.x*v.x + v.y*v.y + v.z*v.z + v.w*v.w;
    bf16x4 hi, lo;
    hi[0] = (__bf16)v.x; hi[1] = (__bf16)v.y; hi[2] = (__bf16)v.z; hi[3] = (__bf16)v.w;
    lo[0] = (__bf16)(v.x - (float)hi[0]);
    lo[1] = (__bf16)(v.y - (float)hi[1]);
    lo[2] = (__bf16)(v.z - (float)hi[2]);
    lo[3] = (__bf16)(v.w - (float)hi[3]);
    *(bf16x4*)(dst + f4 * 4)        = hi;
    *(bf16x4*)(dst + 512 + f4 * 4)  = lo;
    *(bf16x4*)(dst + 1024 + f4 * 4) = hi;
  }
  #pragma unroll
  for (int off = 32; off; off >>= 1) s += __shfl_down(s, off);
  if (lane == 0) h[row] = 0.5f * s;
}

// ---------- norms only (deep fallback) ----------
__global__ void k_hnorm(const float* __restrict__ key_w, float* __restrict__ h) {
  int code = blockIdx.x * 4 + (threadIdx.x >> 6);
  int lane = threadIdx.x & 63;
  const float4* row = reinterpret_cast<const float4*>(key_w + (size_t)code * N_EMBED);
  float s = 0.f;
  float4 v0 = row[lane];
  float4 v1 = row[lane + 64];
  s += v0.x*v0.x + v0.y*v0.y + v0.z*v0.z + v0.w*v0.w;
  s += v1.x*v1.x + v1.y*v1.y + v1.z*v1.z + v1.w*v1.w;
  #pragma unroll
  for (int off = 32; off; off >>= 1) s += __shfl_down(s, off);
  if (lane == 0) h[code] = 0.5f * s;
}

#define BMr 128
#define BNr 128
#define BKe 64   // bf16 elements per K-step (128 B per row)

// ---------- PASS 1: K=512 hi*hi GEMM; 4 nb tiles per block; wave = 32x128 ----
// Running per-lane top-2 across the 4 nb tiles; one butterfly per group.
__global__ __launch_bounds__(256) void k_mfma_top2(
    const __bf16* __restrict__ xp, const __bf16* __restrict__ kp,
    const float* __restrict__ h, float4* __restrict__ slots) {
  __shared__ __bf16 AS[BMr * BKe];
  __shared__ __bf16 BS[BNr * BKe];

  const int nbg = blockIdx.x, mb = blockIdx.y;
  const int m0 = mb * BMr;
  const int tid = threadIdx.x;
  const int lane = tid & 63;
  const int wid = tid >> 6;
  const int wm = wid * 32;           // 4 waves x 32 rows = 128 rows
  const int soff = tid * 16;
  const int rgrp = lane >> 4;
  const int cidx = lane & 15;

  float rs1[8], rs2[8];
  int rc1[8];
  #pragma unroll
  for (int u = 0; u < 8; ++u) { rs1[u] = 3.4e38f; rs2[u] = 3.4e38f; rc1[u] = 0; }

  for (int q = 0; q < 4; ++q) {
    const int n0 = (nbg * 4 + q) * BNr;
    f32x4 acc[2][8] = {};

    for (int ks = 0; ks < 512; ks += BKe) {   // hi columns only
      __syncthreads();
      #pragma unroll
      for (int i = 0; i < 4; ++i) {
        int off = i * 4096 + soff;
        int row = off >> 7;
        int inner = (off & 127) ^ ((row & 7) << 4);
        gl2lds16(xp + (size_t)(m0 + row) * KP + ks + (inner >> 1), (char*)AS + off);
        gl2lds16(kp + (size_t)(n0 + row) * KP + ks + (inner >> 1), (char*)BS + off);
      }
      asm volatile("s_waitcnt vmcnt(0)" ::: "memory");
      __syncthreads();

      #pragma unroll
      for (int kk = 0; kk < 2; ++kk) {
        const int cbyte = kk * 64 + (lane >> 4) * 16;
        bf16x8 af[2], bb[8];
        #pragma unroll
        for (int i = 0; i < 2; ++i) {
          int arow = wm + i * 16 + (lane & 15);
          af[i] = *(const bf16x8*)((const char*)AS + arow * 128 + (cbyte ^ ((arow & 7) << 4)));
        }
        #pragma unroll
        for (int j = 0; j < 8; ++j) {
          int brow = j * 16 + (lane & 15);
          bb[j] = *(const bf16x8*)((const char*)BS + brow * 128 + (cbyte ^ ((brow & 7) << 4)));
        }
        #pragma unroll
        for (int i = 0; i < 2; ++i)
          #pragma unroll
          for (int j = 0; j < 8; ++j)
            acc[i][j] = __builtin_amdgcn_mfma_f32_16x16x32_bf16(af[i], bb[j], acc[i][j], 0, 0, 0);
      }
    }

    // insert this tile's 8 scores per output row into running top-2
    #pragma unroll
    for (int i = 0; i < 2; ++i) {
      #pragma unroll
      for (int r = 0; r < 4; ++r) {
        const int u = i * 4 + r;
        float s1 = rs1[u], s2 = rs2[u];
        int c1 = rc1[u];
        #pragma unroll
        for (int j = 0; j < 8; ++j) {
          int kk = n0 + j * 16 + cidx;
          float sc = h[kk] - acc[i][j][r];
          if (sc < s1) { s2 = s1; s1 = sc; c1 = kk; }
          else s2 = fminf(s2, sc);
        }
        rs1[u] = s1; rs2[u] = s2; rc1[u] = c1;
      }
    }
  }

  // one butterfly per output row; slot per (row, nbg)
  #pragma unroll
  for (int u = 0; u < 8; ++u) {
    float s1 = rs1[u], s2 = rs2[u];
    int c1 = rc1[u];
    #pragma unroll
    for (int msk = 1; msk < 16; msk <<= 1) {
      float o1 = __shfl_xor(s1, msk);
      float o2 = __shfl_xor(s2, msk);
      int   oc = __shfl_xor(c1, msk);
      float ns2 = fminf(fminf(s2, o2), fmaxf(s1, o1));
      bool take = o1 < s1;
      s1 = take ? o1 : s1;
      c1 = take ? oc : c1;
      s2 = ns2;
    }
    if (cidx == 0) {
      int row = m0 + wm + (u >> 2) * 16 + rgrp * 4 + (u & 3);
      float4 p;
      p.x = s1; p.y = s2; p.z = __int_as_float(c1); p.w = 0.f;
      slots[(size_t)row * 16 + nbg] = p;
    }
  }
}

// ---------- reduce: global top-2 (16 slots) -> certain idx (+count) or list --
__global__ void k_top2_reduce(const float4* __restrict__ slots,
                              int* __restrict__ idx, unsigned int* __restrict__ tlist,
                              unsigned int* __restrict__ ucount,
                              int* __restrict__ counts,
                              unsigned long long* __restrict__ rbest) {
  int tid = threadIdx.x;
  int lane = tid & 63, wid = tid >> 6;
  int row = blockIdx.x * 16 + wid * 4 + (lane >> 4);
  int slot = lane & 15;
  float4 a = slots[(size_t)row * 16 + slot];
  float s1 = a.x, s2 = a.y;
  int c1 = __float_as_int(a.z);
  #pragma unroll
  for (int msk = 1; msk < 16; msk <<= 1) {
    float o1 = __shfl_xor(s1, msk);
    float o2 = __shfl_xor(s2, msk);
    int   oc = __shfl_xor(c1, msk);
    float ns2 = fminf(fminf(s2, o2), fmaxf(s1, o1));
    bool take = o1 < s1;
    s1 = take ? o1 : s1;
    c1 = take ? oc : c1;
    s2 = ns2;
  }
  if (slot == 0) {
    if (s2 - s1 >= MARGIN) {
      idx[row] = c1;
      atomicAdd(&counts[c1], 1);
    } else {
      unsigned int p = atomicAdd(ucount, 1u);
      tlist[p] = (unsigned int)row;
      rbest[p] = ~0ull;   // init for refine's atomicMin
    }
  }
}

// ---------- REFINE: 3-term K=1536 exact-class GEMM over uncertain tokens ----
__global__ __launch_bounds__(256) void k_mfma_refine(
    const __bf16* __restrict__ xp, const __bf16* __restrict__ kp,
    const float* __restrict__ h, const unsigned int* __restrict__ tlist,
    const unsigned int* __restrict__ ucount, unsigned long long* __restrict__ rbest) {
  const unsigned int uc = *ucount;
  const int nb = blockIdx.x, mb = blockIdx.y;
  const int m0 = mb * BMr;
  if ((unsigned int)m0 >= uc) return;

  __shared__ __bf16 AS[BMr * BKe];
  __shared__ __bf16 BS[BNr * BKe];

  const int n0 = nb * BNr;
  const int tid = threadIdx.x;
  const int lane = tid & 63;
  const int wid = tid >> 6;
  const int wm = (wid >> 1) * 64, wn = (wid & 1) * 64;

  const int r0 = tid >> 3;  // 0..31
  size_t abase[4];
  #pragma unroll
  for (int i = 0; i < 4; ++i) {
    int p = m0 + r0 + 32 * i;
    int pc = p < (int)uc ? p : (int)uc - 1;
    abase[i] = (size_t)tlist[pc] * KP;
  }

  f32x4 acc[4][4] = {};
  const int soff = tid * 16;
  const int innerC = (soff & 127) ^ ((r0 & 7) << 4);

  for (int ks = 0; ks < KP; ks += BKe) {
    __syncthreads();
    #pragma unroll
    for (int i = 0; i < 4; ++i) {
      int off = i * 4096 + soff;
      int brow = (off >> 7);
      gl2lds16(xp + abase[i] + ks + (innerC >> 1), (char*)AS + off);
      int binner = (off & 127) ^ ((brow & 7) << 4);
      gl2lds16(kp + (size_t)(n0 + brow) * KP + ks + (binner >> 1), (char*)BS + off);
    }
    asm volatile("s_waitcnt vmcnt(0)" ::: "memory");
    __syncthreads();

    #pragma unroll
    for (int kk = 0; kk < 2; ++kk) {
      const int cbyte = kk * 64 + (lane >> 4) * 16;
      bf16x8 af[4], bb[4];
      #pragma unroll
      for (int i = 0; i < 4; ++i) {
        int arow = wm + i * 16 + (lane & 15);
        af[i] = *(const bf16x8*)((const char*)AS + arow * 128 + (cbyte ^ ((arow & 7) << 4)));
        int brow = wn + i * 16 + (lane & 15);
        bb[i] = *(const bf16x8*)((const char*)BS + brow * 128 + (cbyte ^ ((brow & 7) << 4)));
      }
      #pragma unroll
      for (int i = 0; i < 4; ++i)
        #pragma unroll
        for (int j = 0; j < 4; ++j)
          acc[i][j] = __builtin_amdgcn_mfma_f32_16x16x32_bf16(af[i], bb[j], acc[i][j], 0, 0, 0);
    }
  }

  const int rgrp = lane >> 4;
  const int cidx = lane & 15;
  #pragma unroll
  for (int i = 0; i < 4; ++i) {
    #pragma unroll
    for (int r = 0; r < 4; ++r) {
      unsigned long long m = ~0ull;
      #pragma unroll
      for (int j = 0; j < 4; ++j) {
        int kk = n0 + wn + j * 16 + cidx;
        float score = h[kk] - acc[i][j][r];
        unsigned long long cand =
            ((unsigned long long)fkey(score) << 32) | (unsigned int)kk;
        m = umin64(m, cand);
      }
      #pragma unroll
      for (int msk = 1; msk < 16; msk <<= 1) m = umin64(m, __shfl_xor(m, msk));
      if (cidx == 0) {
        int p = m0 + wm + i * 16 + rgrp * 4 + r;
        if ((unsigned int)p < uc) atomicMin(&rbest[p], m);
      }
    }
  }
}

// ---------- finalize: uncertain rows get refined index (+count) ----------
__global__ void k_finalize(const unsigned long long* __restrict__ rbest,
                           const unsigned int* __restrict__ tlist,
                           const unsigned int* __restrict__ ucount,
                           int* __restrict__ idx, int* __restrict__ counts) {
  unsigned int p = blockIdx.x * 256 + threadIdx.x;
  if (p < *ucount) {
    int k = (int)(unsigned int)(rbest[p] & 0xffffffffull);
    idx[tlist[p]] = k;
    atomicAdd(&counts[k], 1);
  }
}

// ---------- counting-sort CSR + fused EMA update ----------
__global__ void k_sum_ema_n(const float* __restrict__ ema_n, float* __restrict__ nsum) {
  __shared__ float sm[256];
  float s = 0.f;
  for (int i = threadIdx.x; i < N_TOKEN; i += 256) s += ema_n[i];
  sm[threadIdx.x] = s;
  __syncthreads();
  for (int off = 128; off; off >>= 1) {
    if (threadIdx.x < off) sm[threadIdx.x] += sm[threadIdx.x + off];
    __syncthreads();
  }
  if (threadIdx.x == 0) *nsum = sm[0];
}

__global__ void k_scan(const int* __restrict__ counts, int* __restrict__ offs,
                       int* __restrict__ cursor) {
  __shared__ int sa[256], sb[256];
  int tid = threadIdx.x;
  int base = tid * 32;
  int loc[32]; int s = 0;
  #pragma unroll
  for (int e = 0; e < 32; ++e) { loc[e] = s; s += counts[base + e]; }
  sa[tid] = s;
  __syncthreads();
  int* src = sa; int* dst = sb;
  for (int d = 1; d < 256; d <<= 1) {
    int v = src[tid] + (tid >= d ? src[tid - d] : 0);
    dst[tid] = v;
    __syncthreads();
    int* tmp = src; src = dst; dst = tmp;
  }
  int excl = src[tid] - s;
  #pragma unroll
  for (int e = 0; e < 32; ++e) {
    int o = excl + loc[e];
    offs[base + e] = o;
    cursor[base + e] = o;
  }
}

__global__ void k_place(const int* __restrict__ idx, int* __restrict__ cursor,
                        int* __restrict__ tok) {
  int t = blockIdx.x * 256 + threadIdx.x;
  if (t < T_TOKENS) {
    int p = atomicAdd(&cursor[idx[t]], 1);
    tok[p] = t;
  }
}

// one wave per code: en; ew = 0.99*ema_w + 0.005*sum(x[tok]); kw = ew/sz;
// and quantized[t] = x[t] + value_w[k] for each token of this code (fused).
__global__ void k_update(const float* __restrict__ x, const float* __restrict__ ema_n,
                         const float* __restrict__ ema_w, const float* __restrict__ value_w,
                         const int* __restrict__ counts,
                         const int* __restrict__ offs, const int* __restrict__ tok,
                         const float* __restrict__ nsum,
                         float* __restrict__ out_en, float* __restrict__ out_ew,
                         float* __restrict__ out_kw, float* __restrict__ out_q) {
  int k = blockIdx.x * 4 + (threadIdx.x >> 6);
  int lane = threadIdx.x & 63;
  int cnt = counts[k];
  int off = offs[k];
  float en = 0.99f * ema_n[k] + 0.005f * (float)cnt;
  if (lane == 0) out_en[k] = en;
  float n = 0.99f * (*nsum) + 81.92f;   // 0.005 * 16384
  float sz = (en + 1e-8f) / (n + 1e-8f * (float)N_TOKEN) * n;

  const float4* er = reinterpret_cast<const float4*>(ema_w + (size_t)k * N_EMBED);
  float4 e0 = er[lane], e1 = er[lane + 64];
  const float4* vr = reinterpret_cast<const float4*>(value_w + (size_t)k * N_EMBED);
  float4 v0 = vr[lane], v1 = vr[lane + 64];
  float4 s0 = {0.f, 0.f, 0.f, 0.f}, s1v = {0.f, 0.f, 0.f, 0.f};
  for (int q = 0; q < cnt; ++q) {
    int t = tok[off + q];
    const float4* xr = reinterpret_cast<const float4*>(x + (size_t)t * N_EMBED);
    float4 a = xr[lane], b = xr[lane + 64];
    s0.x += a.x; s0.y += a.y; s0.z += a.z; s0.w += a.w;
    s1v.x += b.x; s1v.y += b.y; s1v.z += b.z; s1v.w += b.w;
    float4 qa, qb;
    qa.x = a.x + v0.x; qa.y = a.y + v0.y; qa.z = a.z + v0.z; qa.w = a.w + v0.w;
    qb.x = b.x + v1.x; qb.y = b.y + v1.y; qb.z = b.z + v1.z; qb.w = b.w + v1.w;
    float4* oq = reinterpret_cast<float4*>(out_q + (size_t)t * N_EMBED);
    oq[lane] = qa; oq[lane + 64] = qb;
  }
  float4 w0, w1;
  w0.x = 0.99f * e0.x + 0.005f * s0.x;  w0.y = 0.99f * e0.y + 0.005f * s0.y;
  w0.z = 0.99f * e0.z + 0.005f * s0.z;  w0.w = 0.99f * e0.w + 0.005f * s0.w;
  w1.x = 0.99f * e1.x + 0.005f * s1v.x; w1.y = 0.99f * e1.y + 0.005f * s1v.y;
  w1.z = 0.99f * e1.z + 0.005f * s1v.z; w1.w = 0.99f * e1.w + 0.005f * s1v.w;
  float4* ow = reinterpret_cast<float4*>(out_ew + (size_t)k * N_EMBED);
  ow[lane] = w0; ow[lane + 64] = w1;
  float4 q0, q1;
  q0.x = w0.x / sz; q0.y = w0.y / sz; q0.z = w0.z / sz; q0.w = w0.w / sz;
  q1.x = w1.x / sz; q1.y = w1.y / sz; q1.z = w1.z / sz; q1.w = w1.w / sz;
  float4* okw = reinterpret_cast<float4*>(out_kw + (size_t)k * N_EMBED);
  okw[lane] = q0; okw[lane + 64] = q1;
}

// ---------- quantized = x + value_w[idx] (fallback paths only) ----------
__global__ void k_quant(const float* __restrict__ x, const float* __restrict__ value_w,
                        const int* __restrict__ idx, float* __restrict__ q) {
  int gid = blockIdx.x * blockDim.x + threadIdx.x;
  int t = gid >> 7, d4 = gid & 127;
  float4 xv = reinterpret_cast<const float4*>(x)[gid];
  float4 v = reinterpret_cast<const float4*>(value_w + (size_t)idx[t] * N_EMBED)[d4];
  float4 o;
  o.x = xv.x + v.x; o.y = xv.y + v.y; o.z = xv.z + v.z; o.w = xv.w + v.w;
  reinterpret_cast<float4*>(q)[gid] = o;
}

// ---------- single-stage MFMA GEMM + argmin (R6-proven; ws fallback) ----------
__global__ __launch_bounds__(256) void k_mfma_argmin(
    const __bf16* __restrict__ xp, const __bf16* __restrict__ kp,
    const float* __restrict__ h, unsigned long long* __restrict__ best) {
  __shared__ __bf16 AS[BMr * BKe];
  __shared__ __bf16 BS[BNr * BKe];
  const int nb = blockIdx.x, mb = blockIdx.y;
  const int m0 = mb * BMr, n0 = nb * BNr;
  const int tid = threadIdx.x;
  const int lane = tid & 63;
  const int wid = tid >> 6;
  const int wm = (wid >> 1) * 64, wn = (wid & 1) * 64;
  f32x4 acc[4][4] = {};
  const int soff = tid * 16;
  for (int ks = 0; ks < KP; ks += BKe) {
    __syncthreads();
    #pragma unroll
    for (int i = 0; i < 4; ++i) {
      int off = i * 4096 + soff;
      int row = off >> 7;
      int inner = (off & 127) ^ ((row & 7) << 4);
      gl2lds16(xp + (size_t)(m0 + row) * KP + ks + (inner >> 1), (char*)AS + off);
      gl2lds16(kp + (size_t)(n0 + row) * KP + ks + (inner >> 1), (char*)BS + off);
    }
    asm volatile("s_waitcnt vmcnt(0)" ::: "memory");
    __syncthreads();
    #pragma unroll
    for (int kk = 0; kk < 2; ++kk) {
      const int cbyte = kk * 64 + (lane >> 4) * 16;
      bf16x8 af[4], bb[4];
      #pragma unroll
      for (int i = 0; i < 4; ++i) {
        int arow = wm + i * 16 + (lane & 15);
        af[i] = *(const bf16x8*)((const char*)AS + arow * 128 + (cbyte ^ ((arow & 7) << 4)));
        int brow = wn + i * 16 + (lane & 15);
        bb[i] = *(const bf16x8*)((const char*)BS + brow * 128 + (cbyte ^ ((brow & 7) << 4)));
      }
      #pragma unroll
      for (int i = 0; i < 4; ++i)
        #pragma unroll
        for (int j = 0; j < 4; ++j)
          acc[i][j] = __builtin_amdgcn_mfma_f32_16x16x32_bf16(af[i], bb[j], acc[i][j], 0, 0, 0);
    }
  }
  const int rgrp = lane >> 4;
  const int cidx = lane & 15;
  #pragma unroll
  for (int i = 0; i < 4; ++i) {
    #pragma unroll
    for (int r = 0; r < 4; ++r) {
      unsigned long long m = ~0ull;
      #pragma unroll
      for (int j = 0; j < 4; ++j) {
        int kk = n0 + wn + j * 16 + cidx;
        float score = h[kk] - acc[i][j][r];
        unsigned long long cand =
            ((unsigned long long)fkey(score) << 32) | (unsigned int)kk;
        m = umin64(m, cand);
      }
      #pragma unroll
      for (int msk = 1; msk < 16; msk <<= 1) m = umin64(m, __shfl_xor(m, msk));
      if (cidx == 0) {
        int row = m0 + wm + i * 16 + rgrp * 4 + r;
        atomicMin(&best[row], m);
      }
    }
  }
}

// ---------- f32 fallback GEMM+argmin ----------
#define BT 128
#define BK 128
#define DC 32
__global__ __launch_bounds__(256, 2) void k_gemm_argmin(
    const float* __restrict__ x, const float* __restrict__ key_w,
    const float* __restrict__ h, unsigned long long* __restrict__ best) {
  __shared__ float4 XS[BT * 8];
  __shared__ float4 KS[BK * 8];
  const int kb = blockIdx.x, tb = blockIdx.y;
  const int t0 = tb * BT, k0 = kb * BK;
  const int tid = threadIdx.x;
  const int tx = tid & 15;
  const int tyg = tid >> 4;
  float acc[8][8];
  #pragma unroll
  for (int i = 0; i < 8; ++i)
    #pragma unroll
    for (int j = 0; j < 8; ++j) acc[i][j] = 0.f;
  for (int dc = 0; dc < N_EMBED; dc += DC) {
    __syncthreads();
    #pragma unroll
    for (int ld = 0; ld < 4; ++ld) {
      int li = ld * 256 + tid;
      int row = li >> 3, c4 = li & 7;
      XS[row * 8 + (c4 ^ (row & 7))] =
          *reinterpret_cast<const float4*>(x + (size_t)(t0 + row) * N_EMBED + dc + c4 * 4);
      KS[row * 8 + (c4 ^ (row & 7))] =
          *reinterpret_cast<const float4*>(key_w + (size_t)(k0 + row) * N_EMBED + dc + c4 * 4);
    }
    __syncthreads();
    #pragma unroll
    for (int d4 = 0; d4 < 8; ++d4) {
      float4 a[8], b[8];
      #pragma unroll
      for (int j = 0; j < 8; ++j) {
        a[j] = XS[(tyg + 16 * j) * 8 + (d4 ^ (tyg & 7))];
        b[j] = KS[(tx  + 16 * j) * 8 + (d4 ^ (tx  & 7))];
      }
      #pragma unroll
      for (int i = 0; i < 8; ++i) {
        float4 av = a[i];
        #pragma unroll
        for (int j = 0; j < 8; ++j) {
          float4 bv = b[j];
          acc[i][j] = fmaf(av.x, bv.x, fmaf(av.y, bv.y,
                      fmaf(av.z, bv.z, fmaf(av.w, bv.w, acc[i][j]))));
        }
      }
    }
  }
  #pragma unroll
  for (int i = 0; i < 8; ++i) {
    unsigned long long m = ~0ull;
    #pragma unroll
    for (int j = 0; j < 8; ++j) {
      int kk = k0 + tx + 16 * j;
      float score = h[kk] - acc[i][j];
      unsigned long long cand =
          ((unsigned long long)fkey(score) << 32) | (unsigned int)kk;
      m = umin64(m, cand);
    }
    #pragma unroll
    for (int mask = 1; mask < 16; mask <<= 1) m = umin64(m, __shfl_xor(m, mask));
    if (tx == 0) atomicMin(&best[t0 + tyg + 16 * i], m);
  }
}

// ---------- legacy aux (fallback paths) ----------
__global__ void k_extract_counts(const unsigned long long* __restrict__ best,
                                 int* __restrict__ idx, float* __restrict__ out_en) {
  int t = blockIdx.x * blockDim.x + threadIdx.x;
  if (t < T_TOKENS) {
    int k = (int)(unsigned int)(best[t] & 0xffffffffull);
    idx[t] = k;
    atomicAdd(&out_en[k], 0.005f);
  }
}
__global__ void k_quant_scatter(const float* __restrict__ x,
                                const float* __restrict__ value_w,
                                const int* __restrict__ idx,
                                float* __restrict__ q, float* __restrict__ out_ew) {
  int gid = blockIdx.x * blockDim.x + threadIdx.x;
  int t = gid >> 7, d4 = gid & 127;
  float4 xv = reinterpret_cast<const float4*>(x)[gid];
  int k = idx[t];
  float4 v = reinterpret_cast<const float4*>(value_w + (size_t)k * N_EMBED)[d4];
  float4 o;
  o.x = xv.x + v.x; o.y = xv.y + v.y; o.z = xv.z + v.z; o.w = xv.w + v.w;
  reinterpret_cast<float4*>(q)[gid] = o;
  const float c = 0.005f;
  float* dst = out_ew + (size_t)k * N_EMBED + d4 * 4;
  atomicAdd(dst + 0, c * xv.x);
  atomicAdd(dst + 1, c * xv.y);
  atomicAdd(dst + 2, c * xv.z);
  atomicAdd(dst + 3, c * xv.w);
}
__global__ void k_scaleN(const float* __restrict__ ema_n, float* __restrict__ out_en) {
  int k = blockIdx.x * blockDim.x + threadIdx.x;
  if (k < N_TOKEN) out_en[k] = 0.99f * ema_n[k];
}
__global__ void k_scaleW(const float* __restrict__ ema_w, float* __restrict__ out_ew) {
  int gid = blockIdx.x * blockDim.x + threadIdx.x;
  float4 v = reinterpret_cast<const float4*>(ema_w)[gid];
  float4 o;
  o.x = 0.99f * v.x; o.y = 0.99f * v.y; o.z = 0.99f * v.z; o.w = 0.99f * v.w;
  reinterpret_cast<float4*>(out_ew)[gid] = o;
}
__global__ void k_sumn(const float* __restrict__ en, float* __restrict__ nsum) {
  __shared__ float sm[256];
  float s = 0.f;
  for (int i = threadIdx.x; i < N_TOKEN; i += 256) s += en[i];
  sm[threadIdx.x] = s;
  __syncthreads();
  for (int off = 128; off; off >>= 1) {
    if (threadIdx.x < off) sm[threadIdx.x] += sm[threadIdx.x + off];
    __syncthreads();
  }
  if (threadIdx.x == 0) *nsum = sm[0];
}
__global__ void k_keyw(const float* __restrict__ out_ew, const float* __restrict__ out_en,
                       const float* __restrict__ nsum, float* __restrict__ out_kw) {
  int gid = blockIdx.x * blockDim.x + threadIdx.x;
  int k = gid >> 7;
  float n = *nsum;
  float sz = (out_en[k] + 1e-8f) / (n + 1e-8f * (float)N_TOKEN) * n;
  float4 w = reinterpret_cast<const float4*>(out_ew)[gid];
  float4 o;
  o.x = w.x / sz; o.y = w.y / sz; o.z = w.z / sz; o.w = w.w / sz;
  reinterpret_cast<float4*>(out_kw)[gid] = o;
}

// ---------- launcher ----------
extern "C" void kernel_launch(void* const* d_in, const int* in_sizes, int n_in,
                              void* d_out, int out_size, void* d_ws, size_t ws_size,
                              hipStream_t stream) {
  const float* x       = (const float*)d_in[0];
  const float* key_w   = (const float*)d_in[1];
  const float* value_w = (const float*)d_in[2];
  const float* ema_n   = (const float*)d_in[3];
  const float* ema_w   = (const float*)d_in[4];

  float* out_q  = (float*)d_out;
  float* out_en = out_q + 8388608;
  float* out_ew = out_en + N_TOKEN;
  float* out_kw = out_ew + 4194304;

  // ---- two-stage layout ----
  const size_t SLOTS_B = (size_t)T_TOKENS * 16 * 16;               // 4 MiB
  const size_t XP_B    = (size_t)T_TOKENS * KP * 2;                // 48 MiB
  const size_t KP_B    = (size_t)N_TOKEN * KP * 2;                 // 24 MiB
  char* base = (char*)d_ws;
  float4* slots = (float4*)base;
  __bf16* xp3 = (__bf16*)(base + SLOTS_B);
  __bf16* kp3 = (__bf16*)(base + SLOTS_B + XP_B);
  char* tail  = base + SLOTS_B + XP_B + KP_B;
  float* h                  = (float*)(tail + 0);         // 32 KiB
  int*   idx                = (int*)(tail + 32768);       // 64 KiB
  unsigned int* tlist       = (unsigned int*)(tail + 98304);   // 64 KiB
  unsigned long long* rbest = (unsigned long long*)(tail + 163840);  // 128 KiB
  unsigned int* ucount      = (unsigned int*)(tail + 294912);  // 256 B
  float* nsum               = (float*)(tail + 295168);    // 256 B
  int* counts               = (int*)(tail + 295424);      // 32 KiB
  int* offs                 = (int*)(tail + 328192);      // 32 KiB
  int* cursor               = (int*)(tail + 360960);      // 32 KiB
  int* tok                  = (int*)(tail + 393728);      // 64 KiB
  const size_t ws_need2 = SLOTS_B + XP_B + KP_B + 459264;

  // ---- R6 single-stage layout (fallback) ----
  unsigned long long* f_best = (unsigned long long*)d_ws;
  int*   f_idx  = (int*)((char*)d_ws + 131072);
  float* f_h    = (float*)((char*)d_ws + 196608);
  float* f_nsum = (float*)((char*)d_ws + 229376);
  __bf16* f_xp  = (__bf16*)((char*)d_ws + 262144);
  __bf16* f_kp  = (__bf16*)((char*)d_ws + 262144 + XP_B);
  const size_t ws_need1 = 262144 + XP_B + KP_B;

  if (ws_size >= ws_need2) {
    // ---------- two-stage path ----------
    hipMemsetAsync(ucount, 0, 4, stream);
    hipMemsetAsync(counts, 0, N_TOKEN * 4, stream);
    k_sum_ema_n<<<1, 256, 0, stream>>>(ema_n, nsum);
    k_pack_x<<<(T_TOKENS * (N_EMBED / 4)) / 256, 256, 0, stream>>>(x, xp3);
    k_pack_k_norm<<<N_TOKEN / 4, 256, 0, stream>>>(key_w, kp3, h);
    {
      dim3 grid(N_TOKEN / (BNr * 4), T_TOKENS / BMr);   // 16 x 128
      k_mfma_top2<<<grid, 256, 0, stream>>>(xp3, kp3, h, slots);
    }
    k_top2_reduce<<<T_TOKENS / 16, 256, 0, stream>>>(slots, idx, tlist, ucount,
                                                     counts, rbest);
    {
      dim3 grid(N_TOKEN / BNr, T_TOKENS / BMr);
      k_mfma_refine<<<grid, 256, 0, stream>>>(xp3, kp3, h, tlist, ucount, rbest);
    }
    k_finalize<<<T_TOKENS / 256, 256, 0, stream>>>(rbest, tlist, ucount, idx, counts);

    k_scan<<<1, 256, 0, stream>>>(counts, offs, cursor);
    k_place<<<T_TOKENS / 256, 256, 0, stream>>>(idx, cursor, tok);
    k_update<<<N_TOKEN / 4, 256, 0, stream>>>(x, ema_n, ema_w, value_w, counts,
                                              offs, tok, nsum,
                                              out_en, out_ew, out_kw, out_q);
  } else if (ws_size >= ws_need1) {
    // ---------- R6 single-stage path ----------
    hipMemsetAsync(f_best, 0xFF, (size_t)T_TOKENS * 8, stream);
    k_pack_x<<<(T_TOKENS * (N_EMBED / 4)) / 256, 256, 0, stream>>>(x, f_xp);
    k_pack_k_norm<<<N_TOKEN / 4, 256, 0, stream>>>(key_w, f_kp, f_h);
    dim3 grid(N_TOKEN / BNr, T_TOKENS / BMr);
    k_mfma_argmin<<<grid, 256, 0, stream>>>(f_xp, f_kp, f_h, f_best);

    k_scaleN<<<N_TOKEN / 256, 256, 0, stream>>>(ema_n, out_en);
    k_extract_counts<<<T_TOKENS / 256, 256, 0, stream>>>(f_best, f_idx, out_en);
    k_scaleW<<<(N_TOKEN * (N_EMBED / 4)) / 256, 256, 0, stream>>>(ema_w, out_ew);
    k_quant_scatter<<<(T_TOKENS * (N_EMBED / 4)) / 256, 256, 0, stream>>>(
        x, value_w, f_idx, out_q, out_ew);
    k_sumn<<<1, 256, 0, stream>>>(out_en, f_nsum);
    k_keyw<<<(N_TOKEN * (N_EMBED / 4)) / 256, 256, 0, stream>>>(out_ew, out_en, f_nsum, out_kw);
  } else {
    // ---------- deep fallback: f32 vector GEMM ----------
    hipMemsetAsync(f_best, 0xFF, (size_t)T_TOKENS * 8, stream);
    k_hnorm<<<N_TOKEN / 4, 256, 0, stream>>>(key_w, f_h);
    dim3 grid(N_TOKEN / BK, T_TOKENS / BT);
    k_gemm_argmin<<<grid, 256, 0, stream>>>(x, key_w, f_h, f_best);

    k_scaleN<<<N_TOKEN / 256, 256, 0, stream>>>(ema_n, out_en);
    k_extract_counts<<<T_TOKENS / 256, 256, 0, stream>>>(f_best, f_idx, out_en);
    k_scaleW<<<(N_TOKEN * (N_EMBED / 4)) / 256, 256, 0, stream>>>(ema_w, out_ew);
    k_quant_scatter<<<(T_TOKENS * (N_EMBED / 4)) / 256, 256, 0, stream>>>(
        x, value_w, f_idx, out_q, out_ew);
    k_sumn<<<1, 256, 0, stream>>>(out_en, f_nsum);
    k_keyw<<<(N_TOKEN * (N_EMBED / 4)) / 256, 256, 0, stream>>>(out_ew, out_en, f_nsum, out_kw);
  }
}

// Round 11
// 399.523 us; speedup vs baseline: 2.1172x; 1.0398x over previous
//
#include <hip/hip_runtime.h>

#define N_TOKEN 8192
#define N_EMBED 512
#define T_TOKENS 16384
#define KP 1536       // packed K = 3 * 512
#define MARGIN 0.6f   // score-gap certainty threshold (~6 sigma of approx error)
#define NBG 8         // nb tiles per top2 block

typedef __bf16 bf16x8 __attribute__((ext_vector_type(8)));
typedef __bf16 bf16x4 __attribute__((ext_vector_type(4)));
typedef float f32x4 __attribute__((ext_vector_type(4)));

// ---------- helpers ----------
__device__ __forceinline__ unsigned int fkey(float f) {
  unsigned int u = __float_as_uint(f);
  return (u & 0x80000000u) ? ~u : (u | 0x80000000u);
}
__device__ __forceinline__ void gl2lds16(const void* gsrc, void* lds) {
  __builtin_amdgcn_global_load_lds(
      (const __attribute__((address_space(1))) unsigned int*)gsrc,
      (__attribute__((address_space(3))) unsigned int*)lds, 16, 0, 0);
}
__device__ __forceinline__ unsigned long long umin64(unsigned long long a,
                                                     unsigned long long b) {
  return a < b ? a : b;
}

// ---------- pack bodies (shared by standalone + fused kernels) ----------
__device__ __forceinline__ void pack_x_body(const float* __restrict__ x,
                                            __bf16* __restrict__ xp, int gid) {
  int t = gid >> 7, d4 = gid & 127;
  float4 v = reinterpret_cast<const float4*>(x)[gid];
  bf16x4 hi, lo;
  hi[0] = (__bf16)v.x; hi[1] = (__bf16)v.y; hi[2] = (__bf16)v.z; hi[3] = (__bf16)v.w;
  lo[0] = (__bf16)(v.x - (float)hi[0]);
  lo[1] = (__bf16)(v.y - (float)hi[1]);
  lo[2] = (__bf16)(v.z - (float)hi[2]);
  lo[3] = (__bf16)(v.w - (float)hi[3]);
  __bf16* row = xp + (size_t)t * KP + d4 * 4;
  *(bf16x4*)(row)        = hi;
  *(bf16x4*)(row + 512)  = hi;
  *(bf16x4*)(row + 1024) = lo;
}

__device__ __forceinline__ void pack_k_body(const float* __restrict__ kw,
                                            __bf16* __restrict__ kp,
                                            float* __restrict__ h,
                                            int blk, int tid) {
  int row = blk * 4 + (tid >> 6);
  int lane = tid & 63;
  const float4* src = reinterpret_cast<const float4*>(kw + (size_t)row * N_EMBED);
  __bf16* dst = kp + (size_t)row * KP;
  float s = 0.f;
  #pragma unroll
  for (int c = 0; c < 2; ++c) {
    int f4 = lane + c * 64;
    float4 v = src[f4];
    s += v.x*v.x + v.y*v.y + v.z*v.z + v.w*v.w;
    bf16x4 hi, lo;
    hi[0] = (__bf16)v.x; hi[1] = (__bf16)v.y; hi[2] = (__bf16)v.z; hi[3] = (__bf16)v.w;
    lo[0] = (__bf16)(v.x - (float)hi[0]);
    lo[1] = (__bf16)(v.y - (float)hi[1]);
    lo[2] = (__bf16)(v.z - (float)hi[2]);
    lo[3] = (__bf16)(v.w - (float)hi[3]);
    *(bf16x4*)(dst + f4 * 4)        = hi;
    *(bf16x4*)(dst + 512 + f4 * 4)  = lo;
    *(bf16x4*)(dst + 1024 + f4 * 4) = hi;
  }
  #pragma unroll
  for (int off = 32; off; off >>= 1) s += __shfl_down(s, off);
  if (lane == 0) h[row] = 0.5f * s;
}

// ---------- fused prep: pack_x | pack_k+norm | sum(ema_n)+init ----------
__global__ void k_pack_all(const float* __restrict__ x, const float* __restrict__ kw,
                           const float* __restrict__ ema_n,
                           __bf16* __restrict__ xp, __bf16* __restrict__ kp,
                           float* __restrict__ h, float* __restrict__ nsum,
                           unsigned int* __restrict__ ucount, int* __restrict__ counts) {
  int b = blockIdx.x;
  if (b < 8192) {
    pack_x_body(x, xp, b * 256 + threadIdx.x);
  } else if (b < 10240) {
    pack_k_body(kw, kp, h, b - 8192, threadIdx.x);
  } else if (b == 10240) {
    __shared__ float sm[256];
    float s = 0.f;
    for (int i = threadIdx.x; i < N_TOKEN; i += 256) s += ema_n[i];
    sm[threadIdx.x] = s;
    __syncthreads();
    for (int off = 128; off; off >>= 1) {
      if (threadIdx.x < off) sm[threadIdx.x] += sm[threadIdx.x + off];
      __syncthreads();
    }
    if (threadIdx.x == 0) { *nsum = sm[0]; *ucount = 0u; }
  } else {
    for (int i = threadIdx.x; i < N_TOKEN; i += 256) counts[i] = 0;
  }
}

// ---------- standalone packs (fallback paths) ----------
__global__ void k_pack_x(const float* __restrict__ x, __bf16* __restrict__ xp) {
  pack_x_body(x, xp, blockIdx.x * blockDim.x + threadIdx.x);
}
__global__ void k_pack_k_norm(const float* __restrict__ kw, __bf16* __restrict__ kp,
                              float* __restrict__ h) {
  pack_k_body(kw, kp, h, blockIdx.x, threadIdx.x);
}

// ---------- norms only (deep fallback) ----------
__global__ void k_hnorm(const float* __restrict__ key_w, float* __restrict__ h) {
  int code = blockIdx.x * 4 + (threadIdx.x >> 6);
  int lane = threadIdx.x & 63;
  const float4* row = reinterpret_cast<const float4*>(key_w + (size_t)code * N_EMBED);
  float s = 0.f;
  float4 v0 = row[lane];
  float4 v1 = row[lane + 64];
  s += v0.x*v0.x + v0.y*v0.y + v0.z*v0.z + v0.w*v0.w;
  s += v1.x*v1.x + v1.y*v1.y + v1.z*v1.z + v1.w*v1.w;
  #pragma unroll
  for (int off = 32; off; off >>= 1) s += __shfl_down(s, off);
  if (lane == 0) h[code] = 0.5f * s;
}

#define BMr 128
#define BNr 128
#define BKe 64   // refine K-step (128 B rows)

// ---------- PASS 1: K=512 hi*hi GEMM; BK=128 (4 K-steps); 8 nb tiles/block ---
// wave = 32 rows x 128 cols (acc[2][8]); running top-2, one butterfly per 8.
__global__ __launch_bounds__(256) void k_mfma_top2(
    const __bf16* __restrict__ xp, const __bf16* __restrict__ kp,
    const float* __restrict__ h, float4* __restrict__ slots) {
  __shared__ __bf16 AS[128 * 128];  // 32 KB, 256 B rows
  __shared__ __bf16 BS[128 * 128];  // 32 KB

  const int nbg = blockIdx.x, mb = blockIdx.y;
  const int m0 = mb * BMr;
  const int tid = threadIdx.x;
  const int lane = tid & 63;
  const int wid = tid >> 6;
  const int wm = wid * 32;           // 4 waves x 32 rows
  const int soff = tid * 16;
  const int rgrp = lane >> 4;
  const int cidx = lane & 15;

  float rs1[8], rs2[8];
  int rc1[8];
  #pragma unroll
  for (int u = 0; u < 8; ++u) { rs1[u] = 3.4e38f; rs2[u] = 3.4e38f; rc1[u] = 0; }

  for (int q = 0; q < NBG; ++q) {
    const int n0 = (nbg * NBG + q) * BNr;
    f32x4 acc[2][8] = {};

    for (int ks = 0; ks < 512; ks += 128) {   // hi columns, 256 B rows
      __syncthreads();
      #pragma unroll
      for (int i = 0; i < 8; ++i) {
        int off = i * 4096 + soff;
        int row = off >> 8;
        int inner = (off & 255) ^ ((row & 7) << 4);
        gl2lds16(xp + (size_t)(m0 + row) * KP + ks + (inner >> 1), (char*)AS + off);
        gl2lds16(kp + (size_t)(n0 + row) * KP + ks + (inner >> 1), (char*)BS + off);
      }
      asm volatile("s_waitcnt vmcnt(0)" ::: "memory");
      __syncthreads();

      #pragma unroll
      for (int kk = 0; kk < 4; ++kk) {
        const int cbyte = kk * 64 + (lane >> 4) * 16;
        bf16x8 af[2], bb[8];
        #pragma unroll
        for (int i = 0; i < 2; ++i) {
          int arow = wm + i * 16 + (lane & 15);
          af[i] = *(const bf16x8*)((const char*)AS + arow * 256 + (cbyte ^ ((arow & 7) << 4)));
        }
        #pragma unroll
        for (int j = 0; j < 8; ++j) {
          int brow = j * 16 + (lane & 15);
          bb[j] = *(const bf16x8*)((const char*)BS + brow * 256 + (cbyte ^ ((brow & 7) << 4)));
        }
        #pragma unroll
        for (int i = 0; i < 2; ++i)
          #pragma unroll
          for (int j = 0; j < 8; ++j)
            acc[i][j] = __builtin_amdgcn_mfma_f32_16x16x32_bf16(af[i], bb[j], acc[i][j], 0, 0, 0);
      }
    }

    // insert this tile's 8 scores per output row into running top-2
    #pragma unroll
    for (int i = 0; i < 2; ++i) {
      #pragma unroll
      for (int r = 0; r < 4; ++r) {
        const int u = i * 4 + r;
        float s1 = rs1[u], s2 = rs2[u];
        int c1 = rc1[u];
        #pragma unroll
        for (int j = 0; j < 8; ++j) {
          int kk = n0 + j * 16 + cidx;
          float sc = h[kk] - acc[i][j][r];
          if (sc < s1) { s2 = s1; s1 = sc; c1 = kk; }
          else s2 = fminf(s2, sc);
        }
        rs1[u] = s1; rs2[u] = s2; rc1[u] = c1;
      }
    }
  }

  // one butterfly per output row; slot per (row, nbg)
  #pragma unroll
  for (int u = 0; u < 8; ++u) {
    float s1 = rs1[u], s2 = rs2[u];
    int c1 = rc1[u];
    #pragma unroll
    for (int msk = 1; msk < 16; msk <<= 1) {
      float o1 = __shfl_xor(s1, msk);
      float o2 = __shfl_xor(s2, msk);
      int   oc = __shfl_xor(c1, msk);
      float ns2 = fminf(fminf(s2, o2), fmaxf(s1, o1));
      bool take = o1 < s1;
      s1 = take ? o1 : s1;
      c1 = take ? oc : c1;
      s2 = ns2;
    }
    if (cidx == 0) {
      int row = m0 + wm + (u >> 2) * 16 + rgrp * 4 + (u & 3);
      float4 p;
      p.x = s1; p.y = s2; p.z = __int_as_float(c1); p.w = 0.f;
      slots[(size_t)row * NBG + nbg] = p;
    }
  }
}

// ---------- reduce: global top-2 (8 slots) -> certain idx (+count) or list ---
__global__ void k_top2_reduce(const float4* __restrict__ slots,
                              int* __restrict__ idx, unsigned int* __restrict__ tlist,
                              unsigned int* __restrict__ ucount,
                              int* __restrict__ counts,
                              unsigned long long* __restrict__ rbest) {
  int tid = threadIdx.x;
  int lane = tid & 63, wid = tid >> 6;
  int row = blockIdx.x * 32 + wid * 8 + (lane >> 3);
  int slot = lane & 7;
  float4 a = slots[(size_t)row * NBG + slot];
  float s1 = a.x, s2 = a.y;
  int c1 = __float_as_int(a.z);
  #pragma unroll
  for (int msk = 1; msk < 8; msk <<= 1) {
    float o1 = __shfl_xor(s1, msk);
    float o2 = __shfl_xor(s2, msk);
    int   oc = __shfl_xor(c1, msk);
    float ns2 = fminf(fminf(s2, o2), fmaxf(s1, o1));
    bool take = o1 < s1;
    s1 = take ? o1 : s1;
    c1 = take ? oc : c1;
    s2 = ns2;
  }
  if (slot == 0) {
    if (s2 - s1 >= MARGIN) {
      idx[row] = c1;
      atomicAdd(&counts[c1], 1);
    } else {
      unsigned int p = atomicAdd(ucount, 1u);
      tlist[p] = (unsigned int)row;
      rbest[p] = ~0ull;   // init for refine's atomicMin
    }
  }
}

// ---------- REFINE: 3-term K=1536 exact-class GEMM over uncertain tokens ----
__global__ __launch_bounds__(256) void k_mfma_refine(
    const __bf16* __restrict__ xp, const __bf16* __restrict__ kp,
    const float* __restrict__ h, const unsigned int* __restrict__ tlist,
    const unsigned int* __restrict__ ucount, unsigned long long* __restrict__ rbest) {
  const unsigned int uc = *ucount;
  const int nb = blockIdx.x, mb = blockIdx.y;
  const int m0 = mb * BMr;
  if ((unsigned int)m0 >= uc) return;

  __shared__ __bf16 AS[BMr * BKe];
  __shared__ __bf16 BS[BNr * BKe];

  const int n0 = nb * BNr;
  const int tid = threadIdx.x;
  const int lane = tid & 63;
  const int wid = tid >> 6;
  const int wm = (wid >> 1) * 64, wn = (wid & 1) * 64;

  const int r0 = tid >> 3;  // 0..31
  size_t abase[4];
  #pragma unroll
  for (int i = 0; i < 4; ++i) {
    int p = m0 + r0 + 32 * i;
    int pc = p < (int)uc ? p : (int)uc - 1;
    abase[i] = (size_t)tlist[pc] * KP;
  }

  f32x4 acc[4][4] = {};
  const int soff = tid * 16;
  const int innerC = (soff & 127) ^ ((r0 & 7) << 4);

  for (int ks = 0; ks < KP; ks += BKe) {
    __syncthreads();
    #pragma unroll
    for (int i = 0; i < 4; ++i) {
      int off = i * 4096 + soff;
      int brow = (off >> 7);
      gl2lds16(xp + abase[i] + ks + (innerC >> 1), (char*)AS + off);
      int binner = (off & 127) ^ ((brow & 7) << 4);
      gl2lds16(kp + (size_t)(n0 + brow) * KP + ks + (binner >> 1), (char*)BS + off);
    }
    asm volatile("s_waitcnt vmcnt(0)" ::: "memory");
    __syncthreads();

    #pragma unroll
    for (int kk = 0; kk < 2; ++kk) {
      const int cbyte = kk * 64 + (lane >> 4) * 16;
      bf16x8 af[4], bb[4];
      #pragma unroll
      for (int i = 0; i < 4; ++i) {
        int arow = wm + i * 16 + (lane & 15);
        af[i] = *(const bf16x8*)((const char*)AS + arow * 128 + (cbyte ^ ((arow & 7) << 4)));
        int brow = wn + i * 16 + (lane & 15);
        bb[i] = *(const bf16x8*)((const char*)BS + brow * 128 + (cbyte ^ ((brow & 7) << 4)));
      }
      #pragma unroll
      for (int i = 0; i < 4; ++i)
        #pragma unroll
        for (int j = 0; j < 4; ++j)
          acc[i][j] = __builtin_amdgcn_mfma_f32_16x16x32_bf16(af[i], bb[j], acc[i][j], 0, 0, 0);
    }
  }

  const int rgrp = lane >> 4;
  const int cidx = lane & 15;
  #pragma unroll
  for (int i = 0; i < 4; ++i) {
    #pragma unroll
    for (int r = 0; r < 4; ++r) {
      unsigned long long m = ~0ull;
      #pragma unroll
      for (int j = 0; j < 4; ++j) {
        int kk = n0 + wn + j * 16 + cidx;
        float score = h[kk] - acc[i][j][r];
        unsigned long long cand =
            ((unsigned long long)fkey(score) << 32) | (unsigned int)kk;
        m = umin64(m, cand);
      }
      #pragma unroll
      for (int msk = 1; msk < 16; msk <<= 1) m = umin64(m, __shfl_xor(m, msk));
      if (cidx == 0) {
        int p = m0 + wm + i * 16 + rgrp * 4 + r;
        if ((unsigned int)p < uc) atomicMin(&rbest[p], m);
      }
    }
  }
}

// ---------- finalize: uncertain rows get refined index (+count) ----------
__global__ void k_finalize(const unsigned long long* __restrict__ rbest,
                           const unsigned int* __restrict__ tlist,
                           const unsigned int* __restrict__ ucount,
                           int* __restrict__ idx, int* __restrict__ counts) {
  unsigned int p = blockIdx.x * 256 + threadIdx.x;
  if (p < *ucount) {
    int k = (int)(unsigned int)(rbest[p] & 0xffffffffull);
    idx[tlist[p]] = k;
    atomicAdd(&counts[k], 1);
  }
}

// ---------- counting-sort CSR + fused EMA update ----------
__global__ void k_scan(const int* __restrict__ counts, int* __restrict__ offs,
                       int* __restrict__ cursor) {
  __shared__ int sa[256], sb[256];
  int tid = threadIdx.x;
  int base = tid * 32;
  int loc[32]; int s = 0;
  #pragma unroll
  for (int e = 0; e < 32; ++e) { loc[e] = s; s += counts[base + e]; }
  sa[tid] = s;
  __syncthreads();
  int* src = sa; int* dst = sb;
  for (int d = 1; d < 256; d <<= 1) {
    int v = src[tid] + (tid >= d ? src[tid - d] : 0);
    dst[tid] = v;
    __syncthreads();
    int* tmp = src; src = dst; dst = tmp;
  }
  int excl = src[tid] - s;
  #pragma unroll
  for (int e = 0; e < 32; ++e) {
    int o = excl + loc[e];
    offs[base + e] = o;
    cursor[base + e] = o;
  }
}

__global__ void k_place(const int* __restrict__ idx, int* __restrict__ cursor,
                        int* __restrict__ tok) {
  int t = blockIdx.x * 256 + threadIdx.x;
  if (t < T_TOKENS) {
    int p = atomicAdd(&cursor[idx[t]], 1);
    tok[p] = t;
  }
}

// one wave per code: en; ew = 0.99*ema_w + 0.005*sum(x[tok]); kw = ew/sz;
// and quantized[t] = x[t] + value_w[k] for each token of this code (fused).
__global__ void k_update(const float* __restrict__ x, const float* __restrict__ ema_n,
                         const float* __restrict__ ema_w, const float* __restrict__ value_w,
                         const int* __restrict__ counts,
                         const int* __restrict__ offs, const int* __restrict__ tok,
                         const float* __restrict__ nsum,
                         float* __restrict__ out_en, float* __restrict__ out_ew,
                         float* __restrict__ out_kw, float* __restrict__ out_q) {
  int k = blockIdx.x * 4 + (threadIdx.x >> 6);
  int lane = threadIdx.x & 63;
  int cnt = counts[k];
  int off = offs[k];
  float en = 0.99f * ema_n[k] + 0.005f * (float)cnt;
  if (lane == 0) out_en[k] = en;
  float n = 0.99f * (*nsum) + 81.92f;   // 0.005 * 16384
  float sz = (en + 1e-8f) / (n + 1e-8f * (float)N_TOKEN) * n;

  const float4* er = reinterpret_cast<const float4*>(ema_w + (size_t)k * N_EMBED);
  float4 e0 = er[lane], e1 = er[lane + 64];
  const float4* vr = reinterpret_cast<const float4*>(value_w + (size_t)k * N_EMBED);
  float4 v0 = vr[lane], v1 = vr[lane + 64];
  float4 s0 = {0.f, 0.f, 0.f, 0.f}, s1v = {0.f, 0.f, 0.f, 0.f};
  for (int q = 0; q < cnt; ++q) {
    int t = tok[off + q];
    const float4* xr = reinterpret_cast<const float4*>(x + (size_t)t * N_EMBED);
    float4 a = xr[lane], b = xr[lane + 64];
    s0.x += a.x; s0.y += a.y; s0.z += a.z; s0.w += a.w;
    s1v.x += b.x; s1v.y += b.y; s1v.z += b.z; s1v.w += b.w;
    float4 qa, qb;
    qa.x = a.x + v0.x; qa.y = a.y + v0.y; qa.z = a.z + v0.z; qa.w = a.w + v0.w;
    qb.x = b.x + v1.x; qb.y = b.y + v1.y; qb.z = b.z + v1.z; qb.w = b.w + v1.w;
    float4* oq = reinterpret_cast<float4*>(out_q + (size_t)t * N_EMBED);
    oq[lane] = qa; oq[lane + 64] = qb;
  }
  float4 w0, w1;
  w0.x = 0.99f * e0.x + 0.005f * s0.x;  w0.y = 0.99f * e0.y + 0.005f * s0.y;
  w0.z = 0.99f * e0.z + 0.005f * s0.z;  w0.w = 0.99f * e0.w + 0.005f * s0.w;
  w1.x = 0.99f * e1.x + 0.005f * s1v.x; w1.y = 0.99f * e1.y + 0.005f * s1v.y;
  w1.z = 0.99f * e1.z + 0.005f * s1v.z; w1.w = 0.99f * e1.w + 0.005f * s1v.w;
  float4* ow = reinterpret_cast<float4*>(out_ew + (size_t)k * N_EMBED);
  ow[lane] = w0; ow[lane + 64] = w1;
  float4 q0, q1;
  q0.x = w0.x / sz; q0.y = w0.y / sz; q0.z = w0.z / sz; q0.w = w0.w / sz;
  q1.x = w1.x / sz; q1.y = w1.y / sz; q1.z = w1.z / sz; q1.w = w1.w / sz;
  float4* okw = reinterpret_cast<float4*>(out_kw + (size_t)k * N_EMBED);
  okw[lane] = q0; okw[lane + 64] = q1;
}

// ---------- quantized = x + value_w[idx] (fallback paths only) ----------
__global__ void k_quant(const float* __restrict__ x, const float* __restrict__ value_w,
                        const int* __restrict__ idx, float* __restrict__ q) {
  int gid = blockIdx.x * blockDim.x + threadIdx.x;
  int t = gid >> 7, d4 = gid & 127;
  float4 xv = reinterpret_cast<const float4*>(x)[gid];
  float4 v = reinterpret_cast<const float4*>(value_w + (size_t)idx[t] * N_EMBED)[d4];
  float4 o;
  o.x = xv.x + v.x; o.y = xv.y + v.y; o.z = xv.z + v.z; o.w = xv.w + v.w;
  reinterpret_cast<float4*>(q)[gid] = o;
}

// ---------- single-stage MFMA GEMM + argmin (R6-proven; ws fallback) ----------
__global__ __launch_bounds__(256) void k_mfma_argmin(
    const __bf16* __restrict__ xp, const __bf16* __restrict__ kp,
    const float* __restrict__ h, unsigned long long* __restrict__ best) {
  __shared__ __bf16 AS[BMr * BKe];
  __shared__ __bf16 BS[BNr * BKe];
  const int nb = blockIdx.x, mb = blockIdx.y;
  const int m0 = mb * BMr, n0 = nb * BNr;
  const int tid = threadIdx.x;
  const int lane = tid & 63;
  const int wid = tid >> 6;
  const int wm = (wid >> 1) * 64, wn = (wid & 1) * 64;
  f32x4 acc[4][4] = {};
  const int soff = tid * 16;
  for (int ks = 0; ks < KP; ks += BKe) {
    __syncthreads();
    #pragma unroll
    for (int i = 0; i < 4; ++i) {
      int off = i * 4096 + soff;
      int row = off >> 7;
      int inner = (off & 127) ^ ((row & 7) << 4);
      gl2lds16(xp + (size_t)(m0 + row) * KP + ks + (inner >> 1), (char*)AS + off);
      gl2lds16(kp + (size_t)(n0 + row) * KP + ks + (inner >> 1), (char*)BS + off);
    }
    asm volatile("s_waitcnt vmcnt(0)" ::: "memory");
    __syncthreads();
    #pragma unroll
    for (int kk = 0; kk < 2; ++kk) {
      const int cbyte = kk * 64 + (lane >> 4) * 16;
      bf16x8 af[4], bb[4];
      #pragma unroll
      for (int i = 0; i < 4; ++i) {
        int arow = wm + i * 16 + (lane & 15);
        af[i] = *(const bf16x8*)((const char*)AS + arow * 128 + (cbyte ^ ((arow & 7) << 4)));
        int brow = wn + i * 16 + (lane & 15);
        bb[i] = *(const bf16x8*)((const char*)BS + brow * 128 + (cbyte ^ ((brow & 7) << 4)));
      }
      #pragma unroll
      for (int i = 0; i < 4; ++i)
        #pragma unroll
        for (int j = 0; j < 4; ++j)
          acc[i][j] = __builtin_amdgcn_mfma_f32_16x16x32_bf16(af[i], bb[j], acc[i][j], 0, 0, 0);
    }
  }
  const int rgrp = lane >> 4;
  const int cidx = lane & 15;
  #pragma unroll
  for (int i = 0; i < 4; ++i) {
    #pragma unroll
    for (int r = 0; r < 4; ++r) {
      unsigned long long m = ~0ull;
      #pragma unroll
      for (int j = 0; j < 4; ++j) {
        int kk = n0 + wn + j * 16 + cidx;
        float score = h[kk] - acc[i][j][r];
        unsigned long long cand =
            ((unsigned long long)fkey(score) << 32) | (unsigned int)kk;
        m = umin64(m, cand);
      }
      #pragma unroll
      for (int msk = 1; msk < 16; msk <<= 1) m = umin64(m, __shfl_xor(m, msk));
      if (cidx == 0) {
        int row = m0 + wm + i * 16 + rgrp * 4 + r;
        atomicMin(&best[row], m);
      }
    }
  }
}

// ---------- f32 fallback GEMM+argmin ----------
#define BT 128
#define BK 128
#define DC 32
__global__ __launch_bounds__(256, 2) void k_gemm_argmin(
    const float* __restrict__ x, const float* __restrict__ key_w,
    const float* __restrict__ h, unsigned long long* __restrict__ best) {
  __shared__ float4 XS[BT * 8];
  __shared__ float4 KS[BK * 8];
  const int kb = blockIdx.x, tb = blockIdx.y;
  const int t0 = tb * BT, k0 = kb * BK;
  const int tid = threadIdx.x;
  const int tx = tid & 15;
  const int tyg = tid >> 4;
  float acc[8][8];
  #pragma unroll
  for (int i = 0; i < 8; ++i)
    #pragma unroll
    for (int j = 0; j < 8; ++j) acc[i][j] = 0.f;
  for (int dc = 0; dc < N_EMBED; dc += DC) {
    __syncthreads();
    #pragma unroll
    for (int ld = 0; ld < 4; ++ld) {
      int li = ld * 256 + tid;
      int row = li >> 3, c4 = li & 7;
      XS[row * 8 + (c4 ^ (row & 7))] =
          *reinterpret_cast<const float4*>(x + (size_t)(t0 + row) * N_EMBED + dc + c4 * 4);
      KS[row * 8 + (c4 ^ (row & 7))] =
          *reinterpret_cast<const float4*>(key_w + (size_t)(k0 + row) * N_EMBED + dc + c4 * 4);
    }
    __syncthreads();
    #pragma unroll
    for (int d4 = 0; d4 < 8; ++d4) {
      float4 a[8], b[8];
      #pragma unroll
      for (int j = 0; j < 8; ++j) {
        a[j] = XS[(tyg + 16 * j) * 8 + (d4 ^ (tyg & 7))];
        b[j] = KS[(tx  + 16 * j) * 8 + (d4 ^ (tx  & 7))];
      }
      #pragma unroll
      for (int i = 0; i < 8; ++i) {
        float4 av = a[i];
        #pragma unroll
        for (int j = 0; j < 8; ++j) {
          float4 bv = b[j];
          acc[i][j] = fmaf(av.x, bv.x, fmaf(av.y, bv.y,
                      fmaf(av.z, bv.z, fmaf(av.w, bv.w, acc[i][j]))));
        }
      }
    }
  }
  #pragma unroll
  for (int i = 0; i < 8; ++i) {
    unsigned long long m = ~0ull;
    #pragma unroll
    for (int j = 0; j < 8; ++j) {
      int kk = k0 + tx + 16 * j;
      float score = h[kk] - acc[i][j];
      unsigned long long cand =
          ((unsigned long long)fkey(score) << 32) | (unsigned int)kk;
      m = umin64(m, cand);
    }
    #pragma unroll
    for (int mask = 1; mask < 16; mask <<= 1) m = umin64(m, __shfl_xor(m, mask));
    if (tx == 0) atomicMin(&best[t0 + tyg + 16 * i], m);
  }
}

// ---------- legacy aux (fallback paths) ----------
__global__ void k_extract_counts(const unsigned long long* __restrict__ best,
                                 int* __restrict__ idx, float* __restrict__ out_en) {
  int t = blockIdx.x * blockDim.x + threadIdx.x;
  if (t < T_TOKENS) {
    int k = (int)(unsigned int)(best[t] & 0xffffffffull);
    idx[t] = k;
    atomicAdd(&out_en[k], 0.005f);
  }
}
__global__ void k_quant_scatter(const float* __restrict__ x,
                                const float* __restrict__ value_w,
                                const int* __restrict__ idx,
                                float* __restrict__ q, float* __restrict__ out_ew) {
  int gid = blockIdx.x * blockDim.x + threadIdx.x;
  int t = gid >> 7, d4 = gid & 127;
  float4 xv = reinterpret_cast<const float4*>(x)[gid];
  int k = idx[t];
  float4 v = reinterpret_cast<const float4*>(value_w + (size_t)k * N_EMBED)[d4];
  float4 o;
  o.x = xv.x + v.x; o.y = xv.y + v.y; o.z = xv.z + v.z; o.w = xv.w + v.w;
  reinterpret_cast<float4*>(q)[gid] = o;
  const float c = 0.005f;
  float* dst = out_ew + (size_t)k * N_EMBED + d4 * 4;
  atomicAdd(dst + 0, c * xv.x);
  atomicAdd(dst + 1, c * xv.y);
  atomicAdd(dst + 2, c * xv.z);
  atomicAdd(dst + 3, c * xv.w);
}
__global__ void k_scaleN(const float* __restrict__ ema_n, float* __restrict__ out_en) {
  int k = blockIdx.x * blockDim.x + threadIdx.x;
  if (k < N_TOKEN) out_en[k] = 0.99f * ema_n[k];
}
__global__ void k_scaleW(const float* __restrict__ ema_w, float* __restrict__ out_ew) {
  int gid = blockIdx.x * blockDim.x + threadIdx.x;
  float4 v = reinterpret_cast<const float4*>(ema_w)[gid];
  float4 o;
  o.x = 0.99f * v.x; o.y = 0.99f * v.y; o.z = 0.99f * v.z; o.w = 0.99f * v.w;
  reinterpret_cast<float4*>(out_ew)[gid] = o;
}
__global__ void k_sumn(const float* __restrict__ en, float* __restrict__ nsum) {
  __shared__ float sm[256];
  float s = 0.f;
  for (int i = threadIdx.x; i < N_TOKEN; i += 256) s += en[i];
  sm[threadIdx.x] = s;
  __syncthreads();
  for (int off = 128; off; off >>= 1) {
    if (threadIdx.x < off) sm[threadIdx.x] += sm[threadIdx.x + off];
    __syncthreads();
  }
  if (threadIdx.x == 0) *nsum = sm[0];
}
__global__ void k_keyw(const float* __restrict__ out_ew, const float* __restrict__ out_en,
                       const float* __restrict__ nsum, float* __restrict__ out_kw) {
  int gid = blockIdx.x * blockDim.x + threadIdx.x;
  int k = gid >> 7;
  float n = *nsum;
  float sz = (out_en[k] + 1e-8f) / (n + 1e-8f * (float)N_TOKEN) * n;
  float4 w = reinterpret_cast<const float4*>(out_ew)[gid];
  float4 o;
  o.x = w.x / sz; o.y = w.y / sz; o.z = w.z / sz; o.w = w.w / sz;
  reinterpret_cast<float4*>(out_kw)[gid] = o;
}

// ---------- launcher ----------
extern "C" void kernel_launch(void* const* d_in, const int* in_sizes, int n_in,
                              void* d_out, int out_size, void* d_ws, size_t ws_size,
                              hipStream_t stream) {
  const float* x       = (const float*)d_in[0];
  const float* key_w   = (const float*)d_in[1];
  const float* value_w = (const float*)d_in[2];
  const float* ema_n   = (const float*)d_in[3];
  const float* ema_w   = (const float*)d_in[4];

  float* out_q  = (float*)d_out;
  float* out_en = out_q + 8388608;
  float* out_ew = out_en + N_TOKEN;
  float* out_kw = out_ew + 4194304;

  // ---- two-stage layout ----
  const size_t SLOTS_B = (size_t)T_TOKENS * NBG * 16;              // 2 MiB
  const size_t XP_B    = (size_t)T_TOKENS * KP * 2;                // 48 MiB
  const size_t KP_B    = (size_t)N_TOKEN * KP * 2;                 // 24 MiB
  char* base = (char*)d_ws;
  float4* slots = (float4*)base;
  __bf16* xp3 = (__bf16*)(base + SLOTS_B);
  __bf16* kp3 = (__bf16*)(base + SLOTS_B + XP_B);
  char* tail  = base + SLOTS_B + XP_B + KP_B;
  float* h                  = (float*)(tail + 0);         // 32 KiB
  int*   idx                = (int*)(tail + 32768);       // 64 KiB
  unsigned int* tlist       = (unsigned int*)(tail + 98304);   // 64 KiB
  unsigned long long* rbest = (unsigned long long*)(tail + 163840);  // 128 KiB
  unsigned int* ucount      = (unsigned int*)(tail + 294912);  // 256 B
  float* nsum               = (float*)(tail + 295168);    // 256 B
  int* counts               = (int*)(tail + 295424);      // 32 KiB
  int* offs                 = (int*)(tail + 328192);      // 32 KiB
  int* cursor               = (int*)(tail + 360960);      // 32 KiB
  int* tok                  = (int*)(tail + 393728);      // 64 KiB
  const size_t ws_need2 = SLOTS_B + XP_B + KP_B + 459264;

  // ---- R6 single-stage layout (fallback) ----
  unsigned long long* f_best = (unsigned long long*)d_ws;
  int*   f_idx  = (int*)((char*)d_ws + 131072);
  float* f_h    = (float*)((char*)d_ws + 196608);
  float* f_nsum = (float*)((char*)d_ws + 229376);
  __bf16* f_xp  = (__bf16*)((char*)d_ws + 262144);
  __bf16* f_kp  = (__bf16*)((char*)d_ws + 262144 + XP_B);
  const size_t ws_need1 = 262144 + XP_B + KP_B;

  if (ws_size >= ws_need2) {
    // ---------- two-stage path ----------
    k_pack_all<<<10242, 256, 0, stream>>>(x, key_w, ema_n, xp3, kp3, h, nsum,
                                          ucount, counts);
    {
      dim3 grid(N_TOKEN / (BNr * NBG), T_TOKENS / BMr);   // 8 x 128
      k_mfma_top2<<<grid, 256, 0, stream>>>(xp3, kp3, h, slots);
    }
    k_top2_reduce<<<T_TOKENS / 32, 256, 0, stream>>>(slots, idx, tlist, ucount,
                                                     counts, rbest);
    {
      dim3 grid(N_TOKEN / BNr, T_TOKENS / BMr);
      k_mfma_refine<<<grid, 256, 0, stream>>>(xp3, kp3, h, tlist, ucount, rbest);
    }
    k_finalize<<<T_TOKENS / 256, 256, 0, stream>>>(rbest, tlist, ucount, idx, counts);

    k_scan<<<1, 256, 0, stream>>>(counts, offs, cursor);
    k_place<<<T_TOKENS / 256, 256, 0, stream>>>(idx, cursor, tok);
    k_update<<<N_TOKEN / 4, 256, 0, stream>>>(x, ema_n, ema_w, value_w, counts,
                                              offs, tok, nsum,
                                              out_en, out_ew, out_kw, out_q);
  } else if (ws_size >= ws_need1) {
    // ---------- R6 single-stage path ----------
    hipMemsetAsync(f_best, 0xFF, (size_t)T_TOKENS * 8, stream);
    k_pack_x<<<(T_TOKENS * (N_EMBED / 4)) / 256, 256, 0, stream>>>(x, f_xp);
    k_pack_k_norm<<<N_TOKEN / 4, 256, 0, stream>>>(key_w, f_kp, f_h);
    dim3 grid(N_TOKEN / BNr, T_TOKENS / BMr);
    k_mfma_argmin<<<grid, 256, 0, stream>>>(f_xp, f_kp, f_h, f_best);

    k_scaleN<<<N_TOKEN / 256, 256, 0, stream>>>(ema_n, out_en);
    k_extract_counts<<<T_TOKENS / 256, 256, 0, stream>>>(f_best, f_idx, out_en);
    k_scaleW<<<(N_TOKEN * (N_EMBED / 4)) / 256, 256, 0, stream>>>(ema_w, out_ew);
    k_quant_scatter<<<(T_TOKENS * (N_EMBED / 4)) / 256, 256, 0, stream>>>(
        x, value_w, f_idx, out_q, out_ew);
    k_sumn<<<1, 256, 0, stream>>>(out_en, f_nsum);
    k_keyw<<<(N_TOKEN * (N_EMBED / 4)) / 256, 256, 0, stream>>>(out_ew, out_en, f_nsum, out_kw);
  } else {
    // ---------- deep fallback: f32 vector GEMM ----------
    hipMemsetAsync(f_best, 0xFF, (size_t)T_TOKENS * 8, stream);
    k_hnorm<<<N_TOKEN / 4, 256, 0, stream>>>(key_w, f_h);
    dim3 grid(N_TOKEN / BK, T_TOKENS / BT);
    k_gemm_argmin<<<grid, 256, 0, stream>>>(x, key_w, f_h, f_best);

    k_scaleN<<<N_TOKEN / 256, 256, 0, stream>>>(ema_n, out_en);
    k_extract_counts<<<T_TOKENS / 256, 256, 0, stream>>>(f_best, f_idx, out_en);
    k_scaleW<<<(N_TOKEN * (N_EMBED / 4)) / 256, 256, 0, stream>>>(ema_w, out_ew);
    k_quant_scatter<<<(T_TOKENS * (N_EMBED / 4)) / 256, 256, 0, stream>>>(
        x, value_w, f_idx, out_q, out_ew);
    k_sumn<<<1, 256, 0, stream>>>(out_en, f_nsum);
    k_keyw<<<(N_TOKEN * (N_EMBED / 4)) / 256, 256, 0, stream>>>(out_ew, out_en, f_nsum, out_kw);
  }
}

// Round 12
// 397.947 us; speedup vs baseline: 2.1256x; 1.0040x over previous
//
#include <hip/hip_runtime.h>

#define N_TOKEN 8192
#define N_EMBED 512
#define T_TOKENS 16384
#define KP 1536       // packed K = 3 * 512
#define MARGIN 0.45f  // score-gap certainty threshold (~9 sigma of approx error)
#define NBG 8         // nb tiles per top2 block

typedef __bf16 bf16x8 __attribute__((ext_vector_type(8)));
typedef __bf16 bf16x4 __attribute__((ext_vector_type(4)));
typedef float f32x4 __attribute__((ext_vector_type(4)));

// ---------- helpers ----------
__device__ __forceinline__ unsigned int fkey(float f) {
  unsigned int u = __float_as_uint(f);
  return (u & 0x80000000u) ? ~u : (u | 0x80000000u);
}
__device__ __forceinline__ void gl2lds16(const void* gsrc, void* lds) {
  __builtin_amdgcn_global_load_lds(
      (const __attribute__((address_space(1))) unsigned int*)gsrc,
      (__attribute__((address_space(3))) unsigned int*)lds, 16, 0, 0);
}
__device__ __forceinline__ unsigned long long umin64(unsigned long long a,
                                                     unsigned long long b) {
  return a < b ? a : b;
}

// ---------- pack bodies (shared by standalone + fused kernels) ----------
__device__ __forceinline__ void pack_x_body(const float* __restrict__ x,
                                            __bf16* __restrict__ xp, int gid) {
  int t = gid >> 7, d4 = gid & 127;
  float4 v = reinterpret_cast<const float4*>(x)[gid];
  bf16x4 hi, lo;
  hi[0] = (__bf16)v.x; hi[1] = (__bf16)v.y; hi[2] = (__bf16)v.z; hi[3] = (__bf16)v.w;
  lo[0] = (__bf16)(v.x - (float)hi[0]);
  lo[1] = (__bf16)(v.y - (float)hi[1]);
  lo[2] = (__bf16)(v.z - (float)hi[2]);
  lo[3] = (__bf16)(v.w - (float)hi[3]);
  __bf16* row = xp + (size_t)t * KP + d4 * 4;
  *(bf16x4*)(row)        = hi;
  *(bf16x4*)(row + 512)  = hi;
  *(bf16x4*)(row + 1024) = lo;
}

__device__ __forceinline__ void pack_k_body(const float* __restrict__ kw,
                                            __bf16* __restrict__ kp,
                                            float* __restrict__ h,
                                            int blk, int tid) {
  int row = blk * 4 + (tid >> 6);
  int lane = tid & 63;
  const float4* src = reinterpret_cast<const float4*>(kw + (size_t)row * N_EMBED);
  __bf16* dst = kp + (size_t)row * KP;
  float s = 0.f;
  #pragma unroll
  for (int c = 0; c < 2; ++c) {
    int f4 = lane + c * 64;
    float4 v = src[f4];
    s += v.x*v.x + v.y*v.y + v.z*v.z + v.w*v.w;
    bf16x4 hi, lo;
    hi[0] = (__bf16)v.x; hi[1] = (__bf16)v.y; hi[2] = (__bf16)v.z; hi[3] = (__bf16)v.w;
    lo[0] = (__bf16)(v.x - (float)hi[0]);
    lo[1] = (__bf16)(v.y - (float)hi[1]);
    lo[2] = (__bf16)(v.z - (float)hi[2]);
    lo[3] = (__bf16)(v.w - (float)hi[3]);
    *(bf16x4*)(dst + f4 * 4)        = hi;
    *(bf16x4*)(dst + 512 + f4 * 4)  = lo;
    *(bf16x4*)(dst + 1024 + f4 * 4) = hi;
  }
  #pragma unroll
  for (int off = 32; off; off >>= 1) s += __shfl_down(s, off);
  if (lane == 0) h[row] = 0.5f * s;
}

// ---------- fused prep: pack_x | pack_k+norm | sum(ema_n)+init ----------
__global__ void k_pack_all(const float* __restrict__ x, const float* __restrict__ kw,
                           const float* __restrict__ ema_n,
                           __bf16* __restrict__ xp, __bf16* __restrict__ kp,
                           float* __restrict__ h, float* __restrict__ nsum,
                           unsigned int* __restrict__ ucount, int* __restrict__ counts) {
  int b = blockIdx.x;
  if (b < 8192) {
    pack_x_body(x, xp, b * 256 + threadIdx.x);
  } else if (b < 10240) {
    pack_k_body(kw, kp, h, b - 8192, threadIdx.x);
  } else if (b == 10240) {
    __shared__ float sm[256];
    float s = 0.f;
    for (int i = threadIdx.x; i < N_TOKEN; i += 256) s += ema_n[i];
    sm[threadIdx.x] = s;
    __syncthreads();
    for (int off = 128; off; off >>= 1) {
      if (threadIdx.x < off) sm[threadIdx.x] += sm[threadIdx.x + off];
      __syncthreads();
    }
    if (threadIdx.x == 0) { *nsum = sm[0]; *ucount = 0u; }
  } else {
    for (int i = threadIdx.x; i < N_TOKEN; i += 256) counts[i] = 0;
  }
}

// ---------- standalone packs (fallback paths) ----------
__global__ void k_pack_x(const float* __restrict__ x, __bf16* __restrict__ xp) {
  pack_x_body(x, xp, blockIdx.x * blockDim.x + threadIdx.x);
}
__global__ void k_pack_k_norm(const float* __restrict__ kw, __bf16* __restrict__ kp,
                              float* __restrict__ h) {
  pack_k_body(kw, kp, h, blockIdx.x, threadIdx.x);
}

// ---------- norms only (deep fallback) ----------
__global__ void k_hnorm(const float* __restrict__ key_w, float* __restrict__ h) {
  int code = blockIdx.x * 4 + (threadIdx.x >> 6);
  int lane = threadIdx.x & 63;
  const float4* row = reinterpret_cast<const float4*>(key_w + (size_t)code * N_EMBED);
  float s = 0.f;
  float4 v0 = row[lane];
  float4 v1 = row[lane + 64];
  s += v0.x*v0.x + v0.y*v0.y + v0.z*v0.z + v0.w*v0.w;
  s += v1.x*v1.x + v1.y*v1.y + v1.z*v1.z + v1.w*v1.w;
  #pragma unroll
  for (int off = 32; off; off >>= 1) s += __shfl_down(s, off);
  if (lane == 0) h[code] = 0.5f * s;
}

#define BMr 128
#define BNr 128
#define BKe 64   // K-step (128 B rows) — R3-proven 0-conflict geometry

// ---------- PASS 1: K=512 hi*hi GEMM; BKe=64; 8 nb tiles/block ---------------
// wave = 32 rows x 128 cols (acc[2][8]); running top-2, one butterfly per 8.
__global__ __launch_bounds__(256) void k_mfma_top2(
    const __bf16* __restrict__ xp, const __bf16* __restrict__ kp,
    const float* __restrict__ h, float4* __restrict__ slots) {
  __shared__ __bf16 AS[BMr * BKe];  // 16 KB, 128 B rows
  __shared__ __bf16 BS[BNr * BKe];  // 16 KB

  const int nbg = blockIdx.x, mb = blockIdx.y;
  const int m0 = mb * BMr;
  const int tid = threadIdx.x;
  const int lane = tid & 63;
  const int wid = tid >> 6;
  const int wm = wid * 32;           // 4 waves x 32 rows
  const int soff = tid * 16;
  const int rgrp = lane >> 4;
  const int cidx = lane & 15;

  float rs1[8], rs2[8];
  int rc1[8];
  #pragma unroll
  for (int u = 0; u < 8; ++u) { rs1[u] = 3.4e38f; rs2[u] = 3.4e38f; rc1[u] = 0; }

  for (int q = 0; q < NBG; ++q) {
    const int n0 = (nbg * NBG + q) * BNr;
    f32x4 acc[2][8] = {};

    for (int ks = 0; ks < 512; ks += BKe) {   // hi columns only
      __syncthreads();
      #pragma unroll
      for (int i = 0; i < 4; ++i) {
        int off = i * 4096 + soff;
        int row = off >> 7;
        int inner = (off & 127) ^ ((row & 7) << 4);
        gl2lds16(xp + (size_t)(m0 + row) * KP + ks + (inner >> 1), (char*)AS + off);
        gl2lds16(kp + (size_t)(n0 + row) * KP + ks + (inner >> 1), (char*)BS + off);
      }
      asm volatile("s_waitcnt vmcnt(0)" ::: "memory");
      __syncthreads();

      #pragma unroll
      for (int kk = 0; kk < 2; ++kk) {
        const int cbyte = kk * 64 + (lane >> 4) * 16;
        bf16x8 af[2], bb[8];
        #pragma unroll
        for (int i = 0; i < 2; ++i) {
          int arow = wm + i * 16 + (lane & 15);
          af[i] = *(const bf16x8*)((const char*)AS + arow * 128 + (cbyte ^ ((arow & 7) << 4)));
        }
        #pragma unroll
        for (int j = 0; j < 8; ++j) {
          int brow = j * 16 + (lane & 15);
          bb[j] = *(const bf16x8*)((const char*)BS + brow * 128 + (cbyte ^ ((brow & 7) << 4)));
        }
        #pragma unroll
        for (int i = 0; i < 2; ++i)
          #pragma unroll
          for (int j = 0; j < 8; ++j)
            acc[i][j] = __builtin_amdgcn_mfma_f32_16x16x32_bf16(af[i], bb[j], acc[i][j], 0, 0, 0);
      }
    }

    // insert this tile's 8 scores per output row into running top-2
    #pragma unroll
    for (int i = 0; i < 2; ++i) {
      #pragma unroll
      for (int r = 0; r < 4; ++r) {
        const int u = i * 4 + r;
        float s1 = rs1[u], s2 = rs2[u];
        int c1 = rc1[u];
        #pragma unroll
        for (int j = 0; j < 8; ++j) {
          int kk = n0 + j * 16 + cidx;
          float sc = h[kk] - acc[i][j][r];
          if (sc < s1) { s2 = s1; s1 = sc; c1 = kk; }
          else s2 = fminf(s2, sc);
        }
        rs1[u] = s1; rs2[u] = s2; rc1[u] = c1;
      }
    }
  }

  // one butterfly per output row; slot per (row, nbg)
  #pragma unroll
  for (int u = 0; u < 8; ++u) {
    float s1 = rs1[u], s2 = rs2[u];
    int c1 = rc1[u];
    #pragma unroll
    for (int msk = 1; msk < 16; msk <<= 1) {
      float o1 = __shfl_xor(s1, msk);
      float o2 = __shfl_xor(s2, msk);
      int   oc = __shfl_xor(c1, msk);
      float ns2 = fminf(fminf(s2, o2), fmaxf(s1, o1));
      bool take = o1 < s1;
      s1 = take ? o1 : s1;
      c1 = take ? oc : c1;
      s2 = ns2;
    }
    if (cidx == 0) {
      int row = m0 + wm + (u >> 2) * 16 + rgrp * 4 + (u & 3);
      float4 p;
      p.x = s1; p.y = s2; p.z = __int_as_float(c1); p.w = 0.f;
      slots[(size_t)row * NBG + nbg] = p;
    }
  }
}

// ---------- reduce: global top-2 (8 slots) -> certain idx (+count) or list ---
__global__ void k_top2_reduce(const float4* __restrict__ slots,
                              int* __restrict__ idx, unsigned int* __restrict__ tlist,
                              unsigned int* __restrict__ ucount,
                              int* __restrict__ counts,
                              unsigned long long* __restrict__ rbest) {
  int tid = threadIdx.x;
  int lane = tid & 63, wid = tid >> 6;
  int row = blockIdx.x * 32 + wid * 8 + (lane >> 3);
  int slot = lane & 7;
  float4 a = slots[(size_t)row * NBG + slot];
  float s1 = a.x, s2 = a.y;
  int c1 = __float_as_int(a.z);
  #pragma unroll
  for (int msk = 1; msk < 8; msk <<= 1) {
    float o1 = __shfl_xor(s1, msk);
    float o2 = __shfl_xor(s2, msk);
    int   oc = __shfl_xor(c1, msk);
    float ns2 = fminf(fminf(s2, o2), fmaxf(s1, o1));
    bool take = o1 < s1;
    s1 = take ? o1 : s1;
    c1 = take ? oc : c1;
    s2 = ns2;
  }
  if (slot == 0) {
    if (s2 - s1 >= MARGIN) {
      idx[row] = c1;
      atomicAdd(&counts[c1], 1);
    } else {
      unsigned int p = atomicAdd(ucount, 1u);
      tlist[p] = (unsigned int)row;
      rbest[p] = ~0ull;   // init for refine's atomicMin
    }
  }
}

// ---------- REFINE: 3-term K=1536 exact-class GEMM over uncertain tokens ----
__global__ __launch_bounds__(256) void k_mfma_refine(
    const __bf16* __restrict__ xp, const __bf16* __restrict__ kp,
    const float* __restrict__ h, const unsigned int* __restrict__ tlist,
    const unsigned int* __restrict__ ucount, unsigned long long* __restrict__ rbest) {
  const unsigned int uc = *ucount;
  const int nb = blockIdx.x, mb = blockIdx.y;
  const int m0 = mb * BMr;
  if ((unsigned int)m0 >= uc) return;

  __shared__ __bf16 AS[BMr * BKe];
  __shared__ __bf16 BS[BNr * BKe];

  const int n0 = nb * BNr;
  const int tid = threadIdx.x;
  const int lane = tid & 63;
  const int wid = tid >> 6;
  const int wm = (wid >> 1) * 64, wn = (wid & 1) * 64;

  const int r0 = tid >> 3;  // 0..31
  size_t abase[4];
  #pragma unroll
  for (int i = 0; i < 4; ++i) {
    int p = m0 + r0 + 32 * i;
    int pc = p < (int)uc ? p : (int)uc - 1;
    abase[i] = (size_t)tlist[pc] * KP;
  }

  f32x4 acc[4][4] = {};
  const int soff = tid * 16;
  const int innerC = (soff & 127) ^ ((r0 & 7) << 4);

  for (int ks = 0; ks < KP; ks += BKe) {
    __syncthreads();
    #pragma unroll
    for (int i = 0; i < 4; ++i) {
      int off = i * 4096 + soff;
      int brow = (off >> 7);
      gl2lds16(xp + abase[i] + ks + (innerC >> 1), (char*)AS + off);
      int binner = (off & 127) ^ ((brow & 7) << 4);
      gl2lds16(kp + (size_t)(n0 + brow) * KP + ks + (binner >> 1), (char*)BS + off);
    }
    asm volatile("s_waitcnt vmcnt(0)" ::: "memory");
    __syncthreads();

    #pragma unroll
    for (int kk = 0; kk < 2; ++kk) {
      const int cbyte = kk * 64 + (lane >> 4) * 16;
      bf16x8 af[4], bb[4];
      #pragma unroll
      for (int i = 0; i < 4; ++i) {
        int arow = wm + i * 16 + (lane & 15);
        af[i] = *(const bf16x8*)((const char*)AS + arow * 128 + (cbyte ^ ((arow & 7) << 4)));
        int brow = wn + i * 16 + (lane & 15);
        bb[i] = *(const bf16x8*)((const char*)BS + brow * 128 + (cbyte ^ ((brow & 7) << 4)));
      }
      #pragma unroll
      for (int i = 0; i < 4; ++i)
        #pragma unroll
        for (int j = 0; j < 4; ++j)
          acc[i][j] = __builtin_amdgcn_mfma_f32_16x16x32_bf16(af[i], bb[j], acc[i][j], 0, 0, 0);
    }
  }

  const int rgrp = lane >> 4;
  const int cidx = lane & 15;
  #pragma unroll
  for (int i = 0; i < 4; ++i) {
    #pragma unroll
    for (int r = 0; r < 4; ++r) {
      unsigned long long m = ~0ull;
      #pragma unroll
      for (int j = 0; j < 4; ++j) {
        int kk = n0 + wn + j * 16 + cidx;
        float score = h[kk] - acc[i][j][r];
        unsigned long long cand =
            ((unsigned long long)fkey(score) << 32) | (unsigned int)kk;
        m = umin64(m, cand);
      }
      #pragma unroll
      for (int msk = 1; msk < 16; msk <<= 1) m = umin64(m, __shfl_xor(m, msk));
      if (cidx == 0) {
        int p = m0 + wm + i * 16 + rgrp * 4 + r;
        if ((unsigned int)p < uc) atomicMin(&rbest[p], m);
      }
    }
  }
}

// ---------- finalize: uncertain rows get refined index (+count) ----------
__global__ void k_finalize(const unsigned long long* __restrict__ rbest,
                           const unsigned int* __restrict__ tlist,
                           const unsigned int* __restrict__ ucount,
                           int* __restrict__ idx, int* __restrict__ counts) {
  unsigned int p = blockIdx.x * 256 + threadIdx.x;
  if (p < *ucount) {
    int k = (int)(unsigned int)(rbest[p] & 0xffffffffull);
    idx[tlist[p]] = k;
    atomicAdd(&counts[k], 1);
  }
}

// ---------- counting-sort CSR + fused EMA update ----------
__global__ void k_scan(const int* __restrict__ counts, int* __restrict__ offs,
                       int* __restrict__ cursor) {
  __shared__ int sa[256], sb[256];
  int tid = threadIdx.x;
  int base = tid * 32;
  int loc[32]; int s = 0;
  #pragma unroll
  for (int e = 0; e < 32; ++e) { loc[e] = s; s += counts[base + e]; }
  sa[tid] = s;
  __syncthreads();
  int* src = sa; int* dst = sb;
  for (int d = 1; d < 256; d <<= 1) {
    int v = src[tid] + (tid >= d ? src[tid - d] : 0);
    dst[tid] = v;
    __syncthreads();
    int* tmp = src; src = dst; dst = tmp;
  }
  int excl = src[tid] - s;
  #pragma unroll
  for (int e = 0; e < 32; ++e) {
    int o = excl + loc[e];
    offs[base + e] = o;
    cursor[base + e] = o;
  }
}

__global__ void k_place(const int* __restrict__ idx, int* __restrict__ cursor,
                        int* __restrict__ tok) {
  int t = blockIdx.x * 256 + threadIdx.x;
  if (t < T_TOKENS) {
    int p = atomicAdd(&cursor[idx[t]], 1);
    tok[p] = t;
  }
}

// one wave per code: en; ew = 0.99*ema_w + 0.005*sum(x[tok]); kw = ew/sz;
// and quantized[t] = x[t] + value_w[k] for each token of this code (fused).
__global__ void k_update(const float* __restrict__ x, const float* __restrict__ ema_n,
                         const float* __restrict__ ema_w, const float* __restrict__ value_w,
                         const int* __restrict__ counts,
                         const int* __restrict__ offs, const int* __restrict__ tok,
                         const float* __restrict__ nsum,
                         float* __restrict__ out_en, float* __restrict__ out_ew,
                         float* __restrict__ out_kw, float* __restrict__ out_q) {
  int k = blockIdx.x * 4 + (threadIdx.x >> 6);
  int lane = threadIdx.x & 63;
  int cnt = counts[k];
  int off = offs[k];
  float en = 0.99f * ema_n[k] + 0.005f * (float)cnt;
  if (lane == 0) out_en[k] = en;
  float n = 0.99f * (*nsum) + 81.92f;   // 0.005 * 16384
  float sz = (en + 1e-8f) / (n + 1e-8f * (float)N_TOKEN) * n;

  const float4* er = reinterpret_cast<const float4*>(ema_w + (size_t)k * N_EMBED);
  float4 e0 = er[lane], e1 = er[lane + 64];
  const float4* vr = reinterpret_cast<const float4*>(value_w + (size_t)k * N_EMBED);
  float4 v0 = vr[lane], v1 = vr[lane + 64];
  float4 s0 = {0.f, 0.f, 0.f, 0.f}, s1v = {0.f, 0.f, 0.f, 0.f};
  for (int q = 0; q < cnt; ++q) {
    int t = tok[off + q];
    const float4* xr = reinterpret_cast<const float4*>(x + (size_t)t * N_EMBED);
    float4 a = xr[lane], b = xr[lane + 64];
    s0.x += a.x; s0.y += a.y; s0.z += a.z; s0.w += a.w;
    s1v.x += b.x; s1v.y += b.y; s1v.z += b.z; s1v.w += b.w;
    float4 qa, qb;
    qa.x = a.x + v0.x; qa.y = a.y + v0.y; qa.z = a.z + v0.z; qa.w = a.w + v0.w;
    qb.x = b.x + v1.x; qb.y = b.y + v1.y; qb.z = b.z + v1.z; qb.w = b.w + v1.w;
    float4* oq = reinterpret_cast<float4*>(out_q + (size_t)t * N_EMBED);
    oq[lane] = qa; oq[lane + 64] = qb;
  }
  float4 w0, w1;
  w0.x = 0.99f * e0.x + 0.005f * s0.x;  w0.y = 0.99f * e0.y + 0.005f * s0.y;
  w0.z = 0.99f * e0.z + 0.005f * s0.z;  w0.w = 0.99f * e0.w + 0.005f * s0.w;
  w1.x = 0.99f * e1.x + 0.005f * s1v.x; w1.y = 0.99f * e1.y + 0.005f * s1v.y;
  w1.z = 0.99f * e1.z + 0.005f * s1v.z; w1.w = 0.99f * e1.w + 0.005f * s1v.w;
  float4* ow = reinterpret_cast<float4*>(out_ew + (size_t)k * N_EMBED);
  ow[lane] = w0; ow[lane + 64] = w1;
  float4 q0, q1;
  q0.x = w0.x / sz; q0.y = w0.y / sz; q0.z = w0.z / sz; q0.w = w0.w / sz;
  q1.x = w1.x / sz; q1.y = w1.y / sz; q1.z = w1.z / sz; q1.w = w1.w / sz;
  float4* okw = reinterpret_cast<float4*>(out_kw + (size_t)k * N_EMBED);
  okw[lane] = q0; okw[lane + 64] = q1;
}

// ---------- quantized = x + value_w[idx] (fallback paths only) ----------
__global__ void k_quant(const float* __restrict__ x, const float* __restrict__ value_w,
                        const int* __restrict__ idx, float* __restrict__ q) {
  int gid = blockIdx.x * blockDim.x + threadIdx.x;
  int t = gid >> 7, d4 = gid & 127;
  float4 xv = reinterpret_cast<const float4*>(x)[gid];
  float4 v = reinterpret_cast<const float4*>(value_w + (size_t)idx[t] * N_EMBED)[d4];
  float4 o;
  o.x = xv.x + v.x; o.y = xv.y + v.y; o.z = xv.z + v.z; o.w = xv.w + v.w;
  reinterpret_cast<float4*>(q)[gid] = o;
}

// ---------- single-stage MFMA GEMM + argmin (R6-proven; ws fallback) ----------
__global__ __launch_bounds__(256) void k_mfma_argmin(
    const __bf16* __restrict__ xp, const __bf16* __restrict__ kp,
    const float* __restrict__ h, unsigned long long* __restrict__ best) {
  __shared__ __bf16 AS[BMr * BKe];
  __shared__ __bf16 BS[BNr * BKe];
  const int nb = blockIdx.x, mb = blockIdx.y;
  const int m0 = mb * BMr, n0 = nb * BNr;
  const int tid = threadIdx.x;
  const int lane = tid & 63;
  const int wid = tid >> 6;
  const int wm = (wid >> 1) * 64, wn = (wid & 1) * 64;
  f32x4 acc[4][4] = {};
  const int soff = tid * 16;
  for (int ks = 0; ks < KP; ks += BKe) {
    __syncthreads();
    #pragma unroll
    for (int i = 0; i < 4; ++i) {
      int off = i * 4096 + soff;
      int row = off >> 7;
      int inner = (off & 127) ^ ((row & 7) << 4);
      gl2lds16(xp + (size_t)(m0 + row) * KP + ks + (inner >> 1), (char*)AS + off);
      gl2lds16(kp + (size_t)(n0 + row) * KP + ks + (inner >> 1), (char*)BS + off);
    }
    asm volatile("s_waitcnt vmcnt(0)" ::: "memory");
    __syncthreads();
    #pragma unroll
    for (int kk = 0; kk < 2; ++kk) {
      const int cbyte = kk * 64 + (lane >> 4) * 16;
      bf16x8 af[4], bb[4];
      #pragma unroll
      for (int i = 0; i < 4; ++i) {
        int arow = wm + i * 16 + (lane & 15);
        af[i] = *(const bf16x8*)((const char*)AS + arow * 128 + (cbyte ^ ((arow & 7) << 4)));
        int brow = wn + i * 16 + (lane & 15);
        bb[i] = *(const bf16x8*)((const char*)BS + brow * 128 + (cbyte ^ ((brow & 7) << 4)));
      }
      #pragma unroll
      for (int i = 0; i < 4; ++i)
        #pragma unroll
        for (int j = 0; j < 4; ++j)
          acc[i][j] = __builtin_amdgcn_mfma_f32_16x16x32_bf16(af[i], bb[j], acc[i][j], 0, 0, 0);
    }
  }
  const int rgrp = lane >> 4;
  const int cidx = lane & 15;
  #pragma unroll
  for (int i = 0; i < 4; ++i) {
    #pragma unroll
    for (int r = 0; r < 4; ++r) {
      unsigned long long m = ~0ull;
      #pragma unroll
      for (int j = 0; j < 4; ++j) {
        int kk = n0 + wn + j * 16 + cidx;
        float score = h[kk] - acc[i][j][r];
        unsigned long long cand =
            ((unsigned long long)fkey(score) << 32) | (unsigned int)kk;
        m = umin64(m, cand);
      }
      #pragma unroll
      for (int msk = 1; msk < 16; msk <<= 1) m = umin64(m, __shfl_xor(m, msk));
      if (cidx == 0) {
        int row = m0 + wm + i * 16 + rgrp * 4 + r;
        atomicMin(&best[row], m);
      }
    }
  }
}

// ---------- f32 fallback GEMM+argmin ----------
#define BT 128
#define BK 128
#define DC 32
__global__ __launch_bounds__(256, 2) void k_gemm_argmin(
    const float* __restrict__ x, const float* __restrict__ key_w,
    const float* __restrict__ h, unsigned long long* __restrict__ best) {
  __shared__ float4 XS[BT * 8];
  __shared__ float4 KS[BK * 8];
  const int kb = blockIdx.x, tb = blockIdx.y;
  const int t0 = tb * BT, k0 = kb * BK;
  const int tid = threadIdx.x;
  const int tx = tid & 15;
  const int tyg = tid >> 4;
  float acc[8][8];
  #pragma unroll
  for (int i = 0; i < 8; ++i)
    #pragma unroll
    for (int j = 0; j < 8; ++j) acc[i][j] = 0.f;
  for (int dc = 0; dc < N_EMBED; dc += DC) {
    __syncthreads();
    #pragma unroll
    for (int ld = 0; ld < 4; ++ld) {
      int li = ld * 256 + tid;
      int row = li >> 3, c4 = li & 7;
      XS[row * 8 + (c4 ^ (row & 7))] =
          *reinterpret_cast<const float4*>(x + (size_t)(t0 + row) * N_EMBED + dc + c4 * 4);
      KS[row * 8 + (c4 ^ (row & 7))] =
          *reinterpret_cast<const float4*>(key_w + (size_t)(k0 + row) * N_EMBED + dc + c4 * 4);
    }
    __syncthreads();
    #pragma unroll
    for (int d4 = 0; d4 < 8; ++d4) {
      float4 a[8], b[8];
      #pragma unroll
      for (int j = 0; j < 8; ++j) {
        a[j] = XS[(tyg + 16 * j) * 8 + (d4 ^ (tyg & 7))];
        b[j] = KS[(tx  + 16 * j) * 8 + (d4 ^ (tx  & 7))];
      }
      #pragma unroll
      for (int i = 0; i < 8; ++i) {
        float4 av = a[i];
        #pragma unroll
        for (int j = 0; j < 8; ++j) {
          float4 bv = b[j];
          acc[i][j] = fmaf(av.x, bv.x, fmaf(av.y, bv.y,
                      fmaf(av.z, bv.z, fmaf(av.w, bv.w, acc[i][j]))));
        }
      }
    }
  }
  #pragma unroll
  for (int i = 0; i < 8; ++i) {
    unsigned long long m = ~0ull;
    #pragma unroll
    for (int j = 0; j < 8; ++j) {
      int kk = k0 + tx + 16 * j;
      float score = h[kk] - acc[i][j];
      unsigned long long cand =
          ((unsigned long long)fkey(score) << 32) | (unsigned int)kk;
      m = umin64(m, cand);
    }
    #pragma unroll
    for (int mask = 1; mask < 16; mask <<= 1) m = umin64(m, __shfl_xor(m, mask));
    if (tx == 0) atomicMin(&best[t0 + tyg + 16 * i], m);
  }
}

// ---------- legacy aux (fallback paths) ----------
__global__ void k_extract_counts(const unsigned long long* __restrict__ best,
                                 int* __restrict__ idx, float* __restrict__ out_en) {
  int t = blockIdx.x * blockDim.x + threadIdx.x;
  if (t < T_TOKENS) {
    int k = (int)(unsigned int)(best[t] & 0xffffffffull);
    idx[t] = k;
    atomicAdd(&out_en[k], 0.005f);
  }
}
__global__ void k_quant_scatter(const float* __restrict__ x,
                                const float* __restrict__ value_w,
                                const int* __restrict__ idx,
                                float* __restrict__ q, float* __restrict__ out_ew) {
  int gid = blockIdx.x * blockDim.x + threadIdx.x;
  int t = gid >> 7, d4 = gid & 127;
  float4 xv = reinterpret_cast<const float4*>(x)[gid];
  int k = idx[t];
  float4 v = reinterpret_cast<const float4*>(value_w + (size_t)k * N_EMBED)[d4];
  float4 o;
  o.x = xv.x + v.x; o.y = xv.y + v.y; o.z = xv.z + v.z; o.w = xv.w + v.w;
  reinterpret_cast<float4*>(q)[gid] = o;
  const float c = 0.005f;
  float* dst = out_ew + (size_t)k * N_EMBED + d4 * 4;
  atomicAdd(dst + 0, c * xv.x);
  atomicAdd(dst + 1, c * xv.y);
  atomicAdd(dst + 2, c * xv.z);
  atomicAdd(dst + 3, c * xv.w);
}
__global__ void k_scaleN(const float* __restrict__ ema_n, float* __restrict__ out_en) {
  int k = blockIdx.x * blockDim.x + threadIdx.x;
  if (k < N_TOKEN) out_en[k] = 0.99f * ema_n[k];
}
__global__ void k_scaleW(const float* __restrict__ ema_w, float* __restrict__ out_ew) {
  int gid = blockIdx.x * blockDim.x + threadIdx.x;
  float4 v = reinterpret_cast<const float4*>(ema_w)[gid];
  float4 o;
  o.x = 0.99f * v.x; o.y = 0.99f * v.y; o.z = 0.99f * v.z; o.w = 0.99f * v.w;
  reinterpret_cast<float4*>(out_ew)[gid] = o;
}
__global__ void k_sumn(const float* __restrict__ en, float* __restrict__ nsum) {
  __shared__ float sm[256];
  float s = 0.f;
  for (int i = threadIdx.x; i < N_TOKEN; i += 256) s += en[i];
  sm[threadIdx.x] = s;
  __syncthreads();
  for (int off = 128; off; off >>= 1) {
    if (threadIdx.x < off) sm[threadIdx.x] += sm[threadIdx.x + off];
    __syncthreads();
  }
  if (threadIdx.x == 0) *nsum = sm[0];
}
__global__ void k_keyw(const float* __restrict__ out_ew, const float* __restrict__ out_en,
                       const float* __restrict__ nsum, float* __restrict__ out_kw) {
  int gid = blockIdx.x * blockDim.x + threadIdx.x;
  int k = gid >> 7;
  float n = *nsum;
  float sz = (out_en[k] + 1e-8f) / (n + 1e-8f * (float)N_TOKEN) * n;
  float4 w = reinterpret_cast<const float4*>(out_ew)[gid];
  float4 o;
  o.x = w.x / sz; o.y = w.y / sz; o.z = w.z / sz; o.w = w.w / sz;
  reinterpret_cast<float4*>(out_kw)[gid] = o;
}

// ---------- launcher ----------
extern "C" void kernel_launch(void* const* d_in, const int* in_sizes, int n_in,
                              void* d_out, int out_size, void* d_ws, size_t ws_size,
                              hipStream_t stream) {
  const float* x       = (const float*)d_in[0];
  const float* key_w   = (const float*)d_in[1];
  const float* value_w = (const float*)d_in[2];
  const float* ema_n   = (const float*)d_in[3];
  const float* ema_w   = (const float*)d_in[4];

  float* out_q  = (float*)d_out;
  float* out_en = out_q + 8388608;
  float* out_ew = out_en + N_TOKEN;
  float* out_kw = out_ew + 4194304;

  // ---- two-stage layout ----
  const size_t SLOTS_B = (size_t)T_TOKENS * NBG * 16;              // 2 MiB
  const size_t XP_B    = (size_t)T_TOKENS * KP * 2;                // 48 MiB
  const size_t KP_B    = (size_t)N_TOKEN * KP * 2;                 // 24 MiB
  char* base = (char*)d_ws;
  float4* slots = (float4*)base;
  __bf16* xp3 = (__bf16*)(base + SLOTS_B);
  __bf16* kp3 = (__bf16*)(base + SLOTS_B + XP_B);
  char* tail  = base + SLOTS_B + XP_B + KP_B;
  float* h                  = (float*)(tail + 0);         // 32 KiB
  int*   idx                = (int*)(tail + 32768);       // 64 KiB
  unsigned int* tlist       = (unsigned int*)(tail + 98304);   // 64 KiB
  unsigned long long* rbest = (unsigned long long*)(tail + 163840);  // 128 KiB
  unsigned int* ucount      = (unsigned int*)(tail + 294912);  // 256 B
  float* nsum               = (float*)(tail + 295168);    // 256 B
  int* counts               = (int*)(tail + 295424);      // 32 KiB
  int* offs                 = (int*)(tail + 328192);      // 32 KiB
  int* cursor               = (int*)(tail + 360960);      // 32 KiB
  int* tok                  = (int*)(tail + 393728);      // 64 KiB
  const size_t ws_need2 = SLOTS_B + XP_B + KP_B + 459264;

  // ---- R6 single-stage layout (fallback) ----
  unsigned long long* f_best = (unsigned long long*)d_ws;
  int*   f_idx  = (int*)((char*)d_ws + 131072);
  float* f_h    = (float*)((char*)d_ws + 196608);
  float* f_nsum = (float*)((char*)d_ws + 229376);
  __bf16* f_xp  = (__bf16*)((char*)d_ws + 262144);
  __bf16* f_kp  = (__bf16*)((char*)d_ws + 262144 + XP_B);
  const size_t ws_need1 = 262144 + XP_B + KP_B;

  if (ws_size >= ws_need2) {
    // ---------- two-stage path ----------
    k_pack_all<<<10242, 256, 0, stream>>>(x, key_w, ema_n, xp3, kp3, h, nsum,
                                          ucount, counts);
    {
      dim3 grid(N_TOKEN / (BNr * NBG), T_TOKENS / BMr);   // 8 x 128
      k_mfma_top2<<<grid, 256, 0, stream>>>(xp3, kp3, h, slots);
    }
    k_top2_reduce<<<T_TOKENS / 32, 256, 0, stream>>>(slots, idx, tlist, ucount,
                                                     counts, rbest);
    {
      dim3 grid(N_TOKEN / BNr, T_TOKENS / BMr);
      k_mfma_refine<<<grid, 256, 0, stream>>>(xp3, kp3, h, tlist, ucount, rbest);
    }
    k_finalize<<<T_TOKENS / 256, 256, 0, stream>>>(rbest, tlist, ucount, idx, counts);

    k_scan<<<1, 256, 0, stream>>>(counts, offs, cursor);
    k_place<<<T_TOKENS / 256, 256, 0, stream>>>(idx, cursor, tok);
    k_update<<<N_TOKEN / 4, 256, 0, stream>>>(x, ema_n, ema_w, value_w, counts,
                                              offs, tok, nsum,
                                              out_en, out_ew, out_kw, out_q);
  } else if (ws_size >= ws_need1) {
    // ---------- R6 single-stage path ----------
    hipMemsetAsync(f_best, 0xFF, (size_t)T_TOKENS * 8, stream);
    k_pack_x<<<(T_TOKENS * (N_EMBED / 4)) / 256, 256, 0, stream>>>(x, f_xp);
    k_pack_k_norm<<<N_TOKEN / 4, 256, 0, stream>>>(key_w, f_kp, f_h);
    dim3 grid(N_TOKEN / BNr, T_TOKENS / BMr);
    k_mfma_argmin<<<grid, 256, 0, stream>>>(f_xp, f_kp, f_h, f_best);

    k_scaleN<<<N_TOKEN / 256, 256, 0, stream>>>(ema_n, out_en);
    k_extract_counts<<<T_TOKENS / 256, 256, 0, stream>>>(f_best, f_idx, out_en);
    k_scaleW<<<(N_TOKEN * (N_EMBED / 4)) / 256, 256, 0, stream>>>(ema_w, out_ew);
    k_quant_scatter<<<(T_TOKENS * (N_EMBED / 4)) / 256, 256, 0, stream>>>(
        x, value_w, f_idx, out_q, out_ew);
    k_sumn<<<1, 256, 0, stream>>>(out_en, f_nsum);
    k_keyw<<<(N_TOKEN * (N_EMBED / 4)) / 256, 256, 0, stream>>>(out_ew, out_en, f_nsum, out_kw);
  } else {
    // ---------- deep fallback: f32 vector GEMM ----------
    hipMemsetAsync(f_best, 0xFF, (size_t)T_TOKENS * 8, stream);
    k_hnorm<<<N_TOKEN / 4, 256, 0, stream>>>(key_w, f_h);
    dim3 grid(N_TOKEN / BK, T_TOKENS / BT);
    k_gemm_argmin<<<grid, 256, 0, stream>>>(x, key_w, f_h, f_best);

    k_scaleN<<<N_TOKEN / 256, 256, 0, stream>>>(ema_n, out_en);
    k_extract_counts<<<T_TOKENS / 256, 256, 0, stream>>>(f_best, f_idx, out_en);
    k_scaleW<<<(N_TOKEN * (N_EMBED / 4)) / 256, 256, 0, stream>>>(ema_w, out_ew);
    k_quant_scatter<<<(T_TOKENS * (N_EMBED / 4)) / 256, 256, 0, stream>>>(
        x, value_w, f_idx, out_q, out_ew);
    k_sumn<<<1, 256, 0, stream>>>(out_en, f_nsum);
    k_keyw<<<(N_TOKEN * (N_EMBED / 4)) / 256, 256, 0, stream>>>(out_ew, out_en, f_nsum, out_kw);
  }
}

// Round 13
// 371.178 us; speedup vs baseline: 2.2789x; 1.0721x over previous
//
#include <hip/hip_runtime.h>

#define N_TOKEN 8192
#define N_EMBED 512
#define T_TOKENS 16384
#define KP 1536       // packed K = 3 * 512
#define MARGIN 0.45f  // score-gap certainty threshold (~9 sigma of approx error)
#define NBG 8         // nb tiles per top2 block

typedef __bf16 bf16x8 __attribute__((ext_vector_type(8)));
typedef __bf16 bf16x4 __attribute__((ext_vector_type(4)));
typedef float f32x4 __attribute__((ext_vector_type(4)));

// ---------- helpers ----------
__device__ __forceinline__ unsigned int fkey(float f) {
  unsigned int u = __float_as_uint(f);
  return (u & 0x80000000u) ? ~u : (u | 0x80000000u);
}
__device__ __forceinline__ void gl2lds16(const void* gsrc, void* lds) {
  __builtin_amdgcn_global_load_lds(
      (const __attribute__((address_space(1))) unsigned int*)gsrc,
      (__attribute__((address_space(3))) unsigned int*)lds, 16, 0, 0);
}
__device__ __forceinline__ unsigned long long umin64(unsigned long long a,
                                                     unsigned long long b) {
  return a < b ? a : b;
}

// ---------- pack bodies (shared by standalone + fused kernels) ----------
__device__ __forceinline__ void pack_x_body(const float* __restrict__ x,
                                            __bf16* __restrict__ xp, int gid) {
  int t = gid >> 7, d4 = gid & 127;
  float4 v = reinterpret_cast<const float4*>(x)[gid];
  bf16x4 hi, lo;
  hi[0] = (__bf16)v.x; hi[1] = (__bf16)v.y; hi[2] = (__bf16)v.z; hi[3] = (__bf16)v.w;
  lo[0] = (__bf16)(v.x - (float)hi[0]);
  lo[1] = (__bf16)(v.y - (float)hi[1]);
  lo[2] = (__bf16)(v.z - (float)hi[2]);
  lo[3] = (__bf16)(v.w - (float)hi[3]);
  __bf16* row = xp + (size_t)t * KP + d4 * 4;
  *(bf16x4*)(row)        = hi;
  *(bf16x4*)(row + 512)  = hi;
  *(bf16x4*)(row + 1024) = lo;
}

__device__ __forceinline__ void pack_k_body(const float* __restrict__ kw,
                                            __bf16* __restrict__ kp,
                                            float* __restrict__ h,
                                            int blk, int tid) {
  int row = blk * 4 + (tid >> 6);
  int lane = tid & 63;
  const float4* src = reinterpret_cast<const float4*>(kw + (size_t)row * N_EMBED);
  __bf16* dst = kp + (size_t)row * KP;
  float s = 0.f;
  #pragma unroll
  for (int c = 0; c < 2; ++c) {
    int f4 = lane + c * 64;
    float4 v = src[f4];
    s += v.x*v.x + v.y*v.y + v.z*v.z + v.w*v.w;
    bf16x4 hi, lo;
    hi[0] = (__bf16)v.x; hi[1] = (__bf16)v.y; hi[2] = (__bf16)v.z; hi[3] = (__bf16)v.w;
    lo[0] = (__bf16)(v.x - (float)hi[0]);
    lo[1] = (__bf16)(v.y - (float)hi[1]);
    lo[2] = (__bf16)(v.z - (float)hi[2]);
    lo[3] = (__bf16)(v.w - (float)hi[3]);
    *(bf16x4*)(dst + f4 * 4)        = hi;
    *(bf16x4*)(dst + 512 + f4 * 4)  = lo;
    *(bf16x4*)(dst + 1024 + f4 * 4) = hi;
  }
  #pragma unroll
  for (int off = 32; off; off >>= 1) s += __shfl_down(s, off);
  if (lane == 0) h[row] = 0.5f * s;
}

// ---------- fused prep: pack_x | pack_k+norm | sum(ema_n)+init ----------
__global__ void k_pack_all(const float* __restrict__ x, const float* __restrict__ kw,
                           const float* __restrict__ ema_n,
                           __bf16* __restrict__ xp, __bf16* __restrict__ kp,
                           float* __restrict__ h, float* __restrict__ nsum,
                           unsigned int* __restrict__ ucount, int* __restrict__ counts) {
  int b = blockIdx.x;
  if (b < 8192) {
    pack_x_body(x, xp, b * 256 + threadIdx.x);
  } else if (b < 10240) {
    pack_k_body(kw, kp, h, b - 8192, threadIdx.x);
  } else if (b == 10240) {
    __shared__ float sm[256];
    float s = 0.f;
    for (int i = threadIdx.x; i < N_TOKEN; i += 256) s += ema_n[i];
    sm[threadIdx.x] = s;
    __syncthreads();
    for (int off = 128; off; off >>= 1) {
      if (threadIdx.x < off) sm[threadIdx.x] += sm[threadIdx.x + off];
      __syncthreads();
    }
    if (threadIdx.x == 0) { *nsum = sm[0]; *ucount = 0u; }
  } else {
    for (int i = threadIdx.x; i < N_TOKEN; i += 256) counts[i] = 0;
  }
}

// ---------- standalone packs (fallback paths) ----------
__global__ void k_pack_x(const float* __restrict__ x, __bf16* __restrict__ xp) {
  pack_x_body(x, xp, blockIdx.x * blockDim.x + threadIdx.x);
}
__global__ void k_pack_k_norm(const float* __restrict__ kw, __bf16* __restrict__ kp,
                              float* __restrict__ h) {
  pack_k_body(kw, kp, h, blockIdx.x, threadIdx.x);
}

// ---------- norms only (deep fallback) ----------
__global__ void k_hnorm(const float* __restrict__ key_w, float* __restrict__ h) {
  int code = blockIdx.x * 4 + (threadIdx.x >> 6);
  int lane = threadIdx.x & 63;
  const float4* row = reinterpret_cast<const float4*>(key_w + (size_t)code * N_EMBED);
  float s = 0.f;
  float4 v0 = row[lane];
  float4 v1 = row[lane + 64];
  s += v0.x*v0.x + v0.y*v0.y + v0.z*v0.z + v0.w*v0.w;
  s += v1.x*v1.x + v1.y*v1.y + v1.z*v1.z + v1.w*v1.w;
  #pragma unroll
  for (int off = 32; off; off >>= 1) s += __shfl_down(s, off);
  if (lane == 0) h[code] = 0.5f * s;
}

#define BMr 128
#define BNr 128
#define BKe 64   // refine K-step (128 B rows)

// ---------- PASS 1: K=512 hi*hi GEMM; BK=128 (4 K-steps); 8 nb tiles/block ---
// XCD-locality swizzle: each XCD owns a 16-mb A-band reused across all B tiles.
__global__ __launch_bounds__(256) void k_mfma_top2(
    const __bf16* __restrict__ xp, const __bf16* __restrict__ kp,
    const float* __restrict__ h, float4* __restrict__ slots) {
  __shared__ __bf16 AS[128 * 128];  // 32 KB, 256 B rows
  __shared__ __bf16 BS[128 * 128];  // 32 KB

  // 1024 blocks; xcd = b&7 (dispatch heuristic), chunk walks mb inner, nbg outer
  const int b = blockIdx.x;
  const int xcd = b & 7, chunk = b >> 3;
  const int mb = xcd * 16 + (chunk & 15);
  const int nbg = chunk >> 4;
  const int m0 = mb * BMr;
  const int tid = threadIdx.x;
  const int lane = tid & 63;
  const int wid = tid >> 6;
  const int wm = wid * 32;           // 4 waves x 32 rows
  const int soff = tid * 16;
  const int rgrp = lane >> 4;
  const int cidx = lane & 15;

  float rs1[8], rs2[8];
  int rc1[8];
  #pragma unroll
  for (int u = 0; u < 8; ++u) { rs1[u] = 3.4e38f; rs2[u] = 3.4e38f; rc1[u] = 0; }

  for (int q = 0; q < NBG; ++q) {
    const int n0 = (nbg * NBG + q) * BNr;
    f32x4 acc[2][8] = {};

    for (int ks = 0; ks < 512; ks += 128) {   // hi columns, 256 B rows
      __syncthreads();
      #pragma unroll
      for (int i = 0; i < 8; ++i) {
        int off = i * 4096 + soff;
        int row = off >> 8;
        int inner = (off & 255) ^ ((row & 7) << 4);
        gl2lds16(xp + (size_t)(m0 + row) * KP + ks + (inner >> 1), (char*)AS + off);
        gl2lds16(kp + (size_t)(n0 + row) * KP + ks + (inner >> 1), (char*)BS + off);
      }
      asm volatile("s_waitcnt vmcnt(0)" ::: "memory");
      __syncthreads();

      #pragma unroll
      for (int kk = 0; kk < 4; ++kk) {
        const int cbyte = kk * 64 + (lane >> 4) * 16;
        bf16x8 af[2], bb[8];
        #pragma unroll
        for (int i = 0; i < 2; ++i) {
          int arow = wm + i * 16 + (lane & 15);
          af[i] = *(const bf16x8*)((const char*)AS + arow * 256 + (cbyte ^ ((arow & 7) << 4)));
        }
        #pragma unroll
        for (int j = 0; j < 8; ++j) {
          int brow = j * 16 + (lane & 15);
          bb[j] = *(const bf16x8*)((const char*)BS + brow * 256 + (cbyte ^ ((brow & 7) << 4)));
        }
        #pragma unroll
        for (int i = 0; i < 2; ++i)
          #pragma unroll
          for (int j = 0; j < 8; ++j)
            acc[i][j] = __builtin_amdgcn_mfma_f32_16x16x32_bf16(af[i], bb[j], acc[i][j], 0, 0, 0);
      }
    }

    // insert this tile's 8 scores per output row into running top-2
    #pragma unroll
    for (int i = 0; i < 2; ++i) {
      #pragma unroll
      for (int r = 0; r < 4; ++r) {
        const int u = i * 4 + r;
        float s1 = rs1[u], s2 = rs2[u];
        int c1 = rc1[u];
        #pragma unroll
        for (int j = 0; j < 8; ++j) {
          int kk = n0 + j * 16 + cidx;
          float sc = h[kk] - acc[i][j][r];
          if (sc < s1) { s2 = s1; s1 = sc; c1 = kk; }
          else s2 = fminf(s2, sc);
        }
        rs1[u] = s1; rs2[u] = s2; rc1[u] = c1;
      }
    }
  }

  // one butterfly per output row; slot per (row, nbg)
  #pragma unroll
  for (int u = 0; u < 8; ++u) {
    float s1 = rs1[u], s2 = rs2[u];
    int c1 = rc1[u];
    #pragma unroll
    for (int msk = 1; msk < 16; msk <<= 1) {
      float o1 = __shfl_xor(s1, msk);
      float o2 = __shfl_xor(s2, msk);
      int   oc = __shfl_xor(c1, msk);
      float ns2 = fminf(fminf(s2, o2), fmaxf(s1, o1));
      bool take = o1 < s1;
      s1 = take ? o1 : s1;
      c1 = take ? oc : c1;
      s2 = ns2;
    }
    if (cidx == 0) {
      int row = m0 + wm + (u >> 2) * 16 + rgrp * 4 + (u & 3);
      float4 p;
      p.x = s1; p.y = s2; p.z = __int_as_float(c1); p.w = 0.f;
      slots[(size_t)row * NBG + nbg] = p;
    }
  }
}

// ---------- reduce: global top-2 (8 slots) -> certain idx (+count) or list ---
__global__ void k_top2_reduce(const float4* __restrict__ slots,
                              int* __restrict__ idx, unsigned int* __restrict__ tlist,
                              unsigned int* __restrict__ ucount,
                              int* __restrict__ counts,
                              unsigned long long* __restrict__ rbest) {
  int tid = threadIdx.x;
  int lane = tid & 63, wid = tid >> 6;
  int row = blockIdx.x * 32 + wid * 8 + (lane >> 3);
  int slot = lane & 7;
  float4 a = slots[(size_t)row * NBG + slot];
  float s1 = a.x, s2 = a.y;
  int c1 = __float_as_int(a.z);
  #pragma unroll
  for (int msk = 1; msk < 8; msk <<= 1) {
    float o1 = __shfl_xor(s1, msk);
    float o2 = __shfl_xor(s2, msk);
    int   oc = __shfl_xor(c1, msk);
    float ns2 = fminf(fminf(s2, o2), fmaxf(s1, o1));
    bool take = o1 < s1;
    s1 = take ? o1 : s1;
    c1 = take ? oc : c1;
    s2 = ns2;
  }
  if (slot == 0) {
    if (s2 - s1 >= MARGIN) {
      idx[row] = c1;
      atomicAdd(&counts[c1], 1);
    } else {
      unsigned int p = atomicAdd(ucount, 1u);
      tlist[p] = (unsigned int)row;
      rbest[p] = ~0ull;   // init for refine's atomicMin
    }
  }
}

// ---------- REFINE: 3-term K=1536 exact-class GEMM over uncertain tokens ----
__global__ __launch_bounds__(256) void k_mfma_refine(
    const __bf16* __restrict__ xp, const __bf16* __restrict__ kp,
    const float* __restrict__ h, const unsigned int* __restrict__ tlist,
    const unsigned int* __restrict__ ucount, unsigned long long* __restrict__ rbest) {
  const unsigned int uc = *ucount;
  const int nb = blockIdx.x, mb = blockIdx.y;
  const int m0 = mb * BMr;
  if ((unsigned int)m0 >= uc) return;

  __shared__ __bf16 AS[BMr * BKe];
  __shared__ __bf16 BS[BNr * BKe];

  const int n0 = nb * BNr;
  const int tid = threadIdx.x;
  const int lane = tid & 63;
  const int wid = tid >> 6;
  const int wm = (wid >> 1) * 64, wn = (wid & 1) * 64;

  const int r0 = tid >> 3;  // 0..31
  size_t abase[4];
  #pragma unroll
  for (int i = 0; i < 4; ++i) {
    int p = m0 + r0 + 32 * i;
    int pc = p < (int)uc ? p : (int)uc - 1;
    abase[i] = (size_t)tlist[pc] * KP;
  }

  f32x4 acc[4][4] = {};
  const int soff = tid * 16;
  const int innerC = (soff & 127) ^ ((r0 & 7) << 4);

  for (int ks = 0; ks < KP; ks += BKe) {
    __syncthreads();
    #pragma unroll
    for (int i = 0; i < 4; ++i) {
      int off = i * 4096 + soff;
      int brow = (off >> 7);
      gl2lds16(xp + abase[i] + ks + (innerC >> 1), (char*)AS + off);
      int binner = (off & 127) ^ ((brow & 7) << 4);
      gl2lds16(kp + (size_t)(n0 + brow) * KP + ks + (binner >> 1), (char*)BS + off);
    }
    asm volatile("s_waitcnt vmcnt(0)" ::: "memory");
    __syncthreads();

    #pragma unroll
    for (int kk = 0; kk < 2; ++kk) {
      const int cbyte = kk * 64 + (lane >> 4) * 16;
      bf16x8 af[4], bb[4];
      #pragma unroll
      for (int i = 0; i < 4; ++i) {
        int arow = wm + i * 16 + (lane & 15);
        af[i] = *(const bf16x8*)((const char*)AS + arow * 128 + (cbyte ^ ((arow & 7) << 4)));
        int brow = wn + i * 16 + (lane & 15);
        bb[i] = *(const bf16x8*)((const char*)BS + brow * 128 + (cbyte ^ ((brow & 7) << 4)));
      }
      #pragma unroll
      for (int i = 0; i < 4; ++i)
        #pragma unroll
        for (int j = 0; j < 4; ++j)
          acc[i][j] = __builtin_amdgcn_mfma_f32_16x16x32_bf16(af[i], bb[j], acc[i][j], 0, 0, 0);
    }
  }

  const int rgrp = lane >> 4;
  const int cidx = lane & 15;
  #pragma unroll
  for (int i = 0; i < 4; ++i) {
    #pragma unroll
    for (int r = 0; r < 4; ++r) {
      unsigned long long m = ~0ull;
      #pragma unroll
      for (int j = 0; j < 4; ++j) {
        int kk = n0 + wn + j * 16 + cidx;
        float score = h[kk] - acc[i][j][r];
        unsigned long long cand =
            ((unsigned long long)fkey(score) << 32) | (unsigned int)kk;
        m = umin64(m, cand);
      }
      #pragma unroll
      for (int msk = 1; msk < 16; msk <<= 1) m = umin64(m, __shfl_xor(m, msk));
      if (cidx == 0) {
        int p = m0 + wm + i * 16 + rgrp * 4 + r;
        if ((unsigned int)p < uc) atomicMin(&rbest[p], m);
      }
    }
  }
}

// ---------- finalize: uncertain rows get refined index (+count) ----------
__global__ void k_finalize(const unsigned long long* __restrict__ rbest,
                           const unsigned int* __restrict__ tlist,
                           const unsigned int* __restrict__ ucount,
                           int* __restrict__ idx, int* __restrict__ counts) {
  unsigned int p = blockIdx.x * 256 + threadIdx.x;
  if (p < *ucount) {
    int k = (int)(unsigned int)(rbest[p] & 0xffffffffull);
    idx[tlist[p]] = k;
    atomicAdd(&counts[k], 1);
  }
}

// ---------- counting-sort CSR + fused EMA update ----------
__global__ void k_scan(const int* __restrict__ counts, int* __restrict__ offs,
                       int* __restrict__ cursor) {
  __shared__ int sa[256], sb[256];
  int tid = threadIdx.x;
  int base = tid * 32;
  int loc[32]; int s = 0;
  #pragma unroll
  for (int e = 0; e < 32; ++e) { loc[e] = s; s += counts[base + e]; }
  sa[tid] = s;
  __syncthreads();
  int* src = sa; int* dst = sb;
  for (int d = 1; d < 256; d <<= 1) {
    int v = src[tid] + (tid >= d ? src[tid - d] : 0);
    dst[tid] = v;
    __syncthreads();
    int* tmp = src; src = dst; dst = tmp;
  }
  int excl = src[tid] - s;
  #pragma unroll
  for (int e = 0; e < 32; ++e) {
    int o = excl + loc[e];
    offs[base + e] = o;
    cursor[base + e] = o;
  }
}

__global__ void k_place(const int* __restrict__ idx, int* __restrict__ cursor,
                        int* __restrict__ tok) {
  int t = blockIdx.x * 256 + threadIdx.x;
  if (t < T_TOKENS) {
    int p = atomicAdd(&cursor[idx[t]], 1);
    tok[p] = t;
  }
}

// one wave per code: en; ew = 0.99*ema_w + 0.005*sum(x[tok]); kw = ew/sz;
// and quantized[t] = x[t] + value_w[k] for each token of this code (fused).
__global__ void k_update(const float* __restrict__ x, const float* __restrict__ ema_n,
                         const float* __restrict__ ema_w, const float* __restrict__ value_w,
                         const int* __restrict__ counts,
                         const int* __restrict__ offs, const int* __restrict__ tok,
                         const float* __restrict__ nsum,
                         float* __restrict__ out_en, float* __restrict__ out_ew,
                         float* __restrict__ out_kw, float* __restrict__ out_q) {
  int k = blockIdx.x * 4 + (threadIdx.x >> 6);
  int lane = threadIdx.x & 63;
  int cnt = counts[k];
  int off = offs[k];
  float en = 0.99f * ema_n[k] + 0.005f * (float)cnt;
  if (lane == 0) out_en[k] = en;
  float n = 0.99f * (*nsum) + 81.92f;   // 0.005 * 16384
  float sz = (en + 1e-8f) / (n + 1e-8f * (float)N_TOKEN) * n;

  const float4* er = reinterpret_cast<const float4*>(ema_w + (size_t)k * N_EMBED);
  float4 e0 = er[lane], e1 = er[lane + 64];
  const float4* vr = reinterpret_cast<const float4*>(value_w + (size_t)k * N_EMBED);
  float4 v0 = vr[lane], v1 = vr[lane + 64];
  float4 s0 = {0.f, 0.f, 0.f, 0.f}, s1v = {0.f, 0.f, 0.f, 0.f};
  for (int q = 0; q < cnt; ++q) {
    int t = tok[off + q];
    const float4* xr = reinterpret_cast<const float4*>(x + (size_t)t * N_EMBED);
    float4 a = xr[lane], b = xr[lane + 64];
    s0.x += a.x; s0.y += a.y; s0.z += a.z; s0.w += a.w;
    s1v.x += b.x; s1v.y += b.y; s1v.z += b.z; s1v.w += b.w;
    float4 qa, qb;
    qa.x = a.x + v0.x; qa.y = a.y + v0.y; qa.z = a.z + v0.z; qa.w = a.w + v0.w;
    qb.x = b.x + v1.x; qb.y = b.y + v1.y; qb.z = b.z + v1.z; qb.w = b.w + v1.w;
    float4* oq = reinterpret_cast<float4*>(out_q + (size_t)t * N_EMBED);
    oq[lane] = qa; oq[lane + 64] = qb;
  }
  float4 w0, w1;
  w0.x = 0.99f * e0.x + 0.005f * s0.x;  w0.y = 0.99f * e0.y + 0.005f * s0.y;
  w0.z = 0.99f * e0.z + 0.005f * s0.z;  w0.w = 0.99f * e0.w + 0.005f * s0.w;
  w1.x = 0.99f * e1.x + 0.005f * s1v.x; w1.y = 0.99f * e1.y + 0.005f * s1v.y;
  w1.z = 0.99f * e1.z + 0.005f * s1v.z; w1.w = 0.99f * e1.w + 0.005f * s1v.w;
  float4* ow = reinterpret_cast<float4*>(out_ew + (size_t)k * N_EMBED);
  ow[lane] = w0; ow[lane + 64] = w1;
  float4 q0, q1;
  q0.x = w0.x / sz; q0.y = w0.y / sz; q0.z = w0.z / sz; q0.w = w0.w / sz;
  q1.x = w1.x / sz; q1.y = w1.y / sz; q1.z = w1.z / sz; q1.w = w1.w / sz;
  float4* okw = reinterpret_cast<float4*>(out_kw + (size_t)k * N_EMBED);
  okw[lane] = q0; okw[lane + 64] = q1;
}

// ---------- quantized = x + value_w[idx] (fallback paths only) ----------
__global__ void k_quant(const float* __restrict__ x, const float* __restrict__ value_w,
                        const int* __restrict__ idx, float* __restrict__ q) {
  int gid = blockIdx.x * blockDim.x + threadIdx.x;
  int t = gid >> 7, d4 = gid & 127;
  float4 xv = reinterpret_cast<const float4*>(x)[gid];
  float4 v = reinterpret_cast<const float4*>(value_w + (size_t)idx[t] * N_EMBED)[d4];
  float4 o;
  o.x = xv.x + v.x; o.y = xv.y + v.y; o.z = xv.z + v.z; o.w = xv.w + v.w;
  reinterpret_cast<float4*>(q)[gid] = o;
}

// ---------- single-stage MFMA GEMM + argmin (R6-proven; ws fallback) ----------
__global__ __launch_bounds__(256) void k_mfma_argmin(
    const __bf16* __restrict__ xp, const __bf16* __restrict__ kp,
    const float* __restrict__ h, unsigned long long* __restrict__ best) {
  __shared__ __bf16 AS[BMr * BKe];
  __shared__ __bf16 BS[BNr * BKe];
  const int nb = blockIdx.x, mb = blockIdx.y;
  const int m0 = mb * BMr, n0 = nb * BNr;
  const int tid = threadIdx.x;
  const int lane = tid & 63;
  const int wid = tid >> 6;
  const int wm = (wid >> 1) * 64, wn = (wid & 1) * 64;
  f32x4 acc[4][4] = {};
  const int soff = tid * 16;
  for (int ks = 0; ks < KP; ks += BKe) {
    __syncthreads();
    #pragma unroll
    for (int i = 0; i < 4; ++i) {
      int off = i * 4096 + soff;
      int row = off >> 7;
      int inner = (off & 127) ^ ((row & 7) << 4);
      gl2lds16(xp + (size_t)(m0 + row) * KP + ks + (inner >> 1), (char*)AS + off);
      gl2lds16(kp + (size_t)(n0 + row) * KP + ks + (inner >> 1), (char*)BS + off);
    }
    asm volatile("s_waitcnt vmcnt(0)" ::: "memory");
    __syncthreads();
    #pragma unroll
    for (int kk = 0; kk < 2; ++kk) {
      const int cbyte = kk * 64 + (lane >> 4) * 16;
      bf16x8 af[4], bb[4];
      #pragma unroll
      for (int i = 0; i < 4; ++i) {
        int arow = wm + i * 16 + (lane & 15);
        af[i] = *(const bf16x8*)((const char*)AS + arow * 128 + (cbyte ^ ((arow & 7) << 4)));
        int brow = wn + i * 16 + (lane & 15);
        bb[i] = *(const bf16x8*)((const char*)BS + brow * 128 + (cbyte ^ ((brow & 7) << 4)));
      }
      #pragma unroll
      for (int i = 0; i < 4; ++i)
        #pragma unroll
        for (int j = 0; j < 4; ++j)
          acc[i][j] = __builtin_amdgcn_mfma_f32_16x16x32_bf16(af[i], bb[j], acc[i][j], 0, 0, 0);
    }
  }
  const int rgrp = lane >> 4;
  const int cidx = lane & 15;
  #pragma unroll
  for (int i = 0; i < 4; ++i) {
    #pragma unroll
    for (int r = 0; r < 4; ++r) {
      unsigned long long m = ~0ull;
      #pragma unroll
      for (int j = 0; j < 4; ++j) {
        int kk = n0 + wn + j * 16 + cidx;
        float score = h[kk] - acc[i][j][r];
        unsigned long long cand =
            ((unsigned long long)fkey(score) << 32) | (unsigned int)kk;
        m = umin64(m, cand);
      }
      #pragma unroll
      for (int msk = 1; msk < 16; msk <<= 1) m = umin64(m, __shfl_xor(m, msk));
      if (cidx == 0) {
        int row = m0 + wm + i * 16 + rgrp * 4 + r;
        atomicMin(&best[row], m);
      }
    }
  }
}

// ---------- f32 fallback GEMM+argmin ----------
#define BT 128
#define BK 128
#define DC 32
__global__ __launch_bounds__(256, 2) void k_gemm_argmin(
    const float* __restrict__ x, const float* __restrict__ key_w,
    const float* __restrict__ h, unsigned long long* __restrict__ best) {
  __shared__ float4 XS[BT * 8];
  __shared__ float4 KS[BK * 8];
  const int kb = blockIdx.x, tb = blockIdx.y;
  const int t0 = tb * BT, k0 = kb * BK;
  const int tid = threadIdx.x;
  const int tx = tid & 15;
  const int tyg = tid >> 4;
  float acc[8][8];
  #pragma unroll
  for (int i = 0; i < 8; ++i)
    #pragma unroll
    for (int j = 0; j < 8; ++j) acc[i][j] = 0.f;
  for (int dc = 0; dc < N_EMBED; dc += DC) {
    __syncthreads();
    #pragma unroll
    for (int ld = 0; ld < 4; ++ld) {
      int li = ld * 256 + tid;
      int row = li >> 3, c4 = li & 7;
      XS[row * 8 + (c4 ^ (row & 7))] =
          *reinterpret_cast<const float4*>(x + (size_t)(t0 + row) * N_EMBED + dc + c4 * 4);
      KS[row * 8 + (c4 ^ (row & 7))] =
          *reinterpret_cast<const float4*>(key_w + (size_t)(k0 + row) * N_EMBED + dc + c4 * 4);
    }
    __syncthreads();
    #pragma unroll
    for (int d4 = 0; d4 < 8; ++d4) {
      float4 a[8], b[8];
      #pragma unroll
      for (int j = 0; j < 8; ++j) {
        a[j] = XS[(tyg + 16 * j) * 8 + (d4 ^ (tyg & 7))];
        b[j] = KS[(tx  + 16 * j) * 8 + (d4 ^ (tx  & 7))];
      }
      #pragma unroll
      for (int i = 0; i < 8; ++i) {
        float4 av = a[i];
        #pragma unroll
        for (int j = 0; j < 8; ++j) {
          float4 bv = b[j];
          acc[i][j] = fmaf(av.x, bv.x, fmaf(av.y, bv.y,
                      fmaf(av.z, bv.z, fmaf(av.w, bv.w, acc[i][j]))));
        }
      }
    }
  }
  #pragma unroll
  for (int i = 0; i < 8; ++i) {
    unsigned long long m = ~0ull;
    #pragma unroll
    for (int j = 0; j < 8; ++j) {
      int kk = k0 + tx + 16 * j;
      float score = h[kk] - acc[i][j];
      unsigned long long cand =
          ((unsigned long long)fkey(score) << 32) | (unsigned int)kk;
      m = umin64(m, cand);
    }
    #pragma unroll
    for (int mask = 1; mask < 16; mask <<= 1) m = umin64(m, __shfl_xor(m, mask));
    if (tx == 0) atomicMin(&best[t0 + tyg + 16 * i], m);
  }
}

// ---------- legacy aux (fallback paths) ----------
__global__ void k_extract_counts(const unsigned long long* __restrict__ best,
                                 int* __restrict__ idx, float* __restrict__ out_en) {
  int t = blockIdx.x * blockDim.x + threadIdx.x;
  if (t < T_TOKENS) {
    int k = (int)(unsigned int)(best[t] & 0xffffffffull);
    idx[t] = k;
    atomicAdd(&out_en[k], 0.005f);
  }
}
__global__ void k_quant_scatter(const float* __restrict__ x,
                                const float* __restrict__ value_w,
                                const int* __restrict__ idx,
                                float* __restrict__ q, float* __restrict__ out_ew) {
  int gid = blockIdx.x * blockDim.x + threadIdx.x;
  int t = gid >> 7, d4 = gid & 127;
  float4 xv = reinterpret_cast<const float4*>(x)[gid];
  int k = idx[t];
  float4 v = reinterpret_cast<const float4*>(value_w + (size_t)k * N_EMBED)[d4];
  float4 o;
  o.x = xv.x + v.x; o.y = xv.y + v.y; o.z = xv.z + v.z; o.w = xv.w + v.w;
  reinterpret_cast<float4*>(q)[gid] = o;
  const float c = 0.005f;
  float* dst = out_ew + (size_t)k * N_EMBED + d4 * 4;
  atomicAdd(dst + 0, c * xv.x);
  atomicAdd(dst + 1, c * xv.y);
  atomicAdd(dst + 2, c * xv.z);
  atomicAdd(dst + 3, c * xv.w);
}
__global__ void k_scaleN(const float* __restrict__ ema_n, float* __restrict__ out_en) {
  int k = blockIdx.x * blockDim.x + threadIdx.x;
  if (k < N_TOKEN) out_en[k] = 0.99f * ema_n[k];
}
__global__ void k_scaleW(const float* __restrict__ ema_w, float* __restrict__ out_ew) {
  int gid = blockIdx.x * blockDim.x + threadIdx.x;
  float4 v = reinterpret_cast<const float4*>(ema_w)[gid];
  float4 o;
  o.x = 0.99f * v.x; o.y = 0.99f * v.y; o.z = 0.99f * v.z; o.w = 0.99f * v.w;
  reinterpret_cast<float4*>(out_ew)[gid] = o;
}
__global__ void k_sumn(const float* __restrict__ en, float* __restrict__ nsum) {
  __shared__ float sm[256];
  float s = 0.f;
  for (int i = threadIdx.x; i < N_TOKEN; i += 256) s += en[i];
  sm[threadIdx.x] = s;
  __syncthreads();
  for (int off = 128; off; off >>= 1) {
    if (threadIdx.x < off) sm[threadIdx.x] += sm[threadIdx.x + off];
    __syncthreads();
  }
  if (threadIdx.x == 0) *nsum = sm[0];
}
__global__ void k_keyw(const float* __restrict__ out_ew, const float* __restrict__ out_en,
                       const float* __restrict__ nsum, float* __restrict__ out_kw) {
  int gid = blockIdx.x * blockDim.x + threadIdx.x;
  int k = gid >> 7;
  float n = *nsum;
  float sz = (out_en[k] + 1e-8f) / (n + 1e-8f * (float)N_TOKEN) * n;
  float4 w = reinterpret_cast<const float4*>(out_ew)[gid];
  float4 o;
  o.x = w.x / sz; o.y = w.y / sz; o.z = w.z / sz; o.w = w.w / sz;
  reinterpret_cast<float4*>(out_kw)[gid] = o;
}

// ---------- launcher ----------
extern "C" void kernel_launch(void* const* d_in, const int* in_sizes, int n_in,
                              void* d_out, int out_size, void* d_ws, size_t ws_size,
                              hipStream_t stream) {
  const float* x       = (const float*)d_in[0];
  const float* key_w   = (const float*)d_in[1];
  const float* value_w = (const float*)d_in[2];
  const float* ema_n   = (const float*)d_in[3];
  const float* ema_w   = (const float*)d_in[4];

  float* out_q  = (float*)d_out;
  float* out_en = out_q + 8388608;
  float* out_ew = out_en + N_TOKEN;
  float* out_kw = out_ew + 4194304;

  // ---- two-stage layout ----
  const size_t SLOTS_B = (size_t)T_TOKENS * NBG * 16;              // 2 MiB
  const size_t XP_B    = (size_t)T_TOKENS * KP * 2;                // 48 MiB
  const size_t KP_B    = (size_t)N_TOKEN * KP * 2;                 // 24 MiB
  char* base = (char*)d_ws;
  float4* slots = (float4*)base;
  __bf16* xp3 = (__bf16*)(base + SLOTS_B);
  __bf16* kp3 = (__bf16*)(base + SLOTS_B + XP_B);
  char* tail  = base + SLOTS_B + XP_B + KP_B;
  float* h                  = (float*)(tail + 0);         // 32 KiB
  int*   idx                = (int*)(tail + 32768);       // 64 KiB
  unsigned int* tlist       = (unsigned int*)(tail + 98304);   // 64 KiB
  unsigned long long* rbest = (unsigned long long*)(tail + 163840);  // 128 KiB
  unsigned int* ucount      = (unsigned int*)(tail + 294912);  // 256 B
  float* nsum               = (float*)(tail + 295168);    // 256 B
  int* counts               = (int*)(tail + 295424);      // 32 KiB
  int* offs                 = (int*)(tail + 328192);      // 32 KiB
  int* cursor               = (int*)(tail + 360960);      // 32 KiB
  int* tok                  = (int*)(tail + 393728);      // 64 KiB
  const size_t ws_need2 = SLOTS_B + XP_B + KP_B + 459264;

  // ---- R6 single-stage layout (fallback) ----
  unsigned long long* f_best = (unsigned long long*)d_ws;
  int*   f_idx  = (int*)((char*)d_ws + 131072);
  float* f_h    = (float*)((char*)d_ws + 196608);
  float* f_nsum = (float*)((char*)d_ws + 229376);
  __bf16* f_xp  = (__bf16*)((char*)d_ws + 262144);
  __bf16* f_kp  = (__bf16*)((char*)d_ws + 262144 + XP_B);
  const size_t ws_need1 = 262144 + XP_B + KP_B;

  if (ws_size >= ws_need2) {
    // ---------- two-stage path ----------
    k_pack_all<<<10242, 256, 0, stream>>>(x, key_w, ema_n, xp3, kp3, h, nsum,
                                          ucount, counts);
    k_mfma_top2<<<1024, 256, 0, stream>>>(xp3, kp3, h, slots);
    k_top2_reduce<<<T_TOKENS / 32, 256, 0, stream>>>(slots, idx, tlist, ucount,
                                                     counts, rbest);
    {
      dim3 grid(N_TOKEN / BNr, T_TOKENS / BMr);
      k_mfma_refine<<<grid, 256, 0, stream>>>(xp3, kp3, h, tlist, ucount, rbest);
    }
    k_finalize<<<T_TOKENS / 256, 256, 0, stream>>>(rbest, tlist, ucount, idx, counts);

    k_scan<<<1, 256, 0, stream>>>(counts, offs, cursor);
    k_place<<<T_TOKENS / 256, 256, 0, stream>>>(idx, cursor, tok);
    k_update<<<N_TOKEN / 4, 256, 0, stream>>>(x, ema_n, ema_w, value_w, counts,
                                              offs, tok, nsum,
                                              out_en, out_ew, out_kw, out_q);
  } else if (ws_size >= ws_need1) {
    // ---------- R6 single-stage path ----------
    hipMemsetAsync(f_best, 0xFF, (size_t)T_TOKENS * 8, stream);
    k_pack_x<<<(T_TOKENS * (N_EMBED / 4)) / 256, 256, 0, stream>>>(x, f_xp);
    k_pack_k_norm<<<N_TOKEN / 4, 256, 0, stream>>>(key_w, f_kp, f_h);
    dim3 grid(N_TOKEN / BNr, T_TOKENS / BMr);
    k_mfma_argmin<<<grid, 256, 0, stream>>>(f_xp, f_kp, f_h, f_best);

    k_scaleN<<<N_TOKEN / 256, 256, 0, stream>>>(ema_n, out_en);
    k_extract_counts<<<T_TOKENS / 256, 256, 0, stream>>>(f_best, f_idx, out_en);
    k_scaleW<<<(N_TOKEN * (N_EMBED / 4)) / 256, 256, 0, stream>>>(ema_w, out_ew);
    k_quant_scatter<<<(T_TOKENS * (N_EMBED / 4)) / 256, 256, 0, stream>>>(
        x, value_w, f_idx, out_q, out_ew);
    k_sumn<<<1, 256, 0, stream>>>(out_en, f_nsum);
    k_keyw<<<(N_TOKEN * (N_EMBED / 4)) / 256, 256, 0, stream>>>(out_ew, out_en, f_nsum, out_kw);
  } else {
    // ---------- deep fallback: f32 vector GEMM ----------
    hipMemsetAsync(f_best, 0xFF, (size_t)T_TOKENS * 8, stream);
    k_hnorm<<<N_TOKEN / 4, 256, 0, stream>>>(key_w, f_h);
    dim3 grid(N_TOKEN / BK, T_TOKENS / BT);
    k_gemm_argmin<<<grid, 256, 0, stream>>>(x, key_w, f_h, f_best);

    k_scaleN<<<N_TOKEN / 256, 256, 0, stream>>>(ema_n, out_en);
    k_extract_counts<<<T_TOKENS / 256, 256, 0, stream>>>(f_best, f_idx, out_en);
    k_scaleW<<<(N_TOKEN * (N_EMBED / 4)) / 256, 256, 0, stream>>>(ema_w, out_ew);
    k_quant_scatter<<<(T_TOKENS * (N_EMBED / 4)) / 256, 256, 0, stream>>>(
        x, value_w, f_idx, out_q, out_ew);
    k_sumn<<<1, 256, 0, stream>>>(out_en, f_nsum);
    k_keyw<<<(N_TOKEN * (N_EMBED / 4)) / 256, 256, 0, stream>>>(out_ew, out_en, f_nsum, out_kw);
  }
}